// Round 1
// baseline (5145.916 us; speedup 1.0000x reference)
//
#include <hip/hip_runtime.h>
#include <hip/hip_bf16.h>
#include <math.h>

#define TOK 16384
#define DIMC 512
#define FFI 1365
#define CH1 683

// ---------------------------------------------------------------- CPB MLP
// one block per table row; mode 0: spatial (2-d coords, 63x63 rows),
// mode 1: temporal (1-d coords, 31 rows). hidden = 256.
__global__ __launch_bounds__(256) void cpb_kernel(
    const float* __restrict__ w0, const float* __restrict__ b0,
    const float* __restrict__ w1, const float* __restrict__ b1,
    const float* __restrict__ w2, const float* __restrict__ b2,
    float* __restrict__ table, int mode)
{
    __shared__ float t0[256];
    __shared__ float t1[256];
    int r = blockIdx.x;
    int t = threadIdx.x;
    float c0, c1;
    if (mode == 0) { c0 = (float)(r / 63 - 31); c1 = (float)(r % 63 - 31); }
    else           { c0 = (float)(r - 15);      c1 = 0.f; }
    float a = c0 * w0[t] + b0[t];
    if (mode == 0) a += c1 * w0[256 + t];
    t0[t] = a / (1.f + __expf(-a));          // silu
    __syncthreads();
    float s = b1[t];
    for (int k = 0; k < 256; ++k) s += t0[k] * w1[k * 256 + t];
    t1[t] = s / (1.f + __expf(-s));
    __syncthreads();
    if (t < 8) {
        float o = b2[t];
        for (int k = 0; k < 256; ++k) o += t1[k] * w2[k * 8 + t];
        table[r * 8 + t] = o;
    }
}

// ---------------------------------------------------- (C, T) -> (T, C) transpose
__global__ __launch_bounds__(256) void transpose_in_kernel(
    const float* __restrict__ x, float* __restrict__ dst)
{
    __shared__ float tile[32][33];
    int t0b = blockIdx.x * 32;
    int c0b = blockIdx.y * 32;
    int tx = threadIdx.x & 31, ty = threadIdx.x >> 5;
    #pragma unroll
    for (int it = 0; it < 4; ++it) {
        int c = ty + it * 8;
        tile[c][tx] = x[(size_t)(c0b + c) * TOK + t0b + tx];
    }
    __syncthreads();
    #pragma unroll
    for (int it = 0; it < 4; ++it) {
        int tr = ty + it * 8;
        dst[(size_t)(t0b + tr) * DIMC + c0b + tx] = tile[tx][tr];
    }
}

// ---------------------------------------------------------------- LayerNorm (D=512)
__global__ __launch_bounds__(256) void ln_kernel(
    const float* __restrict__ in, float* __restrict__ out,
    const float* __restrict__ w, const float* __restrict__ b)
{
    __shared__ float r1[4], r2[4];
    size_t base = (size_t)blockIdx.x * DIMC;
    int t = threadIdx.x;
    float x0 = in[base + t], x1 = in[base + 256 + t];
    float s = x0 + x1, s2 = x0 * x0 + x1 * x1;
    #pragma unroll
    for (int o = 32; o > 0; o >>= 1) { s += __shfl_down(s, o, 64); s2 += __shfl_down(s2, o, 64); }
    if ((t & 63) == 0) { r1[t >> 6] = s; r2[t >> 6] = s2; }
    __syncthreads();
    float mean = (r1[0] + r1[1] + r1[2] + r1[3]) * (1.f / 512.f);
    float ex2  = (r2[0] + r2[1] + r2[2] + r2[3]) * (1.f / 512.f);
    float rstd = rsqrtf(ex2 - mean * mean + 1e-5f);
    out[base + t]       = (x0 - mean) * rstd * w[t] + b[t];
    out[base + 256 + t] = (x1 - mean) * rstd * w[256 + t] + b[256 + t];
}

// LN(proj) + residual, residual updated in place
__global__ __launch_bounds__(256) void ln_add_kernel(
    const float* __restrict__ proj, float* __restrict__ io,
    const float* __restrict__ w, const float* __restrict__ b)
{
    __shared__ float r1[4], r2[4];
    size_t base = (size_t)blockIdx.x * DIMC;
    int t = threadIdx.x;
    float x0 = proj[base + t], x1 = proj[base + 256 + t];
    float s = x0 + x1, s2 = x0 * x0 + x1 * x1;
    #pragma unroll
    for (int o = 32; o > 0; o >>= 1) { s += __shfl_down(s, o, 64); s2 += __shfl_down(s2, o, 64); }
    if ((t & 63) == 0) { r1[t >> 6] = s; r2[t >> 6] = s2; }
    __syncthreads();
    float mean = (r1[0] + r1[1] + r1[2] + r1[3]) * (1.f / 512.f);
    float ex2  = (r2[0] + r2[1] + r2[2] + r2[3]) * (1.f / 512.f);
    float rstd = rsqrtf(ex2 - mean * mean + 1e-5f);
    io[base + t]       += (x0 - mean) * rstd * w[t] + b[t];
    io[base + 256 + t] += (x1 - mean) * rstd * w[256 + t] + b[256 + t];
}

// -------------------------------------------------- row permute spatial<->temporal
// mode 0: dst temporal row rt=hw*16+f <- src spatial row f*1024+hw
// mode 1: dst spatial row rs=f*1024+hw <- src temporal row hw*16+f
__global__ __launch_bounds__(128) void permute_kernel(
    const float* __restrict__ src, float* __restrict__ dst, int mode)
{
    int rd = blockIdx.x;
    int rs;
    if (mode == 0) rs = (rd & 15) * 1024 + (rd >> 4);
    else           rs = (rd & 1023) * 16 + (rd >> 10);
    const float4* s4 = (const float4*)(src + (size_t)rs * DIMC);
    float4* d4 = (float4*)(dst + (size_t)rd * DIMC);
    d4[threadIdx.x] = s4[threadIdx.x];
}

// ---------------------------------------------------------------- GEMM
__device__ inline float gelu_exact(float x)
{
    return 0.5f * x * (1.f + erff(x * 0.70710678118654752f));
}

// C[M,N] = A[M,K] @ B[K,N] (B column window at bcol).
// AMODE 0: A plain.  AMODE 1: A = shift+channel-LN view of Y (FF): for row m,
//   col k: raw = (k<683) ? Y[m][k] : (m in frame 0 ? 0 : Y[m-1024][k]);
//   a = (raw - mean[m]) * rstd[m] * g[k].
// EPI 0: C = acc.  EPI 1: C = C * gelu(acc) in place.
// EPI 2: out[n*TOK + m] = acc + resid[m*512+n]  (channel-major final store).
template<int AMODE, int EPI>
__global__ __launch_bounds__(256) void gemm_k(
    const float* __restrict__ A, int lda,
    const float* __restrict__ B, int ldb, int bcol,
    float* __restrict__ C, int ldc,
    int M, int N, int K,
    const float* __restrict__ stats,
    const float* __restrict__ g,
    const float* __restrict__ resid,
    float* __restrict__ outT)
{
    __shared__ float As[16][65];
    __shared__ float Bs[16][65];
    int m0 = blockIdx.y * 64, n0 = blockIdx.x * 64;
    int t = threadIdx.x;
    int ty = t >> 4, tx = t & 15;
    float acc[4][4] = {};
    for (int k0 = 0; k0 < K; k0 += 16) {
        #pragma unroll
        for (int i = 0; i < 4; ++i) {
            int e = t * 4 + i;
            int mm = e >> 4, kk = e & 15;
            int m = m0 + mm, k = k0 + kk;
            float v = 0.f;
            if (k < K) {
                if (AMODE == 0) {
                    v = A[(size_t)m * lda + k];
                } else {
                    int msrc = m;
                    if (k >= CH1) msrc = ((m >> 10) == 0) ? -1 : m - 1024;
                    float raw = (msrc < 0) ? 0.f : A[(size_t)msrc * lda + k];
                    v = (raw - stats[2 * m]) * stats[2 * m + 1] * g[k];
                }
            }
            As[kk][mm] = v;
        }
        #pragma unroll
        for (int i = 0; i < 4; ++i) {
            int e = t + i * 256;
            int kk = e >> 6, nn = e & 63;
            int k = k0 + kk, n = n0 + nn;
            Bs[kk][nn] = (k < K && n < N) ? B[(size_t)k * ldb + bcol + n] : 0.f;
        }
        __syncthreads();
        #pragma unroll
        for (int kk = 0; kk < 16; ++kk) {
            float a[4], b[4];
            #pragma unroll
            for (int i = 0; i < 4; ++i) a[i] = As[kk][ty * 4 + i];
            #pragma unroll
            for (int j = 0; j < 4; ++j) b[j] = Bs[kk][tx * 4 + j];
            #pragma unroll
            for (int i = 0; i < 4; ++i)
                #pragma unroll
                for (int j = 0; j < 4; ++j) acc[i][j] += a[i] * b[j];
        }
        __syncthreads();
    }
    #pragma unroll
    for (int i = 0; i < 4; ++i) {
        int m = m0 + ty * 4 + i;
        #pragma unroll
        for (int j = 0; j < 4; ++j) {
            int n = n0 + tx * 4 + j;
            if (n < N) {
                if (EPI == 0) {
                    C[(size_t)m * ldc + n] = acc[i][j];
                } else if (EPI == 1) {
                    size_t idx = (size_t)m * ldc + n;
                    C[idx] = C[idx] * gelu_exact(acc[i][j]);
                } else {
                    outT[(size_t)n * TOK + m] = acc[i][j] + resid[(size_t)m * DIMC + n];
                }
            }
        }
    }
}

// ---------------------------------------------------------------- spatial attention
// grid (128, 8, 16): (i-tile of 8 queries, head, batch-frame). MQA: 1 KV head.
__global__ __launch_bounds__(256) void attn_sp_kernel(
    const float* __restrict__ q, const float* __restrict__ kv,
    const float* __restrict__ nullkv, const float* __restrict__ nullbias,
    const float* __restrict__ table, float* __restrict__ out)
{
    __shared__ float qs[8][64];
    __shared__ float sc[8][1025];
    __shared__ float red[4];
    int b = blockIdx.z, h = blockIdx.y, i0 = blockIdx.x * 8;
    int t = threadIdx.x;
    for (int e = t; e < 512; e += 256) {
        int qi = e >> 6, d = e & 63;
        qs[qi][d] = q[(size_t)(b * 1024 + i0 + qi) * 512 + h * 64 + d] * 0.125f;
    }
    __syncthreads();
    float nb = nullbias[h];
    for (int j = t; j < 1025; j += 256) {
        float acc[8] = {};
        const float* kp = (j == 0) ? nullkv : (kv + (size_t)(b * 1024 + j - 1) * 128);
        const float4* kp4 = (const float4*)kp;
        #pragma unroll 4
        for (int dq = 0; dq < 16; ++dq) {
            float4 k4 = kp4[dq];
            #pragma unroll
            for (int qi = 0; qi < 8; ++qi) {
                acc[qi] += qs[qi][dq * 4 + 0] * k4.x + qs[qi][dq * 4 + 1] * k4.y
                         + qs[qi][dq * 4 + 2] * k4.z + qs[qi][dq * 4 + 3] * k4.w;
            }
        }
        if (j == 0) {
            #pragma unroll
            for (int qi = 0; qi < 8; ++qi) sc[qi][0] = acc[qi] + nb;
        } else {
            int pj = j - 1, phj = pj >> 5, pwj = pj & 31;
            #pragma unroll
            for (int qi = 0; qi < 8; ++qi) {
                int pi = i0 + qi, phi = pi >> 5, pwi = pi & 31;
                int idx = (phi - phj + 31) * 63 + (pwi - pwj + 31);
                sc[qi][j] = acc[qi] + table[idx * 8 + h];
            }
        }
    }
    __syncthreads();
    float denom[8];
    for (int qi = 0; qi < 8; ++qi) {
        float lm = -1e30f;
        for (int j = t; j < 1025; j += 256) lm = fmaxf(lm, sc[qi][j]);
        #pragma unroll
        for (int o = 32; o > 0; o >>= 1) lm = fmaxf(lm, __shfl_down(lm, o, 64));
        if ((t & 63) == 0) red[t >> 6] = lm;
        __syncthreads();
        float mx = fmaxf(fmaxf(red[0], red[1]), fmaxf(red[2], red[3]));
        __syncthreads();
        float ls = 0.f;
        for (int j = t; j < 1025; j += 256) {
            float p = __expf(sc[qi][j] - mx);
            sc[qi][j] = p;
            ls += p;
        }
        #pragma unroll
        for (int o = 32; o > 0; o >>= 1) ls += __shfl_down(ls, o, 64);
        if ((t & 63) == 0) red[t >> 6] = ls;
        __syncthreads();
        denom[qi] = red[0] + red[1] + red[2] + red[3];
        __syncthreads();
    }
    int d = t & 63, ch = t >> 6;
    float acc[8] = {};
    for (int j = ch; j < 1025; j += 4) {
        float vd = (j == 0) ? nullkv[64 + d] : kv[(size_t)(b * 1024 + j - 1) * 128 + 64 + d];
        #pragma unroll
        for (int qi = 0; qi < 8; ++qi) acc[qi] += sc[qi][j] * vd;
    }
    __syncthreads();
    float* racc = &sc[0][0];   // reuse 2048 floats
    #pragma unroll
    for (int qi = 0; qi < 8; ++qi) racc[(qi * 4 + ch) * 64 + d] = acc[qi];
    __syncthreads();
    for (int e = t; e < 512; e += 256) {
        int qi = e >> 6, dd = e & 63;
        float s = racc[(qi * 4 + 0) * 64 + dd] + racc[(qi * 4 + 1) * 64 + dd]
                + racc[(qi * 4 + 2) * 64 + dd] + racc[(qi * 4 + 3) * 64 + dd];
        out[(size_t)(b * 1024 + i0 + qi) * 512 + h * 64 + dd] = s / denom[qi];
    }
}

// ---------------------------------------------------------------- temporal attention
// grid 1024: one block per spatial position (batch), all 8 heads, 16 tokens.
__global__ __launch_bounds__(256) void attn_tp_kernel(
    const float* __restrict__ q, const float* __restrict__ kv,
    const float* __restrict__ nullkv, const float* __restrict__ nullbias,
    const float* __restrict__ table, float* __restrict__ out)
{
    __shared__ float qs[16][512];
    __shared__ float ks[17][64];
    __shared__ float vs[17][64];
    __shared__ float sc[8][16][17];
    int b = blockIdx.x;
    int t = threadIdx.x;
    for (int e = t; e < 16 * 512; e += 256) {
        int f = e >> 9, c = e & 511;
        qs[f][c] = q[(size_t)(b * 16 + f) * 512 + c] * 0.125f;
    }
    for (int e = t; e < 17 * 64; e += 256) {
        int j = e >> 6, d = e & 63;
        ks[j][d] = (j == 0) ? nullkv[d]      : kv[(size_t)(b * 16 + j - 1) * 128 + d];
        vs[j][d] = (j == 0) ? nullkv[64 + d] : kv[(size_t)(b * 16 + j - 1) * 128 + 64 + d];
    }
    __syncthreads();
    for (int e = t; e < 8 * 16 * 17; e += 256) {
        int h = e / 272, rem = e - h * 272;
        int i = rem / 17, j = rem - i * 17;
        float acc = 0.f;
        for (int d = 0; d < 64; ++d) acc += qs[i][h * 64 + d] * ks[j][d];
        float bias = (j == 0) ? nullbias[h] : table[(i - (j - 1) + 15) * 8 + h];
        sc[h][i][j] = acc + bias;
    }
    __syncthreads();
    if (t < 128) {
        int h = t >> 4, i = t & 15;
        float mx = -1e30f;
        for (int j = 0; j < 17; ++j) mx = fmaxf(mx, sc[h][i][j]);
        float s = 0.f;
        for (int j = 0; j < 17; ++j) { float p = __expf(sc[h][i][j] - mx); sc[h][i][j] = p; s += p; }
        float inv = 1.f / s;
        for (int j = 0; j < 17; ++j) sc[h][i][j] *= inv;
    }
    __syncthreads();
    for (int e = t; e < 16 * 512; e += 256) {
        int i = e >> 9, c = e & 511;
        int h = c >> 6, d = c & 63;
        float acc = 0.f;
        #pragma unroll
        for (int j = 0; j < 17; ++j) acc += sc[h][i][j] * vs[j][d];
        out[(size_t)(b * 16 + i) * 512 + c] = acc;
    }
}

// ------------------------------------------------- FF shift-LN row statistics
__global__ __launch_bounds__(256) void rowstats_kernel(
    const float* __restrict__ Y, float* __restrict__ stats)
{
    __shared__ float r1[4], r2[4];
    int r = blockIdx.x, t = threadIdx.x;
    const float* rowa = Y + (size_t)r * FFI;
    const float* rowb = (r >> 10) ? (Y + (size_t)(r - 1024) * FFI) : nullptr;
    float s = 0.f, s2 = 0.f;
    for (int c = t; c < FFI; c += 256) {
        float v = (c < CH1) ? rowa[c] : (rowb ? rowb[c] : 0.f);
        s += v; s2 += v * v;
    }
    #pragma unroll
    for (int o = 32; o > 0; o >>= 1) { s += __shfl_down(s, o, 64); s2 += __shfl_down(s2, o, 64); }
    if ((t & 63) == 0) { r1[t >> 6] = s; r2[t >> 6] = s2; }
    __syncthreads();
    float S  = r1[0] + r1[1] + r1[2] + r1[3];
    float S2 = r2[0] + r2[1] + r2[2] + r2[3];
    float mean = S * (1.f / 1365.f);
    float var  = S2 * (1.f / 1365.f) - mean * mean;
    float rstd = rsqrtf(fmaxf(var, 1e-5f));
    if (t == 0) { stats[2 * r] = mean; stats[2 * r + 1] = rstd; }
}

// ================================================================ launcher
extern "C" void kernel_launch(void* const* d_in, const int* in_sizes, int n_in,
                              void* d_out, int out_size, void* d_ws, size_t ws_size,
                              hipStream_t stream)
{
    const float* x          = (const float*)d_in[0];
    const float* sa_ln_w    = (const float*)d_in[1];
    const float* sa_ln_b    = (const float*)d_in[2];
    const float* sa_wq      = (const float*)d_in[3];
    const float* sa_wkv     = (const float*)d_in[4];
    const float* sa_null_kv = (const float*)d_in[5];
    const float* sa_null_b  = (const float*)d_in[6];
    const float* sa_wout    = (const float*)d_in[7];
    const float* sa_oln_w   = (const float*)d_in[8];
    const float* sa_oln_b   = (const float*)d_in[9];
    const float* ta_ln_w    = (const float*)d_in[10];
    const float* ta_ln_b    = (const float*)d_in[11];
    const float* ta_wq      = (const float*)d_in[12];
    const float* ta_wkv     = (const float*)d_in[13];
    const float* ta_null_kv = (const float*)d_in[14];
    const float* ta_null_b  = (const float*)d_in[15];
    const float* ta_wout    = (const float*)d_in[16];
    const float* ta_oln_w   = (const float*)d_in[17];
    const float* ta_oln_b   = (const float*)d_in[18];
    const float* sp_w0      = (const float*)d_in[19];
    const float* sp_b0      = (const float*)d_in[20];
    const float* sp_w1      = (const float*)d_in[21];
    const float* sp_b1      = (const float*)d_in[22];
    const float* sp_w2      = (const float*)d_in[23];
    const float* sp_b2      = (const float*)d_in[24];
    const float* tp_w0      = (const float*)d_in[25];
    const float* tp_b0      = (const float*)d_in[26];
    const float* tp_w1      = (const float*)d_in[27];
    const float* tp_b1      = (const float*)d_in[28];
    const float* tp_w2      = (const float*)d_in[29];
    const float* tp_b2      = (const float*)d_in[30];
    const float* ff_win     = (const float*)d_in[31];
    const float* ff_g       = (const float*)d_in[32];
    const float* ff_wout    = (const float*)d_in[33];

    char* ws = (char*)d_ws;
    const size_t SZ = (size_t)TOK * DIMC * sizeof(float);   // 33.55 MB
    float* B0   = (float*)(ws);
    float* B1   = (float*)(ws + SZ);
    float* B2   = (float*)(ws + 2 * SZ);
    float* B3   = (float*)(ws + 3 * SZ);
    float* KVB  = (float*)(ws + 4 * SZ);
    size_t off  = 4 * SZ + (size_t)TOK * 128 * sizeof(float);
    float* SPT  = (float*)(ws + off); off += ((size_t)3969 * 8 * 4 + 255) & ~255ULL;
    float* TPT  = (float*)(ws + off); off += ((size_t)31 * 8 * 4 + 255) & ~255ULL;
    float* STATS= (float*)(ws + off);
    float* YA   = B0;   // FF activation (16384 x 1365 f32 = 89.5 MB) aliases B0..B2

    dim3 blk(256);

    // bias tables
    cpb_kernel<<<dim3(3969), blk, 0, stream>>>(sp_w0, sp_b0, sp_w1, sp_b1, sp_w2, sp_b2, SPT, 0);
    cpb_kernel<<<dim3(31),   blk, 0, stream>>>(tp_w0, tp_b0, tp_w1, tp_b1, tp_w2, tp_b2, TPT, 1);

    // ---------------- spatial attention ----------------
    transpose_in_kernel<<<dim3(512, 16), blk, 0, stream>>>(x, B0);
    ln_kernel<<<dim3(TOK), blk, 0, stream>>>(B0, B1, sa_ln_w, sa_ln_b);
    gemm_k<0, 0><<<dim3(8, 256), blk, 0, stream>>>(B1, 512, sa_wq, 512, 0, B2, 512,
        TOK, 512, 512, nullptr, nullptr, nullptr, nullptr);
    gemm_k<0, 0><<<dim3(2, 256), blk, 0, stream>>>(B1, 512, sa_wkv, 128, 0, KVB, 128,
        TOK, 128, 512, nullptr, nullptr, nullptr, nullptr);
    attn_sp_kernel<<<dim3(128, 8, 16), blk, 0, stream>>>(B2, KVB, sa_null_kv, sa_null_b, SPT, B3);
    gemm_k<0, 0><<<dim3(8, 256), blk, 0, stream>>>(B3, 512, sa_wout, 512, 0, B1, 512,
        TOK, 512, 512, nullptr, nullptr, nullptr, nullptr);
    ln_add_kernel<<<dim3(TOK), blk, 0, stream>>>(B1, B0, sa_oln_w, sa_oln_b);

    // ---------------- temporal attention ----------------
    permute_kernel<<<dim3(TOK), dim3(128), 0, stream>>>(B0, B1, 0);
    ln_kernel<<<dim3(TOK), blk, 0, stream>>>(B1, B2, ta_ln_w, ta_ln_b);
    gemm_k<0, 0><<<dim3(8, 256), blk, 0, stream>>>(B2, 512, ta_wq, 512, 0, B3, 512,
        TOK, 512, 512, nullptr, nullptr, nullptr, nullptr);
    gemm_k<0, 0><<<dim3(2, 256), blk, 0, stream>>>(B2, 512, ta_wkv, 128, 0, KVB, 128,
        TOK, 128, 512, nullptr, nullptr, nullptr, nullptr);
    attn_tp_kernel<<<dim3(1024), blk, 0, stream>>>(B3, KVB, ta_null_kv, ta_null_b, TPT, B0);
    gemm_k<0, 0><<<dim3(8, 256), blk, 0, stream>>>(B0, 512, ta_wout, 512, 0, B2, 512,
        TOK, 512, 512, nullptr, nullptr, nullptr, nullptr);
    ln_add_kernel<<<dim3(TOK), blk, 0, stream>>>(B2, B1, ta_oln_w, ta_oln_b);
    permute_kernel<<<dim3(TOK), dim3(128), 0, stream>>>(B1, B3, 1);   // B3 = x2 (FF input + residual)

    // ---------------- feed-forward ----------------
    // a-half, then gate-half fused with a*gelu(gate) in place
    gemm_k<0, 0><<<dim3(22, 256), blk, 0, stream>>>(B3, 512, ff_win, 2730, 0, YA, FFI,
        TOK, FFI, 512, nullptr, nullptr, nullptr, nullptr);
    gemm_k<0, 1><<<dim3(22, 256), blk, 0, stream>>>(B3, 512, ff_win, 2730, FFI, YA, FFI,
        TOK, FFI, 512, nullptr, nullptr, nullptr, nullptr);
    rowstats_kernel<<<dim3(TOK), blk, 0, stream>>>(YA, STATS);
    // shift+LN applied in A-load; epilogue adds residual and stores channel-major
    gemm_k<1, 2><<<dim3(8, 256), blk, 0, stream>>>(YA, FFI, ff_wout, 512, 0, nullptr, 0,
        TOK, 512, FFI, STATS, ff_g, B3, (float*)d_out);
}

// Round 3
// 1391.444 us; speedup vs baseline: 3.6983x; 3.6983x over previous
//
#include <hip/hip_runtime.h>
#include <math.h>

#define TOK 16384
#define DIMC 512
#define FFI 1365
#define CH1 683
#define YLD 1368          // YA row stride (floats, 16B aligned)
#define KVPAD 1056        // padded key count for spatial attn (mult of 8)

typedef unsigned int u32;
typedef unsigned short ushort_t;
typedef __attribute__((ext_vector_type(8))) short bf16x8;
typedef __attribute__((ext_vector_type(4))) float f32x4;

__device__ inline ushort_t f2b(float x) {
    u32 u = __float_as_uint(x);
    u32 r = (u + 0x7fffu + ((u >> 16) & 1u)) >> 16;
    return (ushort_t)r;
}
__device__ inline float b2f(ushort_t u) { return __uint_as_float(((u32)u) << 16); }

__device__ inline void gload_lds16(const void* g, void* l) {
    __builtin_amdgcn_global_load_lds(
        (const __attribute__((address_space(1))) u32*)g,
        (__attribute__((address_space(3))) u32*)l, 16, 0, 0);
}

__device__ inline float gelu_exact(float x) {
    return 0.5f * x * (1.f + erff(x * 0.70710678118654752f));
}

// ---------------------------------------------------------------- CPB MLP
__global__ __launch_bounds__(256) void cpb_kernel(
    const float* __restrict__ w0, const float* __restrict__ b0,
    const float* __restrict__ w1, const float* __restrict__ b1,
    const float* __restrict__ w2, const float* __restrict__ b2,
    float* __restrict__ table, int mode)
{
    __shared__ float t0[256];
    __shared__ float t1[256];
    int r = blockIdx.x;
    int t = threadIdx.x;
    float c0, c1;
    if (mode == 0) { c0 = (float)(r / 63 - 31); c1 = (float)(r % 63 - 31); }
    else           { c0 = (float)(r - 15);      c1 = 0.f; }
    float a = c0 * w0[t] + b0[t];
    if (mode == 0) a += c1 * w0[256 + t];
    t0[t] = a / (1.f + __expf(-a));
    __syncthreads();
    float s = b1[t];
    for (int k = 0; k < 256; ++k) s += t0[k] * w1[k * 256 + t];
    t1[t] = s / (1.f + __expf(-s));
    __syncthreads();
    if (t < 8) {
        float o = b2[t];
        for (int k = 0; k < 256; ++k) o += t1[k] * w2[k * 8 + t];
        table[r * 8 + t] = o;
    }
}

// --------------------------------------------- materialize spatial bias bf16
__global__ __launch_bounds__(256) void bias_sp_kernel(
    const float* __restrict__ tab, ushort_t* __restrict__ out)
{
    int pi = blockIdx.x, h = blockIdx.y;
    int phi = pi >> 5, pwi = pi & 31;
    for (int pj = threadIdx.x; pj < 1024; pj += 256) {
        int phj = pj >> 5, pwj = pj & 31;
        int idx = (phi - phj + 31) * 63 + (pwi - pwj + 31);
        out[((size_t)h * 1024 + pi) * 1024 + pj] = f2b(tab[idx * 8 + h]);
    }
}

// -------------------------------------------- KP/VT pad+null init. grid 16
__global__ __launch_bounds__(256) void kvinit_kernel(
    const float* __restrict__ nullkv, ushort_t* __restrict__ KP, ushort_t* __restrict__ VT)
{
    int f = blockIdx.x, t = threadIdx.x;
    for (int e = t; e < 32 * 64; e += 256) {
        int rr = e >> 6, d = e & 63;
        int row = (rr == 0) ? 0 : (1024 + rr);
        KP[((size_t)f * KVPAD + row) * 64 + d] = (rr == 0) ? f2b(nullkv[d]) : (ushort_t)0;
    }
    for (int e = t; e < 64 * 32; e += 256) {
        int d = e >> 5, cc = e & 31;
        int col = (cc == 0) ? 0 : (1024 + cc);
        VT[((size_t)f * 64 + d) * KVPAD + col] = (cc == 0) ? f2b(nullkv[64 + d]) : (ushort_t)0;
    }
}

// ------------------------------------- weight convert: W[K][ldw] -> Bt[N][Kp] bf16
__global__ __launch_bounds__(256) void wcvt_kernel(
    const float* __restrict__ W, int ldw, int c0,
    ushort_t* __restrict__ Bt, int Kp, int K, int Ncols)
{
    __shared__ float tile[32][33];
    int nb = blockIdx.x * 32, kb = blockIdx.y * 32;
    int tx = threadIdx.x & 31, ty = threadIdx.x >> 5;
    #pragma unroll
    for (int it = 0; it < 4; ++it) {
        int k = kb + ty + it * 8, n = nb + tx;
        tile[ty + it * 8][tx] = (k < K && n < Ncols) ? W[(size_t)k * ldw + c0 + n] : 0.f;
    }
    __syncthreads();
    #pragma unroll
    for (int it = 0; it < 4; ++it) {
        int n = nb + ty + it * 8, k = kb + tx;
        if (n < Ncols && k < Kp) Bt[(size_t)n * Kp + k] = f2b(tile[tx][ty + it * 8]);
    }
}

// ---------------------------------------------------- (C,T) -> (T,C) transpose
__global__ __launch_bounds__(256) void transpose_in_kernel(
    const float* __restrict__ x, float* __restrict__ dst)
{
    __shared__ float tile[32][33];
    int t0b = blockIdx.x * 32, c0b = blockIdx.y * 32;
    int tx = threadIdx.x & 31, ty = threadIdx.x >> 5;
    #pragma unroll
    for (int it = 0; it < 4; ++it) {
        int c = ty + it * 8;
        tile[c][tx] = x[(size_t)(c0b + c) * TOK + t0b + tx];
    }
    __syncthreads();
    #pragma unroll
    for (int it = 0; it < 4; ++it) {
        int tr = ty + it * 8;
        dst[(size_t)(t0b + tr) * DIMC + c0b + tx] = tile[tx][tr];
    }
}

// ---------------------------------------------------------------- LayerNorm → bf16
__global__ __launch_bounds__(256) void ln_bf16_kernel(
    const float* __restrict__ in, ushort_t* __restrict__ out,
    const float* __restrict__ w, const float* __restrict__ b)
{
    __shared__ float r1[4], r2[4];
    size_t base = (size_t)blockIdx.x * DIMC;
    int t = threadIdx.x;
    float x0 = in[base + t], x1 = in[base + 256 + t];
    float s = x0 + x1, s2 = x0 * x0 + x1 * x1;
    #pragma unroll
    for (int o = 32; o > 0; o >>= 1) { s += __shfl_down(s, o, 64); s2 += __shfl_down(s2, o, 64); }
    if ((t & 63) == 0) { r1[t >> 6] = s; r2[t >> 6] = s2; }
    __syncthreads();
    float mean = (r1[0] + r1[1] + r1[2] + r1[3]) * (1.f / 512.f);
    float ex2  = (r2[0] + r2[1] + r2[2] + r2[3]) * (1.f / 512.f);
    float rstd = rsqrtf(ex2 - mean * mean + 1e-5f);
    out[base + t]       = f2b((x0 - mean) * rstd * w[t] + b[t]);
    out[base + 256 + t] = f2b((x1 - mean) * rstd * w[256 + t] + b[256 + t]);
}

// LN(proj f32) + residual in place
__global__ __launch_bounds__(256) void ln_add_kernel(
    const float* __restrict__ proj, float* __restrict__ io,
    const float* __restrict__ w, const float* __restrict__ b)
{
    __shared__ float r1[4], r2[4];
    size_t base = (size_t)blockIdx.x * DIMC;
    int t = threadIdx.x;
    float x0 = proj[base + t], x1 = proj[base + 256 + t];
    float s = x0 + x1, s2 = x0 * x0 + x1 * x1;
    #pragma unroll
    for (int o = 32; o > 0; o >>= 1) { s += __shfl_down(s, o, 64); s2 += __shfl_down(s2, o, 64); }
    if ((t & 63) == 0) { r1[t >> 6] = s; r2[t >> 6] = s2; }
    __syncthreads();
    float mean = (r1[0] + r1[1] + r1[2] + r1[3]) * (1.f / 512.f);
    float ex2  = (r2[0] + r2[1] + r2[2] + r2[3]) * (1.f / 512.f);
    float rstd = rsqrtf(ex2 - mean * mean + 1e-5f);
    io[base + t]       += (x0 - mean) * rstd * w[t] + b[t];
    io[base + 256 + t] += (x1 - mean) * rstd * w[256 + t] + b[256 + t];
}

// spatial->temporal row permute (f32)
__global__ __launch_bounds__(128) void permute0_kernel(
    const float* __restrict__ src, float* __restrict__ dst)
{
    int rd = blockIdx.x;
    int rs = (rd & 15) * 1024 + (rd >> 4);
    ((float4*)(dst + (size_t)rd * DIMC))[threadIdx.x] =
        ((const float4*)(src + (size_t)rs * DIMC))[threadIdx.x];
}

// temporal->spatial permute, dual output f32 + bf16
__global__ __launch_bounds__(128) void permute1_dual_kernel(
    const float* __restrict__ src, float* __restrict__ dst, ushort_t* __restrict__ dstb)
{
    int rd = blockIdx.x;
    int rs = (rd & 1023) * 16 + (rd >> 10);
    float4 v = ((const float4*)(src + (size_t)rs * DIMC))[threadIdx.x];
    ((float4*)(dst + (size_t)rd * DIMC))[threadIdx.x] = v;
    u32 lo = (u32)f2b(v.x) | ((u32)f2b(v.y) << 16);
    u32 hi = (u32)f2b(v.z) | ((u32)f2b(v.w) << 16);
    ((uint2*)(dstb + (size_t)rd * DIMC))[threadIdx.x] = make_uint2(lo, hi);
}

// ---------------------------------------------------------------- MFMA GEMM
// C[M,N] = A[M,K] @ B[K,N]; Bt is B^T bf16 [N][Kp].
// AMODE 0: A bf16 [M][lda].  AMODE 1: A = shift+chanLN view of f32 YA.
// EPI 0: C f32 = acc*scale. EPI 1: C f32 *= gelu(acc) in place.
// EPI 2: outT[n*TOK+m] = acc + resid[m*512+n]. EPI 3: Cb bf16 = acc*scale.
// EPI 4: spatial KV scatter into KP/VT.
template<int AMODE, int EPI>
__global__ __launch_bounds__(256) void gemm_mfma(
    const ushort_t* __restrict__ A, const float* __restrict__ Af, int lda,
    const ushort_t* __restrict__ Bt, int Kp,
    float* __restrict__ C, ushort_t* __restrict__ Cb, int ldc,
    int M, int N, int K, int Kreal, float scale,
    const float* __restrict__ stats, const float* __restrict__ g,
    const float* __restrict__ resid, float* __restrict__ outT,
    ushort_t* __restrict__ KPo, ushort_t* __restrict__ VTo)
{
    __shared__ __align__(16) ushort_t As[4 * 128 * 8];
    __shared__ __align__(16) ushort_t Bs[4 * 128 * 8];
    int m0 = blockIdx.y * 128, n0 = blockIdx.x * 128;
    int tid = threadIdx.x, lane = tid & 63, wid = tid >> 6;
    int wy = wid >> 1, wx = wid & 1, quad = lane >> 4, l16 = lane & 15;
    bool bfull = (n0 + 128 <= N);
    f32x4 acc[4][4];
    #pragma unroll
    for (int i = 0; i < 4; ++i)
        #pragma unroll
        for (int j = 0; j < 4; ++j) { acc[i][j][0]=0.f; acc[i][j][1]=0.f; acc[i][j][2]=0.f; acc[i][j][3]=0.f; }

    for (int k0 = 0; k0 < K; k0 += 32) {
        if (k0) __syncthreads();
        // ---- stage A tile (128 m x 32 k) as [kg 4][m 128][8]
        if (AMODE == 0) {
            #pragma unroll
            for (int r = 0; r < 2; ++r) {
                int c = wid * 128 + r * 64 + lane;
                const ushort_t* src = A + (size_t)(m0 + (c & 127)) * lda + k0 + (c >> 7) * 8;
                gload_lds16(src, &As[(wid * 128 + r * 64) * 8]);
            }
        } else {
            #pragma unroll
            for (int r = 0; r < 2; ++r) {
                int c = tid + r * 256;
                int kg = c >> 7, mloc = c & 127, m = m0 + mloc;
                float mean = stats[2 * m], rstd = stats[2 * m + 1];
                bf16x8 tv;
                #pragma unroll
                for (int e = 0; e < 8; ++e) {
                    int k = k0 + kg * 8 + e;
                    float v = 0.f;
                    if (k < Kreal) {
                        int ms = (k >= CH1) ? ((m >> 10) ? m - 1024 : -1) : m;
                        float raw = (ms < 0) ? 0.f : Af[(size_t)ms * lda + k];
                        v = (raw - mean) * rstd * g[k];
                    }
                    tv[e] = (short)f2b(v);
                }
                *(bf16x8*)&As[c * 8] = tv;
            }
        }
        // ---- stage B tile (128 n x 32 k) as [kg 4][n 128][8]
        if (bfull) {
            #pragma unroll
            for (int r = 0; r < 2; ++r) {
                int c = wid * 128 + r * 64 + lane;
                const ushort_t* src = Bt + (size_t)(n0 + (c & 127)) * Kp + k0 + (c >> 7) * 8;
                gload_lds16(src, &Bs[(wid * 128 + r * 64) * 8]);
            }
        } else {
            #pragma unroll
            for (int r = 0; r < 2; ++r) {
                int c = tid + r * 256;
                int kg = c >> 7, nloc = c & 127;
                bf16x8 v;
                if (n0 + nloc < N) v = *(const bf16x8*)(Bt + (size_t)(n0 + nloc) * Kp + k0 + kg * 8);
                else { for (int e = 0; e < 8; ++e) v[e] = 0; }
                *(bf16x8*)&Bs[c * 8] = v;
            }
        }
        __syncthreads();
        // ---- compute
        bf16x8 af[4], bfr[4];
        #pragma unroll
        for (int i = 0; i < 4; ++i) af[i] = *(bf16x8*)&As[(quad * 128 + wy * 64 + i * 16 + l16) * 8];
        #pragma unroll
        for (int j = 0; j < 4; ++j) bfr[j] = *(bf16x8*)&Bs[(quad * 128 + wx * 64 + j * 16 + l16) * 8];
        #pragma unroll
        for (int i = 0; i < 4; ++i)
            #pragma unroll
            for (int j = 0; j < 4; ++j)
                acc[i][j] = __builtin_amdgcn_mfma_f32_16x16x32_bf16(af[i], bfr[j], acc[i][j], 0, 0, 0);
    }
    // ---- epilogue
    #pragma unroll
    for (int i = 0; i < 4; ++i) {
        #pragma unroll
        for (int j = 0; j < 4; ++j) {
            #pragma unroll
            for (int r = 0; r < 4; ++r) {
                int m = m0 + wy * 64 + i * 16 + quad * 4 + r;
                int n = n0 + wx * 64 + j * 16 + l16;
                if (n >= N) continue;
                float v = acc[i][j][r] * scale;
                if (EPI == 0) {
                    C[(size_t)m * ldc + n] = v;
                } else if (EPI == 1) {
                    size_t idx = (size_t)m * ldc + n;
                    C[idx] = C[idx] * gelu_exact(v);
                } else if (EPI == 2) {
                    outT[(size_t)n * TOK + m] = v + resid[(size_t)m * DIMC + n];
                } else if (EPI == 3) {
                    Cb[(size_t)m * ldc + n] = f2b(v);
                } else if (EPI == 4) {
                    int frame = m >> 10, tt = m & 1023;
                    if (n < 64) KPo[((size_t)frame * KVPAD + 1 + tt) * 64 + n] = f2b(v);
                    else        VTo[((size_t)frame * 64 + (n - 64)) * KVPAD + 1 + tt] = f2b(v);
                }
            }
        }
    }
}

// --------------------------------------------------- spatial attention (MFMA flash)
// grid (64 q-tiles of 16, 16 frames); block 256 = 4 waves.
// FIX vs round 2: each wave owns 2 WHOLE heads and the FULL 128-key tile, so the
// online-softmax stats (mrow/lrow) cover every key column — no cross-wave mixing.
__global__ __launch_bounds__(256) void attn_sp_mfma(
    const ushort_t* __restrict__ Q,     // [16384][512] bf16 pre-scaled
    const ushort_t* __restrict__ KP,    // [16][1056][64] bf16 (row0=null, pads 0)
    const ushort_t* __restrict__ VT,    // [16][64][1056] bf16
    const ushort_t* __restrict__ BIAS,  // [8][1024][1024] bf16
    const float* __restrict__ nullbias,
    ushort_t* __restrict__ O)           // [16384][512] bf16
{
    __shared__ __align__(16) ushort_t Ks[128 * 64];    // swizzled 16B chunks
    __shared__ __align__(16) ushort_t Vs[64 * 128];    // swizzled
    __shared__ __align__(16) ushort_t Ps[128 * 136];   // per-wave rows [wid*32, wid*32+32)
    int qt = blockIdx.x, frame = blockIdx.y;
    int q0 = qt * 16;
    int tid = threadIdx.x, lane = tid & 63, wid = tid >> 6;
    int quad = lane >> 4, l16 = lane & 15;

    bf16x8 aQ[2][2];
    float nbv[2];
    #pragma unroll
    for (int i = 0; i < 2; ++i) {
        int h = wid * 2 + i;
        const ushort_t* qp = Q + (size_t)(frame * 1024 + q0 + l16) * 512 + h * 64 + quad * 8;
        aQ[i][0] = *(const bf16x8*)qp;
        aQ[i][1] = *(const bf16x8*)(qp + 32);
        nbv[i] = nullbias[h];
    }
    f32x4 Oc[2][4];
    float mrow[2][4], lrow[2][4];
    #pragma unroll
    for (int i = 0; i < 2; ++i) {
        #pragma unroll
        for (int nt = 0; nt < 4; ++nt) { Oc[i][nt][0]=0.f; Oc[i][nt][1]=0.f; Oc[i][nt][2]=0.f; Oc[i][nt][3]=0.f; }
        #pragma unroll
        for (int r = 0; r < 4; ++r) { mrow[i][r] = -3.0e38f; lrow[i][r] = 0.f; }
    }

    for (int jt = 0; jt < 9; ++jt) {
        __syncthreads();   // all waves done reading Ks/Vs (and it's the entry barrier)
        // stage K: chunk(c,g') at c*8+g' holds K[c][(g'^(c&7))*8..]
        #pragma unroll
        for (int r = 0; r < 4; ++r) {
            int L = wid * 256 + r * 64 + lane;
            int c = L >> 3, gp = L & 7, gg = gp ^ (c & 7);
            int jj = jt * 128 + c; if (jj > KVPAD - 1) jj = KVPAD - 1;
            gload_lds16(KP + ((size_t)frame * KVPAD + jj) * 64 + gg * 8, &Ks[(wid * 256 + r * 64) * 8]);
        }
        // stage V: chunk(d,cg') holds VT[d][decode(cg')*8..]
        #pragma unroll
        for (int r = 0; r < 4; ++r) {
            int L = wid * 256 + r * 64 + lane;
            int d = L >> 4, cgp = L & 15;
            int cg = (cgp & 8) | ((cgp & 7) ^ (d & 7));
            int col = jt * 128 + cg * 8; if (col > KVPAD - 8) col = KVPAD - 8;
            gload_lds16(VT + ((size_t)frame * 64 + d) * KVPAD + col, &Vs[(wid * 256 + r * 64) * 8]);
        }
        __syncthreads();
        // S = Q K^T : 2 heads x 16 q x FULL 128 keys per wave
        f32x4 S[2][8];
        #pragma unroll
        for (int i = 0; i < 2; ++i)
            #pragma unroll
            for (int j = 0; j < 8; ++j) { S[i][j][0]=0.f; S[i][j][1]=0.f; S[i][j][2]=0.f; S[i][j][3]=0.f; }
        #pragma unroll
        for (int j = 0; j < 8; ++j) {
            int c = j * 16 + l16;
            #pragma unroll
            for (int ks = 0; ks < 2; ++ks) {
                bf16x8 kb = *(bf16x8*)&Ks[(c * 8 + ((ks * 4 + quad) ^ (c & 7))) * 8];
                #pragma unroll
                for (int i = 0; i < 2; ++i)
                    S[i][j] = __builtin_amdgcn_mfma_f32_16x16x32_bf16(aQ[i][ks], kb, S[i][j], 0, 0, 0);
            }
        }
        // bias + mask
        #pragma unroll
        for (int i = 0; i < 2; ++i) {
            int h = wid * 2 + i;
            #pragma unroll
            for (int j = 0; j < 8; ++j) {
                int jj = jt * 128 + j * 16 + l16;
                #pragma unroll
                for (int r = 0; r < 4; ++r) {
                    int ql = quad * 4 + r;
                    float s = S[i][j][r];
                    if (jj == 0) s += nbv[i];
                    else if (jj <= 1024) s += b2f(BIAS[((size_t)h * 1024 + q0 + ql) * 1024 + jj - 1]);
                    else s = -3.0e38f;
                    S[i][j][r] = s;
                }
            }
        }
        // online softmax per row (i, r) — covers all 128 keys of the tile
        #pragma unroll
        for (int i = 0; i < 2; ++i) {
            #pragma unroll
            for (int r = 0; r < 4; ++r) {
                float mx = S[i][0][r];
                #pragma unroll
                for (int j = 1; j < 8; ++j) mx = fmaxf(mx, S[i][j][r]);
                #pragma unroll
                for (int o = 1; o < 16; o <<= 1) mx = fmaxf(mx, __shfl_xor(mx, o, 64));
                float mnew = fmaxf(mrow[i][r], mx);
                float alpha = __expf(mrow[i][r] - mnew);
                mrow[i][r] = mnew;
                float rs = 0.f;
                #pragma unroll
                for (int j = 0; j < 8; ++j) {
                    float p = __expf(S[i][j][r] - mnew);
                    S[i][j][r] = p;
                    rs += p;
                }
                #pragma unroll
                for (int o = 1; o < 16; o <<= 1) rs += __shfl_xor(rs, o, 64);
                lrow[i][r] = lrow[i][r] * alpha + rs;
                #pragma unroll
                for (int nt = 0; nt < 4; ++nt) Oc[i][nt][r] *= alpha;
            }
        }
        // write P (bf16) to this wave's own Ps rows
        #pragma unroll
        for (int i = 0; i < 2; ++i)
            #pragma unroll
            for (int j = 0; j < 8; ++j)
                #pragma unroll
                for (int r = 0; r < 4; ++r) {
                    int rw = wid * 32 + i * 16 + quad * 4 + r;
                    int cl = j * 16 + l16;
                    Ps[rw * 136 + cl] = f2b(S[i][j][r]);
                }
        // O += P V  (Ps rows are wave-private; Vs already barriered after staging)
        #pragma unroll
        for (int ks = 0; ks < 4; ++ks) {
            bf16x8 vb[4];
            #pragma unroll
            for (int nt = 0; nt < 4; ++nt) {
                int d = nt * 16 + l16;
                int cg = ks * 4 + quad;
                int phys = (cg & 8) | ((cg & 7) ^ (d & 7));
                vb[nt] = *(bf16x8*)&Vs[(d * 16 + phys) * 8];
            }
            #pragma unroll
            for (int i = 0; i < 2; ++i) {
                bf16x8 pa = *(bf16x8*)&Ps[(wid * 32 + i * 16 + l16) * 136 + ks * 32 + quad * 8];
                #pragma unroll
                for (int nt = 0; nt < 4; ++nt)
                    Oc[i][nt] = __builtin_amdgcn_mfma_f32_16x16x32_bf16(pa, vb[nt], Oc[i][nt], 0, 0, 0);
            }
        }
    }
    // epilogue: O / l, store bf16
    #pragma unroll
    for (int i = 0; i < 2; ++i) {
        int h = wid * 2 + i;
        #pragma unroll
        for (int nt = 0; nt < 4; ++nt) {
            int d = nt * 16 + l16;
            #pragma unroll
            for (int r = 0; r < 4; ++r) {
                int ql = quad * 4 + r;
                float v = Oc[i][nt][r] / lrow[i][r];
                O[(size_t)(frame * 1024 + q0 + ql) * 512 + h * 64 + d] = f2b(v);
            }
        }
    }
}

// ---------------------------------------------------------------- temporal attention
__global__ __launch_bounds__(256) void attn_tp_kernel(
    const ushort_t* __restrict__ q, const ushort_t* __restrict__ kv,
    const float* __restrict__ nullkv, const float* __restrict__ nullbias,
    const float* __restrict__ table, ushort_t* __restrict__ out)
{
    __shared__ float qs[16][512];
    __shared__ float ks[17][64];
    __shared__ float vs[17][64];
    __shared__ float sc[8][16][17];
    int b = blockIdx.x;
    int t = threadIdx.x;
    for (int e = t; e < 16 * 512; e += 256) {
        int f = e >> 9, c = e & 511;
        qs[f][c] = b2f(q[(size_t)(b * 16 + f) * 512 + c]);
    }
    for (int e = t; e < 17 * 64; e += 256) {
        int j = e >> 6, d = e & 63;
        ks[j][d] = (j == 0) ? nullkv[d]      : b2f(kv[(size_t)(b * 16 + j - 1) * 128 + d]);
        vs[j][d] = (j == 0) ? nullkv[64 + d] : b2f(kv[(size_t)(b * 16 + j - 1) * 128 + 64 + d]);
    }
    __syncthreads();
    for (int e = t; e < 8 * 16 * 17; e += 256) {
        int h = e / 272, rem = e - h * 272;
        int i = rem / 17, j = rem - i * 17;
        float acc = 0.f;
        for (int d = 0; d < 64; ++d) acc += qs[i][h * 64 + d] * ks[j][d];
        float bias = (j == 0) ? nullbias[h] : table[(i - (j - 1) + 15) * 8 + h];
        sc[h][i][j] = acc + bias;
    }
    __syncthreads();
    if (t < 128) {
        int h = t >> 4, i = t & 15;
        float mx = -1e30f;
        for (int j = 0; j < 17; ++j) mx = fmaxf(mx, sc[h][i][j]);
        float s = 0.f;
        for (int j = 0; j < 17; ++j) { float p = __expf(sc[h][i][j] - mx); sc[h][i][j] = p; s += p; }
        float inv = 1.f / s;
        for (int j = 0; j < 17; ++j) sc[h][i][j] *= inv;
    }
    __syncthreads();
    for (int e = t; e < 16 * 512; e += 256) {
        int i = e >> 9, c = e & 511;
        int h = c >> 6, d = c & 63;
        float acc = 0.f;
        #pragma unroll
        for (int j = 0; j < 17; ++j) acc += sc[h][i][j] * vs[j][d];
        out[(size_t)(b * 16 + i) * 512 + c] = f2b(acc);
    }
}

// ------------------------------------------------- FF shift-LN row statistics
__global__ __launch_bounds__(256) void rowstats_kernel(
    const float* __restrict__ Y, float* __restrict__ stats)
{
    __shared__ float r1[4], r2[4];
    int r = blockIdx.x, t = threadIdx.x;
    const float* rowa = Y + (size_t)r * YLD;
    const float* rowb = (r >> 10) ? (Y + (size_t)(r - 1024) * YLD) : nullptr;
    float s = 0.f, s2 = 0.f;
    for (int c = t; c < FFI; c += 256) {
        float v = (c < CH1) ? rowa[c] : (rowb ? rowb[c] : 0.f);
        s += v; s2 += v * v;
    }
    #pragma unroll
    for (int o = 32; o > 0; o >>= 1) { s += __shfl_down(s, o, 64); s2 += __shfl_down(s2, o, 64); }
    if ((t & 63) == 0) { r1[t >> 6] = s; r2[t >> 6] = s2; }
    __syncthreads();
    float S  = r1[0] + r1[1] + r1[2] + r1[3];
    float S2 = r2[0] + r2[1] + r2[2] + r2[3];
    float mean = S * (1.f / 1365.f);
    float var  = S2 * (1.f / 1365.f) - mean * mean;
    float rstd = rsqrtf(fmaxf(var, 1e-5f));
    if (t == 0) { stats[2 * r] = mean; stats[2 * r + 1] = rstd; }
}

// ================================================================ launcher
extern "C" void kernel_launch(void* const* d_in, const int* in_sizes, int n_in,
                              void* d_out, int out_size, void* d_ws, size_t ws_size,
                              hipStream_t stream)
{
    const float* x          = (const float*)d_in[0];
    const float* sa_ln_w    = (const float*)d_in[1];
    const float* sa_ln_b    = (const float*)d_in[2];
    const float* sa_wq      = (const float*)d_in[3];
    const float* sa_wkv     = (const float*)d_in[4];
    const float* sa_null_kv = (const float*)d_in[5];
    const float* sa_null_b  = (const float*)d_in[6];
    const float* sa_wout    = (const float*)d_in[7];
    const float* sa_oln_w   = (const float*)d_in[8];
    const float* sa_oln_b   = (const float*)d_in[9];
    const float* ta_ln_w    = (const float*)d_in[10];
    const float* ta_ln_b    = (const float*)d_in[11];
    const float* ta_wq      = (const float*)d_in[12];
    const float* ta_wkv     = (const float*)d_in[13];
    const float* ta_null_kv = (const float*)d_in[14];
    const float* ta_null_b  = (const float*)d_in[15];
    const float* ta_wout    = (const float*)d_in[16];
    const float* ta_oln_w   = (const float*)d_in[17];
    const float* ta_oln_b   = (const float*)d_in[18];
    const float* sp_w0      = (const float*)d_in[19];
    const float* sp_b0      = (const float*)d_in[20];
    const float* sp_w1      = (const float*)d_in[21];
    const float* sp_b1      = (const float*)d_in[22];
    const float* sp_w2      = (const float*)d_in[23];
    const float* sp_b2      = (const float*)d_in[24];
    const float* tp_w0      = (const float*)d_in[25];
    const float* tp_b0      = (const float*)d_in[26];
    const float* tp_w1      = (const float*)d_in[27];
    const float* tp_b1      = (const float*)d_in[28];
    const float* tp_w2      = (const float*)d_in[29];
    const float* tp_b2      = (const float*)d_in[30];
    const float* ff_win     = (const float*)d_in[31];
    const float* ff_g       = (const float*)d_in[32];
    const float* ff_wout    = (const float*)d_in[33];

    char* ws = (char*)d_ws;
    // regions (bytes)
    float*    RES   = (float*)(ws + 0);                        // 33,554,432
    ushort_t* XN16  = (ushort_t*)(ws + 33554432);              // 16,777,216 (xn sp / xn tp / x2 bf16)
    ushort_t* Q16   = (ushort_t*)(ws + 50331648);              // spatial Q bf16
    float*    RT    = (float*)(ws + 50331648);                 // temporal residual f32
    ushort_t* WSA   = (ushort_t*)(ws + 67108864);              // spatial weights
    ushort_t* KP    = (ushort_t*)(ws + 83886080);              // 16x1056x64 bf16
    ushort_t* VTb   = (ushort_t*)(ws + 86048768);              // 16x64x1056 bf16
    ushort_t* KV16  = (ushort_t*)(ws + 83886080);              // temporal KV bf16
    ushort_t* WTA   = (ushort_t*)(ws + 90439680);              // temporal weights
    ushort_t* AO16  = (ushort_t*)(ws + 92274688);              // attn out bf16
    ushort_t* BIAS16= (ushort_t*)(ws + 109051904);             // spatial bias bf16 (PRJ region)
    float*    PRJ   = (float*)(ws + 109051904);                // proj out f32
    ushort_t* Q16t  = (ushort_t*)(ws + 109051904);             // temporal Q bf16
    float*    YA    = (float*)(ws + 50331648);                 // FF act f32, stride YLD
    ushort_t* WFF   = (ushort_t*)(ws + 139984896);             // FF weights JIT
    float*    STATS = (float*)(ws + 142606336);
    float*    SPT   = (float*)(ws + 142737408);
    float*    TPT   = (float*)(ws + 142864448);

    ushort_t* WQ_T  = WSA;                 // [512][512]
    ushort_t* WKV_T = WSA + 262144;        // [128][512]
    ushort_t* WO_T  = WSA + 327680;        // [512][512]
    ushort_t* tWQ_T  = WTA;
    ushort_t* tWKV_T = WTA + 262144;
    ushort_t* tWO_T  = WTA + 327680;

    dim3 blk(256);

    // bias tables
    cpb_kernel<<<dim3(3969), blk, 0, stream>>>(sp_w0, sp_b0, sp_w1, sp_b1, sp_w2, sp_b2, SPT, 0);
    cpb_kernel<<<dim3(31),   blk, 0, stream>>>(tp_w0, tp_b0, tp_w1, tp_b1, tp_w2, tp_b2, TPT, 1);
    bias_sp_kernel<<<dim3(1024, 8), blk, 0, stream>>>(SPT, BIAS16);
    kvinit_kernel<<<dim3(16), blk, 0, stream>>>(sa_null_kv, KP, VTb);

    // ---------------- spatial ----------------
    wcvt_kernel<<<dim3(16, 16), blk, 0, stream>>>(sa_wq, 512, 0, WQ_T, 512, 512, 512);
    wcvt_kernel<<<dim3(4, 16),  blk, 0, stream>>>(sa_wkv, 128, 0, WKV_T, 512, 512, 128);
    wcvt_kernel<<<dim3(16, 16), blk, 0, stream>>>(sa_wout, 512, 0, WO_T, 512, 512, 512);
    transpose_in_kernel<<<dim3(512, 16), blk, 0, stream>>>(x, RES);
    ln_bf16_kernel<<<dim3(TOK), blk, 0, stream>>>(RES, XN16, sa_ln_w, sa_ln_b);
    gemm_mfma<0, 3><<<dim3(4, 128), blk, 0, stream>>>(XN16, nullptr, 512, WQ_T, 512,
        nullptr, Q16, 512, TOK, 512, 512, 512, 0.125f, nullptr, nullptr, nullptr, nullptr, nullptr, nullptr);
    gemm_mfma<0, 4><<<dim3(1, 128), blk, 0, stream>>>(XN16, nullptr, 512, WKV_T, 512,
        nullptr, nullptr, 0, TOK, 128, 512, 512, 1.0f, nullptr, nullptr, nullptr, nullptr, KP, VTb);
    attn_sp_mfma<<<dim3(64, 16), blk, 0, stream>>>(Q16, KP, VTb, BIAS16, sa_null_b, AO16);
    gemm_mfma<0, 0><<<dim3(4, 128), blk, 0, stream>>>(AO16, nullptr, 512, WO_T, 512,
        PRJ, nullptr, 512, TOK, 512, 512, 512, 1.0f, nullptr, nullptr, nullptr, nullptr, nullptr, nullptr);
    ln_add_kernel<<<dim3(TOK), blk, 0, stream>>>(PRJ, RES, sa_oln_w, sa_oln_b);

    // ---------------- temporal ----------------
    permute0_kernel<<<dim3(TOK), dim3(128), 0, stream>>>(RES, RT);
    wcvt_kernel<<<dim3(16, 16), blk, 0, stream>>>(ta_wq, 512, 0, tWQ_T, 512, 512, 512);
    wcvt_kernel<<<dim3(4, 16),  blk, 0, stream>>>(ta_wkv, 128, 0, tWKV_T, 512, 512, 128);
    wcvt_kernel<<<dim3(16, 16), blk, 0, stream>>>(ta_wout, 512, 0, tWO_T, 512, 512, 512);
    ln_bf16_kernel<<<dim3(TOK), blk, 0, stream>>>(RT, XN16, ta_ln_w, ta_ln_b);
    gemm_mfma<0, 3><<<dim3(4, 128), blk, 0, stream>>>(XN16, nullptr, 512, tWQ_T, 512,
        nullptr, Q16t, 512, TOK, 512, 512, 512, 0.125f, nullptr, nullptr, nullptr, nullptr, nullptr, nullptr);
    gemm_mfma<0, 3><<<dim3(1, 128), blk, 0, stream>>>(XN16, nullptr, 512, tWKV_T, 512,
        nullptr, KV16, 128, TOK, 128, 512, 512, 1.0f, nullptr, nullptr, nullptr, nullptr, nullptr, nullptr);
    attn_tp_kernel<<<dim3(1024), blk, 0, stream>>>(Q16t, KV16, ta_null_kv, ta_null_b, TPT, AO16);
    gemm_mfma<0, 0><<<dim3(4, 128), blk, 0, stream>>>(AO16, nullptr, 512, tWO_T, 512,
        PRJ, nullptr, 512, TOK, 512, 512, 512, 1.0f, nullptr, nullptr, nullptr, nullptr, nullptr, nullptr);
    ln_add_kernel<<<dim3(TOK), blk, 0, stream>>>(PRJ, RT, ta_oln_w, ta_oln_b);
    permute1_dual_kernel<<<dim3(TOK), dim3(128), 0, stream>>>(RT, RES, XN16);

    // ---------------- feed-forward ----------------
    wcvt_kernel<<<dim3(43, 16), blk, 0, stream>>>(ff_win, 2730, 0, WFF, 512, 512, FFI);
    gemm_mfma<0, 0><<<dim3(11, 128), blk, 0, stream>>>(XN16, nullptr, 512, WFF, 512,
        YA, nullptr, YLD, TOK, FFI, 512, 512, 1.0f, nullptr, nullptr, nullptr, nullptr, nullptr, nullptr);
    wcvt_kernel<<<dim3(43, 16), blk, 0, stream>>>(ff_win, 2730, FFI, WFF, 512, 512, FFI);
    gemm_mfma<0, 1><<<dim3(11, 128), blk, 0, stream>>>(XN16, nullptr, 512, WFF, 512,
        YA, nullptr, YLD, TOK, FFI, 512, 512, 1.0f, nullptr, nullptr, nullptr, nullptr, nullptr, nullptr);
    rowstats_kernel<<<dim3(TOK), blk, 0, stream>>>(YA, STATS);
    wcvt_kernel<<<dim3(16, 43), blk, 0, stream>>>(ff_wout, 512, 0, WFF, 1376, FFI, 512);
    gemm_mfma<1, 2><<<dim3(4, 128), blk, 0, stream>>>(nullptr, YA, YLD, WFF, 1376,
        nullptr, nullptr, 0, TOK, 512, 1376, FFI, 1.0f, STATS, ff_g, RES, (float*)d_out, nullptr, nullptr);
}

// Round 4
// 1148.080 us; speedup vs baseline: 4.4822x; 1.2120x over previous
//
#include <hip/hip_runtime.h>
#include <math.h>

#define TOK 16384
#define DIMC 512
#define FFI 1365
#define CH1 683
#define YLD 1368          // YA row stride (floats, 16B aligned)
#define KVPAD 1056        // padded key count for spatial attn (mult of 8)
#define BSTRIDE 1152      // BIASX row stride (cols: 0=null, 1..1024=keys, rest=-1e38)

typedef unsigned int u32;
typedef unsigned short ushort_t;
typedef __attribute__((ext_vector_type(8))) short bf16x8;
typedef __attribute__((ext_vector_type(4))) float f32x4;

__device__ inline ushort_t f2b(float x) {
    u32 u = __float_as_uint(x);
    u32 r = (u + 0x7fffu + ((u >> 16) & 1u)) >> 16;
    return (ushort_t)r;
}
__device__ inline float b2f(ushort_t u) { return __uint_as_float(((u32)u) << 16); }

__device__ inline void gload_lds16(const void* g, void* l) {
    __builtin_amdgcn_global_load_lds(
        (const __attribute__((address_space(1))) u32*)g,
        (__attribute__((address_space(3))) u32*)l, 16, 0, 0);
}

__device__ inline float gelu_exact(float x) {
    return 0.5f * x * (1.f + erff(x * 0.70710678118654752f));
}

// ---------------------------------------------------------------- CPB MLP
__global__ __launch_bounds__(256) void cpb_kernel(
    const float* __restrict__ w0, const float* __restrict__ b0,
    const float* __restrict__ w1, const float* __restrict__ b1,
    const float* __restrict__ w2, const float* __restrict__ b2,
    float* __restrict__ table, int mode)
{
    __shared__ float t0[256];
    __shared__ float t1[256];
    int r = blockIdx.x;
    int t = threadIdx.x;
    float c0, c1;
    if (mode == 0) { c0 = (float)(r / 63 - 31); c1 = (float)(r % 63 - 31); }
    else           { c0 = (float)(r - 15);      c1 = 0.f; }
    float a = c0 * w0[t] + b0[t];
    if (mode == 0) a += c1 * w0[256 + t];
    t0[t] = a / (1.f + __expf(-a));
    __syncthreads();
    float s = b1[t];
    for (int k = 0; k < 256; ++k) s += t0[k] * w1[k * 256 + t];
    t1[t] = s / (1.f + __expf(-s));
    __syncthreads();
    if (t < 8) {
        float o = b2[t];
        for (int k = 0; k < 256; ++k) o += t1[k] * w2[k * 8 + t];
        table[r * 8 + t] = o;
    }
}

// ------------------------------- materialize spatial bias bf16, padded layout
// BIASX[h][pi][c]: c=0 -> nullbias[h]; 1..1024 -> table; 1025..1151 -> -1e38
__global__ __launch_bounds__(256) void bias_sp_kernel(
    const float* __restrict__ tab, const float* __restrict__ nullbias,
    ushort_t* __restrict__ out)
{
    int pi = blockIdx.x, h = blockIdx.y;
    int phi = pi >> 5, pwi = pi & 31;
    ushort_t* row = out + ((size_t)h * 1024 + pi) * BSTRIDE;
    for (int c = threadIdx.x; c < BSTRIDE; c += 256) {
        float v;
        if (c == 0) v = nullbias[h];
        else if (c <= 1024) {
            int pj = c - 1;
            int phj = pj >> 5, pwj = pj & 31;
            int idx = (phi - phj + 31) * 63 + (pwi - pwj + 31);
            v = tab[idx * 8 + h];
        } else v = -1e38f;
        row[c] = f2b(v);
    }
}

// -------------------------------------------- KP/VT pad+null init. grid 16
__global__ __launch_bounds__(256) void kvinit_kernel(
    const float* __restrict__ nullkv, ushort_t* __restrict__ KP, ushort_t* __restrict__ VT)
{
    int f = blockIdx.x, t = threadIdx.x;
    for (int e = t; e < 32 * 64; e += 256) {
        int rr = e >> 6, d = e & 63;
        int row = (rr == 0) ? 0 : (1024 + rr);
        KP[((size_t)f * KVPAD + row) * 64 + d] = (rr == 0) ? f2b(nullkv[d]) : (ushort_t)0;
    }
    for (int e = t; e < 64 * 32; e += 256) {
        int d = e >> 5, cc = e & 31;
        int col = (cc == 0) ? 0 : (1024 + cc);
        VT[((size_t)f * 64 + d) * KVPAD + col] = (cc == 0) ? f2b(nullkv[64 + d]) : (ushort_t)0;
    }
}

// ------------------------------------- weight convert: W[K][ldw] -> Bt[N][Kp] bf16
__global__ __launch_bounds__(256) void wcvt_kernel(
    const float* __restrict__ W, int ldw, int c0,
    ushort_t* __restrict__ Bt, int Kp, int K, int Ncols)
{
    __shared__ float tile[32][33];
    int nb = blockIdx.x * 32, kb = blockIdx.y * 32;
    int tx = threadIdx.x & 31, ty = threadIdx.x >> 5;
    #pragma unroll
    for (int it = 0; it < 4; ++it) {
        int k = kb + ty + it * 8, n = nb + tx;
        tile[ty + it * 8][tx] = (k < K && n < Ncols) ? W[(size_t)k * ldw + c0 + n] : 0.f;
    }
    __syncthreads();
    #pragma unroll
    for (int it = 0; it < 4; ++it) {
        int n = nb + ty + it * 8, k = kb + tx;
        if (n < Ncols && k < Kp) Bt[(size_t)n * Kp + k] = f2b(tile[tx][ty + it * 8]);
    }
}

// ---------------------------------------------------- (C,T) -> (T,C) transpose
__global__ __launch_bounds__(256) void transpose_in_kernel(
    const float* __restrict__ x, float* __restrict__ dst)
{
    __shared__ float tile[32][33];
    int t0b = blockIdx.x * 32, c0b = blockIdx.y * 32;
    int tx = threadIdx.x & 31, ty = threadIdx.x >> 5;
    #pragma unroll
    for (int it = 0; it < 4; ++it) {
        int c = ty + it * 8;
        tile[c][tx] = x[(size_t)(c0b + c) * TOK + t0b + tx];
    }
    __syncthreads();
    #pragma unroll
    for (int it = 0; it < 4; ++it) {
        int tr = ty + it * 8;
        dst[(size_t)(t0b + tr) * DIMC + c0b + tx] = tile[tx][tr];
    }
}

// ---------------------------------------------------------------- LayerNorm → bf16
__global__ __launch_bounds__(256) void ln_bf16_kernel(
    const float* __restrict__ in, ushort_t* __restrict__ out,
    const float* __restrict__ w, const float* __restrict__ b)
{
    __shared__ float r1[4], r2[4];
    size_t base = (size_t)blockIdx.x * DIMC;
    int t = threadIdx.x;
    float x0 = in[base + t], x1 = in[base + 256 + t];
    float s = x0 + x1, s2 = x0 * x0 + x1 * x1;
    #pragma unroll
    for (int o = 32; o > 0; o >>= 1) { s += __shfl_down(s, o, 64); s2 += __shfl_down(s2, o, 64); }
    if ((t & 63) == 0) { r1[t >> 6] = s; r2[t >> 6] = s2; }
    __syncthreads();
    float mean = (r1[0] + r1[1] + r1[2] + r1[3]) * (1.f / 512.f);
    float ex2  = (r2[0] + r2[1] + r2[2] + r2[3]) * (1.f / 512.f);
    float rstd = rsqrtf(ex2 - mean * mean + 1e-5f);
    out[base + t]       = f2b((x0 - mean) * rstd * w[t] + b[t]);
    out[base + 256 + t] = f2b((x1 - mean) * rstd * w[256 + t] + b[256 + t]);
}

// LN(proj f32) + residual in place
__global__ __launch_bounds__(256) void ln_add_kernel(
    const float* __restrict__ proj, float* __restrict__ io,
    const float* __restrict__ w, const float* __restrict__ b)
{
    __shared__ float r1[4], r2[4];
    size_t base = (size_t)blockIdx.x * DIMC;
    int t = threadIdx.x;
    float x0 = proj[base + t], x1 = proj[base + 256 + t];
    float s = x0 + x1, s2 = x0 * x0 + x1 * x1;
    #pragma unroll
    for (int o = 32; o > 0; o >>= 1) { s += __shfl_down(s, o, 64); s2 += __shfl_down(s2, o, 64); }
    if ((t & 63) == 0) { r1[t >> 6] = s; r2[t >> 6] = s2; }
    __syncthreads();
    float mean = (r1[0] + r1[1] + r1[2] + r1[3]) * (1.f / 512.f);
    float ex2  = (r2[0] + r2[1] + r2[2] + r2[3]) * (1.f / 512.f);
    float rstd = rsqrtf(ex2 - mean * mean + 1e-5f);
    io[base + t]       += (x0 - mean) * rstd * w[t] + b[t];
    io[base + 256 + t] += (x1 - mean) * rstd * w[256 + t] + b[256 + t];
}

// spatial->temporal row permute (f32)
__global__ __launch_bounds__(128) void permute0_kernel(
    const float* __restrict__ src, float* __restrict__ dst)
{
    int rd = blockIdx.x;
    int rs = (rd & 15) * 1024 + (rd >> 4);
    ((float4*)(dst + (size_t)rd * DIMC))[threadIdx.x] =
        ((const float4*)(src + (size_t)rs * DIMC))[threadIdx.x];
}

// temporal->spatial permute, dual output f32 + bf16
__global__ __launch_bounds__(128) void permute1_dual_kernel(
    const float* __restrict__ src, float* __restrict__ dst, ushort_t* __restrict__ dstb)
{
    int rd = blockIdx.x;
    int rs = (rd & 1023) * 16 + (rd >> 10);
    float4 v = ((const float4*)(src + (size_t)rs * DIMC))[threadIdx.x];
    ((float4*)(dst + (size_t)rd * DIMC))[threadIdx.x] = v;
    u32 lo = (u32)f2b(v.x) | ((u32)f2b(v.y) << 16);
    u32 hi = (u32)f2b(v.z) | ((u32)f2b(v.w) << 16);
    ((uint2*)(dstb + (size_t)rd * DIMC))[threadIdx.x] = make_uint2(lo, hi);
}

// ---------------------------------------------------------------- MFMA GEMM
template<int AMODE, int EPI>
__global__ __launch_bounds__(256) void gemm_mfma(
    const ushort_t* __restrict__ A, const float* __restrict__ Af, int lda,
    const ushort_t* __restrict__ Bt, int Kp,
    float* __restrict__ C, ushort_t* __restrict__ Cb, int ldc,
    int M, int N, int K, int Kreal, float scale,
    const float* __restrict__ stats, const float* __restrict__ g,
    const float* __restrict__ resid, float* __restrict__ outT,
    ushort_t* __restrict__ KPo, ushort_t* __restrict__ VTo)
{
    __shared__ __align__(16) ushort_t As[4 * 128 * 8];
    __shared__ __align__(16) ushort_t Bs[4 * 128 * 8];
    int m0 = blockIdx.y * 128, n0 = blockIdx.x * 128;
    int tid = threadIdx.x, lane = tid & 63, wid = tid >> 6;
    int wy = wid >> 1, wx = wid & 1, quad = lane >> 4, l16 = lane & 15;
    bool bfull = (n0 + 128 <= N);
    f32x4 acc[4][4];
    #pragma unroll
    for (int i = 0; i < 4; ++i)
        #pragma unroll
        for (int j = 0; j < 4; ++j) { acc[i][j][0]=0.f; acc[i][j][1]=0.f; acc[i][j][2]=0.f; acc[i][j][3]=0.f; }

    for (int k0 = 0; k0 < K; k0 += 32) {
        if (k0) __syncthreads();
        if (AMODE == 0) {
            #pragma unroll
            for (int r = 0; r < 2; ++r) {
                int c = wid * 128 + r * 64 + lane;
                const ushort_t* src = A + (size_t)(m0 + (c & 127)) * lda + k0 + (c >> 7) * 8;
                gload_lds16(src, &As[(wid * 128 + r * 64) * 8]);
            }
        } else {
            #pragma unroll
            for (int r = 0; r < 2; ++r) {
                int c = tid + r * 256;
                int kg = c >> 7, mloc = c & 127, m = m0 + mloc;
                float mean = stats[2 * m], rstd = stats[2 * m + 1];
                bf16x8 tv;
                #pragma unroll
                for (int e = 0; e < 8; ++e) {
                    int k = k0 + kg * 8 + e;
                    float v = 0.f;
                    if (k < Kreal) {
                        int ms = (k >= CH1) ? ((m >> 10) ? m - 1024 : -1) : m;
                        float raw = (ms < 0) ? 0.f : Af[(size_t)ms * lda + k];
                        v = (raw - mean) * rstd * g[k];
                    }
                    tv[e] = (short)f2b(v);
                }
                *(bf16x8*)&As[c * 8] = tv;
            }
        }
        if (bfull) {
            #pragma unroll
            for (int r = 0; r < 2; ++r) {
                int c = wid * 128 + r * 64 + lane;
                const ushort_t* src = Bt + (size_t)(n0 + (c & 127)) * Kp + k0 + (c >> 7) * 8;
                gload_lds16(src, &Bs[(wid * 128 + r * 64) * 8]);
            }
        } else {
            #pragma unroll
            for (int r = 0; r < 2; ++r) {
                int c = tid + r * 256;
                int kg = c >> 7, nloc = c & 127;
                bf16x8 v;
                if (n0 + nloc < N) v = *(const bf16x8*)(Bt + (size_t)(n0 + nloc) * Kp + k0 + kg * 8);
                else { for (int e = 0; e < 8; ++e) v[e] = 0; }
                *(bf16x8*)&Bs[c * 8] = v;
            }
        }
        __syncthreads();
        bf16x8 af[4], bfr[4];
        #pragma unroll
        for (int i = 0; i < 4; ++i) af[i] = *(bf16x8*)&As[(quad * 128 + wy * 64 + i * 16 + l16) * 8];
        #pragma unroll
        for (int j = 0; j < 4; ++j) bfr[j] = *(bf16x8*)&Bs[(quad * 128 + wx * 64 + j * 16 + l16) * 8];
        #pragma unroll
        for (int i = 0; i < 4; ++i)
            #pragma unroll
            for (int j = 0; j < 4; ++j)
                acc[i][j] = __builtin_amdgcn_mfma_f32_16x16x32_bf16(af[i], bfr[j], acc[i][j], 0, 0, 0);
    }
    #pragma unroll
    for (int i = 0; i < 4; ++i) {
        #pragma unroll
        for (int j = 0; j < 4; ++j) {
            #pragma unroll
            for (int r = 0; r < 4; ++r) {
                int m = m0 + wy * 64 + i * 16 + quad * 4 + r;
                int n = n0 + wx * 64 + j * 16 + l16;
                if (n >= N) continue;
                float v = acc[i][j][r] * scale;
                if (EPI == 0) {
                    C[(size_t)m * ldc + n] = v;
                } else if (EPI == 1) {
                    size_t idx = (size_t)m * ldc + n;
                    C[idx] = C[idx] * gelu_exact(v);
                } else if (EPI == 2) {
                    outT[(size_t)n * TOK + m] = v + resid[(size_t)m * DIMC + n];
                } else if (EPI == 3) {
                    Cb[(size_t)m * ldc + n] = f2b(v);
                } else if (EPI == 4) {
                    int frame = m >> 10, tt = m & 1023;
                    if (n < 64) KPo[((size_t)frame * KVPAD + 1 + tt) * 64 + n] = f2b(v);
                    else        VTo[((size_t)frame * 64 + (n - 64)) * KVPAD + 1 + tt] = f2b(v);
                }
            }
        }
    }
}

// --------------------------------------------------- spatial attention (MFMA flash)
// grid (64 q-tiles of 16, 16 frames); block 256 = 4 waves; wave owns 2 whole heads.
// S^T = mfma(K, Q): rows = keys (quad*4+r), cols = q (l16). Softmax stats are
// per-column -> quad-only shuffles; bias loads 4 consecutive keys (8B); P packs
// to wave-private LDS via ds_write_b64 and reads back b128 in A-layout.
__global__ __launch_bounds__(256) void attn_sp_mfma(
    const ushort_t* __restrict__ Q,      // [16384][512] bf16 pre-scaled
    const ushort_t* __restrict__ KP,     // [16][1056][64]
    const ushort_t* __restrict__ VT,     // [16][64][1056]
    const ushort_t* __restrict__ BIASX,  // [8][1024][1152]
    ushort_t* __restrict__ O)            // [16384][512] bf16
{
    __shared__ __align__(16) ushort_t Ks[128 * 64];
    __shared__ __align__(16) ushort_t Vs[64 * 128];
    __shared__ __align__(16) ushort_t PT[4][16 * 136];   // per-wave, one head at a time
    int qt = blockIdx.x, frame = blockIdx.y;
    int q0 = qt * 16;
    int tid = threadIdx.x, lane = tid & 63, wid = tid >> 6;
    int quad = lane >> 4, l16 = lane & 15;
    ushort_t* PTw = &PT[wid][0];

    bf16x8 aQ[2][2];
    const ushort_t* brow[2];
    #pragma unroll
    for (int i = 0; i < 2; ++i) {
        int h = wid * 2 + i;
        const ushort_t* qp = Q + (size_t)(frame * 1024 + q0 + l16) * 512 + h * 64 + quad * 8;
        aQ[i][0] = *(const bf16x8*)qp;
        aQ[i][1] = *(const bf16x8*)(qp + 32);
        brow[i] = BIASX + ((size_t)h * 1024 + q0 + l16) * BSTRIDE;
    }
    f32x4 Oc[2][4];
    float mcol[2], lcol[2];
    #pragma unroll
    for (int i = 0; i < 2; ++i) {
        #pragma unroll
        for (int nt = 0; nt < 4; ++nt) { Oc[i][nt][0]=0.f; Oc[i][nt][1]=0.f; Oc[i][nt][2]=0.f; Oc[i][nt][3]=0.f; }
        mcol[i] = -3.0e38f; lcol[i] = 0.f;
    }

    for (int jt = 0; jt < 9; ++jt) {
        __syncthreads();
        // stage K: chunk(c,g') at c*8+g' holds K[c][(g'^(c&7))*8..]
        #pragma unroll
        for (int r = 0; r < 4; ++r) {
            int L = wid * 256 + r * 64 + lane;
            int c = L >> 3, gp = L & 7, gg = gp ^ (c & 7);
            int jj = jt * 128 + c; if (jj > KVPAD - 1) jj = KVPAD - 1;
            gload_lds16(KP + ((size_t)frame * KVPAD + jj) * 64 + gg * 8, &Ks[(wid * 256 + r * 64) * 8]);
        }
        // stage V: chunk(d,cg') holds VT[d][decode(cg')*8..]
        #pragma unroll
        for (int r = 0; r < 4; ++r) {
            int L = wid * 256 + r * 64 + lane;
            int d = L >> 4, cgp = L & 15;
            int cg = (cgp & 8) | ((cgp & 7) ^ (d & 7));
            int col = jt * 128 + cg * 8; if (col > KVPAD - 8) col = KVPAD - 8;
            gload_lds16(VT + ((size_t)frame * 64 + d) * KVPAD + col, &Vs[(wid * 256 + r * 64) * 8]);
        }
        __syncthreads();
        // S^T = K Q^T : rows = 128 keys, cols = 16 q, per 2 heads
        f32x4 S[2][8];
        #pragma unroll
        for (int i = 0; i < 2; ++i)
            #pragma unroll
            for (int j = 0; j < 8; ++j) { S[i][j][0]=0.f; S[i][j][1]=0.f; S[i][j][2]=0.f; S[i][j][3]=0.f; }
        #pragma unroll
        for (int j = 0; j < 8; ++j) {
            int c = j * 16 + l16;
            #pragma unroll
            for (int ks = 0; ks < 2; ++ks) {
                bf16x8 kb = *(bf16x8*)&Ks[(c * 8 + ((ks * 4 + quad) ^ (c & 7))) * 8];
                S[0][j] = __builtin_amdgcn_mfma_f32_16x16x32_bf16(kb, aQ[0][ks], S[0][j], 0, 0, 0);
                S[1][j] = __builtin_amdgcn_mfma_f32_16x16x32_bf16(kb, aQ[1][ks], S[1][j], 0, 0, 0);
            }
        }
        // bias: 4 consecutive keys per reg -> one 8B load per (head, j)
        #pragma unroll
        for (int i = 0; i < 2; ++i) {
            #pragma unroll
            for (int j = 0; j < 8; ++j) {
                int kbase = jt * 128 + j * 16 + quad * 4;
                uint2 bv = *(const uint2*)(brow[i] + kbase);
                S[i][j][0] += b2f((ushort_t)(bv.x & 0xffffu));
                S[i][j][1] += b2f((ushort_t)(bv.x >> 16));
                S[i][j][2] += b2f((ushort_t)(bv.y & 0xffffu));
                S[i][j][3] += b2f((ushort_t)(bv.y >> 16));
            }
        }
        // online softmax per column (q = l16); reduce over quads only
        float alpha[2];
        #pragma unroll
        for (int i = 0; i < 2; ++i) {
            float mx = S[i][0][0];
            #pragma unroll
            for (int j = 0; j < 8; ++j)
                #pragma unroll
                for (int r = 0; r < 4; ++r) mx = fmaxf(mx, S[i][j][r]);
            mx = fmaxf(mx, __shfl_xor(mx, 16, 64));
            mx = fmaxf(mx, __shfl_xor(mx, 32, 64));
            float mnew = fmaxf(mcol[i], mx);
            alpha[i] = __expf(mcol[i] - mnew);
            mcol[i] = mnew;
            float rs = 0.f;
            #pragma unroll
            for (int j = 0; j < 8; ++j)
                #pragma unroll
                for (int r = 0; r < 4; ++r) {
                    float p = __expf(S[i][j][r] - mnew);
                    S[i][j][r] = p;
                    rs += p;
                }
            rs += __shfl_xor(rs, 16, 64);
            rs += __shfl_xor(rs, 32, 64);
            lcol[i] = lcol[i] * alpha[i] + rs;
        }
        // rescale Oc: broadcast alpha from column-layout to row-layout
        #pragma unroll
        for (int i = 0; i < 2; ++i) {
            #pragma unroll
            for (int r = 0; r < 4; ++r) {
                float ar = __shfl(alpha[i], quad * 4 + r, 64);
                #pragma unroll
                for (int nt = 0; nt < 4; ++nt) Oc[i][nt][r] *= ar;
            }
        }
        // per head: P -> wave-private LDS (b64), read A-frags (b128), PV MFMA
        #pragma unroll
        for (int i = 0; i < 2; ++i) {
            #pragma unroll
            for (int j = 0; j < 8; ++j) {
                u32 u0 = __float_as_uint(S[i][j][0]) + 0x8000u;
                u32 u1 = __float_as_uint(S[i][j][1]) + 0x8000u;
                u32 u2 = __float_as_uint(S[i][j][2]) + 0x8000u;
                u32 u3 = __float_as_uint(S[i][j][3]) + 0x8000u;
                uint2 pk;
                pk.x = (u0 >> 16) | (u1 & 0xffff0000u);
                pk.y = (u2 >> 16) | (u3 & 0xffff0000u);
                *(uint2*)&PTw[l16 * 136 + j * 16 + quad * 4] = pk;
            }
            #pragma unroll
            for (int ks = 0; ks < 4; ++ks) {
                bf16x8 pa = *(bf16x8*)&PTw[l16 * 136 + ks * 32 + quad * 8];
                #pragma unroll
                for (int nt = 0; nt < 4; ++nt) {
                    int d = nt * 16 + l16;
                    int cg = ks * 4 + quad;
                    int phys = (cg & 8) | ((cg & 7) ^ (d & 7));
                    bf16x8 vb = *(bf16x8*)&Vs[(d * 16 + phys) * 8];
                    Oc[i][nt] = __builtin_amdgcn_mfma_f32_16x16x32_bf16(pa, vb, Oc[i][nt], 0, 0, 0);
                }
            }
        }
    }
    // epilogue: O / l, store bf16
    #pragma unroll
    for (int i = 0; i < 2; ++i) {
        int h = wid * 2 + i;
        #pragma unroll
        for (int r = 0; r < 4; ++r) {
            float linv = 1.f / __shfl(lcol[i], quad * 4 + r, 64);
            int ql = quad * 4 + r;
            #pragma unroll
            for (int nt = 0; nt < 4; ++nt) {
                int d = nt * 16 + l16;
                O[(size_t)(frame * 1024 + q0 + ql) * 512 + h * 64 + d] = f2b(Oc[i][nt][r] * linv);
            }
        }
    }
}

// ---------------------------------------------------------------- temporal attention
__global__ __launch_bounds__(256) void attn_tp_kernel(
    const ushort_t* __restrict__ q, const ushort_t* __restrict__ kv,
    const float* __restrict__ nullkv, const float* __restrict__ nullbias,
    const float* __restrict__ table, ushort_t* __restrict__ out)
{
    __shared__ float qs[16][512];
    __shared__ float ks[17][64];
    __shared__ float vs[17][64];
    __shared__ float sc[8][16][17];
    int b = blockIdx.x;
    int t = threadIdx.x;
    for (int e = t; e < 16 * 512; e += 256) {
        int f = e >> 9, c = e & 511;
        qs[f][c] = b2f(q[(size_t)(b * 16 + f) * 512 + c]);
    }
    for (int e = t; e < 17 * 64; e += 256) {
        int j = e >> 6, d = e & 63;
        ks[j][d] = (j == 0) ? nullkv[d]      : b2f(kv[(size_t)(b * 16 + j - 1) * 128 + d]);
        vs[j][d] = (j == 0) ? nullkv[64 + d] : b2f(kv[(size_t)(b * 16 + j - 1) * 128 + 64 + d]);
    }
    __syncthreads();
    for (int e = t; e < 8 * 16 * 17; e += 256) {
        int h = e / 272, rem = e - h * 272;
        int i = rem / 17, j = rem - i * 17;
        float acc = 0.f;
        for (int d = 0; d < 64; ++d) acc += qs[i][h * 64 + d] * ks[j][d];
        float bias = (j == 0) ? nullbias[h] : table[(i - (j - 1) + 15) * 8 + h];
        sc[h][i][j] = acc + bias;
    }
    __syncthreads();
    if (t < 128) {
        int h = t >> 4, i = t & 15;
        float mx = -1e30f;
        for (int j = 0; j < 17; ++j) mx = fmaxf(mx, sc[h][i][j]);
        float s = 0.f;
        for (int j = 0; j < 17; ++j) { float p = __expf(sc[h][i][j] - mx); sc[h][i][j] = p; s += p; }
        float inv = 1.f / s;
        for (int j = 0; j < 17; ++j) sc[h][i][j] *= inv;
    }
    __syncthreads();
    for (int e = t; e < 16 * 512; e += 256) {
        int i = e >> 9, c = e & 511;
        int h = c >> 6, d = c & 63;
        float acc = 0.f;
        #pragma unroll
        for (int j = 0; j < 17; ++j) acc += sc[h][i][j] * vs[j][d];
        out[(size_t)(b * 16 + i) * 512 + c] = f2b(acc);
    }
}

// ------------------------------------------------- FF shift-LN row statistics
__global__ __launch_bounds__(256) void rowstats_kernel(
    const float* __restrict__ Y, float* __restrict__ stats)
{
    __shared__ float r1[4], r2[4];
    int r = blockIdx.x, t = threadIdx.x;
    const float* rowa = Y + (size_t)r * YLD;
    const float* rowb = (r >> 10) ? (Y + (size_t)(r - 1024) * YLD) : nullptr;
    float s = 0.f, s2 = 0.f;
    for (int c = t; c < FFI; c += 256) {
        float v = (c < CH1) ? rowa[c] : (rowb ? rowb[c] : 0.f);
        s += v; s2 += v * v;
    }
    #pragma unroll
    for (int o = 32; o > 0; o >>= 1) { s += __shfl_down(s, o, 64); s2 += __shfl_down(s2, o, 64); }
    if ((t & 63) == 0) { r1[t >> 6] = s; r2[t >> 6] = s2; }
    __syncthreads();
    float S  = r1[0] + r1[1] + r1[2] + r1[3];
    float S2 = r2[0] + r2[1] + r2[2] + r2[3];
    float mean = S * (1.f / 1365.f);
    float var  = S2 * (1.f / 1365.f) - mean * mean;
    float rstd = rsqrtf(fmaxf(var, 1e-5f));
    if (t == 0) { stats[2 * r] = mean; stats[2 * r + 1] = rstd; }
}

// ================================================================ launcher
extern "C" void kernel_launch(void* const* d_in, const int* in_sizes, int n_in,
                              void* d_out, int out_size, void* d_ws, size_t ws_size,
                              hipStream_t stream)
{
    const float* x          = (const float*)d_in[0];
    const float* sa_ln_w    = (const float*)d_in[1];
    const float* sa_ln_b    = (const float*)d_in[2];
    const float* sa_wq      = (const float*)d_in[3];
    const float* sa_wkv     = (const float*)d_in[4];
    const float* sa_null_kv = (const float*)d_in[5];
    const float* sa_null_b  = (const float*)d_in[6];
    const float* sa_wout    = (const float*)d_in[7];
    const float* sa_oln_w   = (const float*)d_in[8];
    const float* sa_oln_b   = (const float*)d_in[9];
    const float* ta_ln_w    = (const float*)d_in[10];
    const float* ta_ln_b    = (const float*)d_in[11];
    const float* ta_wq      = (const float*)d_in[12];
    const float* ta_wkv     = (const float*)d_in[13];
    const float* ta_null_kv = (const float*)d_in[14];
    const float* ta_null_b  = (const float*)d_in[15];
    const float* ta_wout    = (const float*)d_in[16];
    const float* ta_oln_w   = (const float*)d_in[17];
    const float* ta_oln_b   = (const float*)d_in[18];
    const float* sp_w0      = (const float*)d_in[19];
    const float* sp_b0      = (const float*)d_in[20];
    const float* sp_w1      = (const float*)d_in[21];
    const float* sp_b1      = (const float*)d_in[22];
    const float* sp_w2      = (const float*)d_in[23];
    const float* sp_b2      = (const float*)d_in[24];
    const float* tp_w0      = (const float*)d_in[25];
    const float* tp_b0      = (const float*)d_in[26];
    const float* tp_w1      = (const float*)d_in[27];
    const float* tp_b1      = (const float*)d_in[28];
    const float* tp_w2      = (const float*)d_in[29];
    const float* tp_b2      = (const float*)d_in[30];
    const float* ff_win     = (const float*)d_in[31];
    const float* ff_g       = (const float*)d_in[32];
    const float* ff_wout    = (const float*)d_in[33];

    char* ws = (char*)d_ws;
    // regions (bytes)
    float*    RES   = (float*)(ws + 0);                        // 33,554,432
    ushort_t* XN16  = (ushort_t*)(ws + 33554432);              // 16,777,216
    ushort_t* Q16   = (ushort_t*)(ws + 50331648);              // spatial Q bf16
    float*    RT    = (float*)(ws + 50331648);                 // temporal residual f32
    ushort_t* WSA   = (ushort_t*)(ws + 67108864);              // spatial weights
    ushort_t* KP    = (ushort_t*)(ws + 83886080);              // 16x1056x64 bf16
    ushort_t* VTb   = (ushort_t*)(ws + 86048768);              // 16x64x1056 bf16
    ushort_t* KV16  = (ushort_t*)(ws + 83886080);              // temporal KV bf16
    ushort_t* WTA   = (ushort_t*)(ws + 90439680);              // temporal weights
    ushort_t* AO16  = (ushort_t*)(ws + 92274688);              // attn out bf16
    ushort_t* BIAS16= (ushort_t*)(ws + 109051904);             // spatial bias bf16 (PRJ region)
    float*    PRJ   = (float*)(ws + 109051904);                // proj out f32
    ushort_t* Q16t  = (ushort_t*)(ws + 109051904);             // temporal Q bf16
    float*    YA    = (float*)(ws + 50331648);                 // FF act f32, stride YLD
    ushort_t* WFF   = (ushort_t*)(ws + 139984896);             // FF weights JIT
    float*    STATS = (float*)(ws + 142606336);
    float*    SPT   = (float*)(ws + 142737408);
    float*    TPT   = (float*)(ws + 142864448);

    ushort_t* WQ_T  = WSA;                 // [512][512]
    ushort_t* WKV_T = WSA + 262144;        // [128][512]
    ushort_t* WO_T  = WSA + 327680;        // [512][512]
    ushort_t* tWQ_T  = WTA;
    ushort_t* tWKV_T = WTA + 262144;
    ushort_t* tWO_T  = WTA + 327680;

    dim3 blk(256);

    // bias tables
    cpb_kernel<<<dim3(3969), blk, 0, stream>>>(sp_w0, sp_b0, sp_w1, sp_b1, sp_w2, sp_b2, SPT, 0);
    cpb_kernel<<<dim3(31),   blk, 0, stream>>>(tp_w0, tp_b0, tp_w1, tp_b1, tp_w2, tp_b2, TPT, 1);
    bias_sp_kernel<<<dim3(1024, 8), blk, 0, stream>>>(SPT, sa_null_b, BIAS16);
    kvinit_kernel<<<dim3(16), blk, 0, stream>>>(sa_null_kv, KP, VTb);

    // ---------------- spatial ----------------
    wcvt_kernel<<<dim3(16, 16), blk, 0, stream>>>(sa_wq, 512, 0, WQ_T, 512, 512, 512);
    wcvt_kernel<<<dim3(4, 16),  blk, 0, stream>>>(sa_wkv, 128, 0, WKV_T, 512, 512, 128);
    wcvt_kernel<<<dim3(16, 16), blk, 0, stream>>>(sa_wout, 512, 0, WO_T, 512, 512, 512);
    transpose_in_kernel<<<dim3(512, 16), blk, 0, stream>>>(x, RES);
    ln_bf16_kernel<<<dim3(TOK), blk, 0, stream>>>(RES, XN16, sa_ln_w, sa_ln_b);
    gemm_mfma<0, 3><<<dim3(4, 128), blk, 0, stream>>>(XN16, nullptr, 512, WQ_T, 512,
        nullptr, Q16, 512, TOK, 512, 512, 512, 0.125f, nullptr, nullptr, nullptr, nullptr, nullptr, nullptr);
    gemm_mfma<0, 4><<<dim3(1, 128), blk, 0, stream>>>(XN16, nullptr, 512, WKV_T, 512,
        nullptr, nullptr, 0, TOK, 128, 512, 512, 1.0f, nullptr, nullptr, nullptr, nullptr, KP, VTb);
    attn_sp_mfma<<<dim3(64, 16), blk, 0, stream>>>(Q16, KP, VTb, BIAS16, AO16);
    gemm_mfma<0, 0><<<dim3(4, 128), blk, 0, stream>>>(AO16, nullptr, 512, WO_T, 512,
        PRJ, nullptr, 512, TOK, 512, 512, 512, 1.0f, nullptr, nullptr, nullptr, nullptr, nullptr, nullptr);
    ln_add_kernel<<<dim3(TOK), blk, 0, stream>>>(PRJ, RES, sa_oln_w, sa_oln_b);

    // ---------------- temporal ----------------
    permute0_kernel<<<dim3(TOK), dim3(128), 0, stream>>>(RES, RT);
    wcvt_kernel<<<dim3(16, 16), blk, 0, stream>>>(ta_wq, 512, 0, tWQ_T, 512, 512, 512);
    wcvt_kernel<<<dim3(4, 16),  blk, 0, stream>>>(ta_wkv, 128, 0, tWKV_T, 512, 512, 128);
    wcvt_kernel<<<dim3(16, 16), blk, 0, stream>>>(ta_wout, 512, 0, tWO_T, 512, 512, 512);
    ln_bf16_kernel<<<dim3(TOK), blk, 0, stream>>>(RT, XN16, ta_ln_w, ta_ln_b);
    gemm_mfma<0, 3><<<dim3(4, 128), blk, 0, stream>>>(XN16, nullptr, 512, tWQ_T, 512,
        nullptr, Q16t, 512, TOK, 512, 512, 512, 0.125f, nullptr, nullptr, nullptr, nullptr, nullptr, nullptr);
    gemm_mfma<0, 3><<<dim3(1, 128), blk, 0, stream>>>(XN16, nullptr, 512, tWKV_T, 512,
        nullptr, KV16, 128, TOK, 128, 512, 512, 1.0f, nullptr, nullptr, nullptr, nullptr, nullptr, nullptr);
    attn_tp_kernel<<<dim3(1024), blk, 0, stream>>>(Q16t, KV16, ta_null_kv, ta_null_b, TPT, AO16);
    gemm_mfma<0, 0><<<dim3(4, 128), blk, 0, stream>>>(AO16, nullptr, 512, tWO_T, 512,
        PRJ, nullptr, 512, TOK, 512, 512, 512, 1.0f, nullptr, nullptr, nullptr, nullptr, nullptr, nullptr);
    ln_add_kernel<<<dim3(TOK), blk, 0, stream>>>(PRJ, RT, ta_oln_w, ta_oln_b);
    permute1_dual_kernel<<<dim3(TOK), dim3(128), 0, stream>>>(RT, RES, XN16);

    // ---------------- feed-forward ----------------
    wcvt_kernel<<<dim3(43, 16), blk, 0, stream>>>(ff_win, 2730, 0, WFF, 512, 512, FFI);
    gemm_mfma<0, 0><<<dim3(11, 128), blk, 0, stream>>>(XN16, nullptr, 512, WFF, 512,
        YA, nullptr, YLD, TOK, FFI, 512, 512, 1.0f, nullptr, nullptr, nullptr, nullptr, nullptr, nullptr);
    wcvt_kernel<<<dim3(43, 16), blk, 0, stream>>>(ff_win, 2730, FFI, WFF, 512, 512, FFI);
    gemm_mfma<0, 1><<<dim3(11, 128), blk, 0, stream>>>(XN16, nullptr, 512, WFF, 512,
        YA, nullptr, YLD, TOK, FFI, 512, 512, 1.0f, nullptr, nullptr, nullptr, nullptr, nullptr, nullptr);
    rowstats_kernel<<<dim3(TOK), blk, 0, stream>>>(YA, STATS);
    wcvt_kernel<<<dim3(16, 43), blk, 0, stream>>>(ff_wout, 512, 0, WFF, 1376, FFI, 512);
    gemm_mfma<1, 2><<<dim3(4, 128), blk, 0, stream>>>(nullptr, YA, YLD, WFF, 1376,
        nullptr, nullptr, 0, TOK, 512, 1376, FFI, 1.0f, STATS, ff_g, RES, (float*)d_out, nullptr, nullptr);
}

// Round 6
// 1038.329 us; speedup vs baseline: 4.9560x; 1.1057x over previous
//
#include <hip/hip_runtime.h>
#include <math.h>

#define TOK 16384
#define DIMC 512
#define FFI 1365
#define CH1 683
#define YSLD 1376         // YS row stride (bf16 elements, 16B aligned)
#define KVPAD 1056        // padded key count for spatial attn (mult of 8)
#define BSTRIDE 1152      // BIASX row stride (cols: 0=null, 1..1024=keys, rest=mask)
#define MASKB (-30000.f)  // softmax mask bias (bf16-safe, no near-inf)

typedef unsigned int u32;
typedef unsigned short ushort_t;
typedef __attribute__((ext_vector_type(8))) short bf16x8;
typedef __attribute__((ext_vector_type(4))) float f32x4;

__device__ inline ushort_t f2b(float x) {
    u32 u = __float_as_uint(x);
    u32 r = (u + 0x7fffu + ((u >> 16) & 1u)) >> 16;
    return (ushort_t)r;
}
__device__ inline float b2f(ushort_t u) { return __uint_as_float(((u32)u) << 16); }

__device__ inline void gload_lds16(const void* g, void* l) {
    __builtin_amdgcn_global_load_lds(
        (const __attribute__((address_space(1))) u32*)g,
        (__attribute__((address_space(3))) u32*)l, 16, 0, 0);
}

__device__ inline float gelu_exact(float x) {
    return 0.5f * x * (1.f + erff(x * 0.70710678118654752f));
}

// ---------------------------------------------------------------- CPB MLP
__global__ __launch_bounds__(256) void cpb_kernel(
    const float* __restrict__ w0, const float* __restrict__ b0,
    const float* __restrict__ w1, const float* __restrict__ b1,
    const float* __restrict__ w2, const float* __restrict__ b2,
    float* __restrict__ table, int mode)
{
    __shared__ float t0[256];
    __shared__ float t1[256];
    int r = blockIdx.x;
    int t = threadIdx.x;
    float c0, c1;
    if (mode == 0) { c0 = (float)(r / 63 - 31); c1 = (float)(r % 63 - 31); }
    else           { c0 = (float)(r - 15);      c1 = 0.f; }
    float a = c0 * w0[t] + b0[t];
    if (mode == 0) a += c1 * w0[256 + t];
    t0[t] = a / (1.f + __expf(-a));
    __syncthreads();
    float s = b1[t];
    for (int k = 0; k < 256; ++k) s += t0[k] * w1[k * 256 + t];
    t1[t] = s / (1.f + __expf(-s));
    __syncthreads();
    if (t < 8) {
        float o = b2[t];
        for (int k = 0; k < 256; ++k) o += t1[k] * w2[k * 8 + t];
        table[r * 8 + t] = o;
    }
}

// ------------------------------- materialize spatial bias bf16, padded layout
__global__ __launch_bounds__(256) void bias_sp_kernel(
    const float* __restrict__ tab, const float* __restrict__ nullbias,
    ushort_t* __restrict__ out)
{
    int pi = blockIdx.x, h = blockIdx.y;
    int phi = pi >> 5, pwi = pi & 31;
    ushort_t* row = out + ((size_t)h * 1024 + pi) * BSTRIDE;
    for (int c = threadIdx.x; c < BSTRIDE; c += 256) {
        float v;
        if (c == 0) v = nullbias[h];
        else if (c <= 1024) {
            int pj = c - 1;
            int phj = pj >> 5, pwj = pj & 31;
            int idx = (phi - phj + 31) * 63 + (pwi - pwj + 31);
            v = tab[idx * 8 + h];
        } else v = MASKB;
        row[c] = f2b(v);
    }
}

// -------------------------------------------- KP/VT pad+null init. grid 16
__global__ __launch_bounds__(256) void kvinit_kernel(
    const float* __restrict__ nullkv, ushort_t* __restrict__ KP, ushort_t* __restrict__ VT)
{
    int f = blockIdx.x, t = threadIdx.x;
    for (int e = t; e < 32 * 64; e += 256) {
        int rr = e >> 6, d = e & 63;
        int row = (rr == 0) ? 0 : (1024 + rr);
        KP[((size_t)f * KVPAD + row) * 64 + d] = (rr == 0) ? f2b(nullkv[d]) : (ushort_t)0;
    }
    for (int e = t; e < 64 * 32; e += 256) {
        int d = e >> 5, cc = e & 31;
        int col = (cc == 0) ? 0 : (1024 + cc);
        VT[((size_t)f * 64 + d) * KVPAD + col] = (cc == 0) ? f2b(nullkv[64 + d]) : (ushort_t)0;
    }
}

// ---------------- weight convert: W[K][ldw] (col window c0) -> Bt[N][Kp] bf16
// optional gv: scale row k by gv[k] (folds ff_g into ff_wout)
__global__ __launch_bounds__(256) void wcvt_kernel(
    const float* __restrict__ W, int ldw, int c0,
    ushort_t* __restrict__ Bt, int Kp, int K, int Ncols,
    const float* __restrict__ gv)
{
    __shared__ float tile[32][33];
    int nb = blockIdx.x * 32, kb = blockIdx.y * 32;
    int tx = threadIdx.x & 31, ty = threadIdx.x >> 5;
    #pragma unroll
    for (int it = 0; it < 4; ++it) {
        int k = kb + ty + it * 8, n = nb + tx;
        float v = (k < K && n < Ncols) ? W[(size_t)k * ldw + c0 + n] : 0.f;
        if (gv && k < K) v *= gv[k];
        tile[ty + it * 8][tx] = v;
    }
    __syncthreads();
    #pragma unroll
    for (int it = 0; it < 4; ++it) {
        int n = nb + ty + it * 8, k = kb + tx;
        if (n < Ncols && k < Kp) Bt[(size_t)n * Kp + k] = f2b(tile[tx][ty + it * 8]);
    }
}

// ---------------------------------------------------- (C,T) -> (T,C) transpose
__global__ __launch_bounds__(256) void transpose_in_kernel(
    const float* __restrict__ x, float* __restrict__ dst)
{
    __shared__ float tile[32][33];
    int t0b = blockIdx.x * 32, c0b = blockIdx.y * 32;
    int tx = threadIdx.x & 31, ty = threadIdx.x >> 5;
    #pragma unroll
    for (int it = 0; it < 4; ++it) {
        int c = ty + it * 8;
        tile[c][tx] = x[(size_t)(c0b + c) * TOK + t0b + tx];
    }
    __syncthreads();
    #pragma unroll
    for (int it = 0; it < 4; ++it) {
        int tr = ty + it * 8;
        dst[(size_t)(t0b + tr) * DIMC + c0b + tx] = tile[tx][tr];
    }
}

// ---------------------------------------------------------------- LayerNorm → bf16
__global__ __launch_bounds__(256) void ln_bf16_kernel(
    const float* __restrict__ in, ushort_t* __restrict__ out,
    const float* __restrict__ w, const float* __restrict__ b)
{
    __shared__ float r1[4], r2[4];
    size_t base = (size_t)blockIdx.x * DIMC;
    int t = threadIdx.x;
    float x0 = in[base + t], x1 = in[base + 256 + t];
    float s = x0 + x1, s2 = x0 * x0 + x1 * x1;
    #pragma unroll
    for (int o = 32; o > 0; o >>= 1) { s += __shfl_down(s, o, 64); s2 += __shfl_down(s2, o, 64); }
    if ((t & 63) == 0) { r1[t >> 6] = s; r2[t >> 6] = s2; }
    __syncthreads();
    float mean = (r1[0] + r1[1] + r1[2] + r1[3]) * (1.f / 512.f);
    float ex2  = (r2[0] + r2[1] + r2[2] + r2[3]) * (1.f / 512.f);
    float rstd = rsqrtf(ex2 - mean * mean + 1e-5f);
    out[base + t]       = f2b((x0 - mean) * rstd * w[t] + b[t]);
    out[base + 256 + t] = f2b((x1 - mean) * rstd * w[256 + t] + b[256 + t]);
}

// LN(proj f32) + residual in place
__global__ __launch_bounds__(256) void ln_add_kernel(
    const float* __restrict__ proj, float* __restrict__ io,
    const float* __restrict__ w, const float* __restrict__ b)
{
    __shared__ float r1[4], r2[4];
    size_t base = (size_t)blockIdx.x * DIMC;
    int t = threadIdx.x;
    float x0 = proj[base + t], x1 = proj[base + 256 + t];
    float s = x0 + x1, s2 = x0 * x0 + x1 * x1;
    #pragma unroll
    for (int o = 32; o > 0; o >>= 1) { s += __shfl_down(s, o, 64); s2 += __shfl_down(s2, o, 64); }
    if ((t & 63) == 0) { r1[t >> 6] = s; r2[t >> 6] = s2; }
    __syncthreads();
    float mean = (r1[0] + r1[1] + r1[2] + r1[3]) * (1.f / 512.f);
    float ex2  = (r2[0] + r2[1] + r2[2] + r2[3]) * (1.f / 512.f);
    float rstd = rsqrtf(ex2 - mean * mean + 1e-5f);
    io[base + t]       += (x0 - mean) * rstd * w[t] + b[t];
    io[base + 256 + t] += (x1 - mean) * rstd * w[256 + t] + b[256 + t];
}

// spatial->temporal row permute (f32)
__global__ __launch_bounds__(128) void permute0_kernel(
    const float* __restrict__ src, float* __restrict__ dst)
{
    int rd = blockIdx.x;
    int rs = (rd & 15) * 1024 + (rd >> 4);
    ((float4*)(dst + (size_t)rd * DIMC))[threadIdx.x] =
        ((const float4*)(src + (size_t)rs * DIMC))[threadIdx.x];
}

// temporal->spatial permute, dual output f32 + bf16
__global__ __launch_bounds__(128) void permute1_dual_kernel(
    const float* __restrict__ src, float* __restrict__ dst, ushort_t* __restrict__ dstb)
{
    int rd = blockIdx.x;
    int rs = (rd & 1023) * 16 + (rd >> 10);
    float4 v = ((const float4*)(src + (size_t)rs * DIMC))[threadIdx.x];
    ((float4*)(dst + (size_t)rd * DIMC))[threadIdx.x] = v;
    u32 lo = (u32)f2b(v.x) | ((u32)f2b(v.y) << 16);
    u32 hi = (u32)f2b(v.z) | ((u32)f2b(v.w) << 16);
    ((uint2*)(dstb + (size_t)rd * DIMC))[threadIdx.x] = make_uint2(lo, hi);
}

// ---------------------------------------------------------------- MFMA GEMM
// EPI 0: C f32 = acc*scale. EPI 3: Cb bf16 = acc*scale.
// EPI 4: spatial KV scatter. EPI 5: final FF epilogue:
//        outT[n*TOK+m] = acc*s1 - s0*colsum[n] + resid[m*512+n]
template<int EPI>
__global__ __launch_bounds__(256) void gemm_mfma(
    const ushort_t* __restrict__ A, int lda,
    const ushort_t* __restrict__ Bt, int Kp,
    float* __restrict__ C, ushort_t* __restrict__ Cb, int ldc,
    int M, int N, int K, float scale,
    const float* __restrict__ stats, const float* __restrict__ g,
    const float* __restrict__ resid, float* __restrict__ outT,
    ushort_t* __restrict__ KPo, ushort_t* __restrict__ VTo)
{
    __shared__ __align__(16) ushort_t As[4 * 128 * 8];
    __shared__ __align__(16) ushort_t Bs[4 * 128 * 8];
    int m0 = blockIdx.y * 128, n0 = blockIdx.x * 128;
    int tid = threadIdx.x, lane = tid & 63, wid = tid >> 6;
    int wy = wid >> 1, wx = wid & 1, quad = lane >> 4, l16 = lane & 15;
    bool bfull = (n0 + 128 <= N);
    f32x4 acc[4][4];
    #pragma unroll
    for (int i = 0; i < 4; ++i)
        #pragma unroll
        for (int j = 0; j < 4; ++j) { acc[i][j][0]=0.f; acc[i][j][1]=0.f; acc[i][j][2]=0.f; acc[i][j][3]=0.f; }

    for (int k0 = 0; k0 < K; k0 += 32) {
        if (k0) __syncthreads();
        #pragma unroll
        for (int r = 0; r < 2; ++r) {
            int c = wid * 128 + r * 64 + lane;
            const ushort_t* src = A + (size_t)(m0 + (c & 127)) * lda + k0 + (c >> 7) * 8;
            gload_lds16(src, &As[(wid * 128 + r * 64) * 8]);
        }
        if (bfull) {
            #pragma unroll
            for (int r = 0; r < 2; ++r) {
                int c = wid * 128 + r * 64 + lane;
                const ushort_t* src = Bt + (size_t)(n0 + (c & 127)) * Kp + k0 + (c >> 7) * 8;
                gload_lds16(src, &Bs[(wid * 128 + r * 64) * 8]);
            }
        } else {
            #pragma unroll
            for (int r = 0; r < 2; ++r) {
                int c = tid + r * 256;
                int kg = c >> 7, nloc = c & 127;
                bf16x8 v;
                if (n0 + nloc < N) v = *(const bf16x8*)(Bt + (size_t)(n0 + nloc) * Kp + k0 + kg * 8);
                else { for (int e = 0; e < 8; ++e) v[e] = 0; }
                *(bf16x8*)&Bs[c * 8] = v;
            }
        }
        __syncthreads();
        bf16x8 af[4], bfr[4];
        #pragma unroll
        for (int i = 0; i < 4; ++i) af[i] = *(bf16x8*)&As[(quad * 128 + wy * 64 + i * 16 + l16) * 8];
        #pragma unroll
        for (int j = 0; j < 4; ++j) bfr[j] = *(bf16x8*)&Bs[(quad * 128 + wx * 64 + j * 16 + l16) * 8];
        #pragma unroll
        for (int i = 0; i < 4; ++i)
            #pragma unroll
            for (int j = 0; j < 4; ++j)
                acc[i][j] = __builtin_amdgcn_mfma_f32_16x16x32_bf16(af[i], bfr[j], acc[i][j], 0, 0, 0);
    }
    #pragma unroll
    for (int i = 0; i < 4; ++i) {
        #pragma unroll
        for (int j = 0; j < 4; ++j) {
            #pragma unroll
            for (int r = 0; r < 4; ++r) {
                int m = m0 + wy * 64 + i * 16 + quad * 4 + r;
                int n = n0 + wx * 64 + j * 16 + l16;
                if (n >= N) continue;
                float v = acc[i][j][r] * scale;
                if (EPI == 0) {
                    C[(size_t)m * ldc + n] = v;
                } else if (EPI == 3) {
                    Cb[(size_t)m * ldc + n] = f2b(v);
                } else if (EPI == 4) {
                    int frame = m >> 10, tt = m & 1023;
                    if (n < 64) KPo[((size_t)frame * KVPAD + 1 + tt) * 64 + n] = f2b(v);
                    else        VTo[((size_t)frame * 64 + (n - 64)) * KVPAD + 1 + tt] = f2b(v);
                } else if (EPI == 5) {
                    float s0 = stats[2 * m], s1 = stats[2 * m + 1];
                    outT[(size_t)n * TOK + m] = v * s1 - s0 * g[n] + resid[(size_t)m * DIMC + n];
                }
            }
        }
    }
}

// ------------------------------------------- fused FF front GEMM (a & gate)
// A[16384][512] bf16, Ba/Bg = W^T halves [1365][512] bf16.
// YS[dr][n] = bf16( a * gelu(gate) ) with temporal shift at store:
//   n<683 -> dr=m ; n>=683 -> dr=m+1024 (drop dr>=16384); zero YS[m<1024][n>=683];
//   zero pad cols n in [FFI, YSLD).
// B staged via register loads + ds_write (conservative); A via global_load_lds.
__global__ __launch_bounds__(256) void ff_gemm_fused(
    const ushort_t* __restrict__ A,
    const ushort_t* __restrict__ Ba, const ushort_t* __restrict__ Bg,
    ushort_t* __restrict__ YS)
{
    __shared__ __align__(16) ushort_t As[4 * 128 * 8];
    __shared__ __align__(16) ushort_t Bsa[4 * 128 * 8];
    __shared__ __align__(16) ushort_t Bsg[4 * 128 * 8];
    int m0 = blockIdx.y * 128, n0 = blockIdx.x * 128;
    int tid = threadIdx.x, lane = tid & 63, wid = tid >> 6;
    int wy = wid >> 1, wx = wid & 1, quad = lane >> 4, l16 = lane & 15;
    f32x4 aA[4][4], aG[4][4];
    #pragma unroll
    for (int i = 0; i < 4; ++i)
        #pragma unroll
        for (int j = 0; j < 4; ++j) {
            aA[i][j][0]=0.f; aA[i][j][1]=0.f; aA[i][j][2]=0.f; aA[i][j][3]=0.f;
            aG[i][j][0]=0.f; aG[i][j][1]=0.f; aG[i][j][2]=0.f; aG[i][j][3]=0.f;
        }

    for (int k0 = 0; k0 < 512; k0 += 32) {
        if (k0) __syncthreads();
        #pragma unroll
        for (int r = 0; r < 2; ++r) {
            int c = wid * 128 + r * 64 + lane;
            gload_lds16(A + (size_t)(m0 + (c & 127)) * 512 + k0 + (c >> 7) * 8,
                        &As[(wid * 128 + r * 64) * 8]);
        }
        #pragma unroll
        for (int r = 0; r < 2; ++r) {
            int c = tid + r * 256;
            int nloc = c & 127;
            bf16x8 va, vg;
            if (n0 + nloc < FFI) {
                size_t off = (size_t)(n0 + nloc) * 512 + k0 + (c >> 7) * 8;
                va = *(const bf16x8*)(Ba + off);
                vg = *(const bf16x8*)(Bg + off);
            } else {
                #pragma unroll
                for (int e = 0; e < 8; ++e) { va[e] = 0; vg[e] = 0; }
            }
            *(bf16x8*)&Bsa[c * 8] = va;
            *(bf16x8*)&Bsg[c * 8] = vg;
        }
        __syncthreads();
        bf16x8 af[4], ba[4], bg[4];
        #pragma unroll
        for (int i = 0; i < 4; ++i) af[i] = *(bf16x8*)&As[(quad * 128 + wy * 64 + i * 16 + l16) * 8];
        #pragma unroll
        for (int j = 0; j < 4; ++j) {
            int idx = (quad * 128 + wx * 64 + j * 16 + l16) * 8;
            ba[j] = *(bf16x8*)&Bsa[idx];
            bg[j] = *(bf16x8*)&Bsg[idx];
        }
        #pragma unroll
        for (int i = 0; i < 4; ++i)
            #pragma unroll
            for (int j = 0; j < 4; ++j) {
                aA[i][j] = __builtin_amdgcn_mfma_f32_16x16x32_bf16(af[i], ba[j], aA[i][j], 0, 0, 0);
                aG[i][j] = __builtin_amdgcn_mfma_f32_16x16x32_bf16(af[i], bg[j], aG[i][j], 0, 0, 0);
            }
    }
    #pragma unroll
    for (int i = 0; i < 4; ++i) {
        #pragma unroll
        for (int j = 0; j < 4; ++j) {
            #pragma unroll
            for (int r = 0; r < 4; ++r) {
                int m = m0 + wy * 64 + i * 16 + quad * 4 + r;
                int n = n0 + wx * 64 + j * 16 + l16;
                if (n >= FFI) {
                    if (n < YSLD) YS[(size_t)m * YSLD + n] = 0;   // zero pad cols
                    continue;
                }
                float v = aA[i][j][r] * gelu_exact(aG[i][j][r]);
                int dr = (n < CH1) ? m : m + 1024;
                if (dr < TOK) YS[(size_t)dr * YSLD + n] = f2b(v);
                if (n >= CH1 && m < 1024) YS[(size_t)m * YSLD + n] = 0;
            }
        }
    }
}

// --------------------------------------------------- spatial attention (MFMA flash)
__global__ __launch_bounds__(256) void attn_sp_mfma(
    const ushort_t* __restrict__ Q,      // [16384][512] bf16 pre-scaled
    const ushort_t* __restrict__ KP,     // [16][1056][64]
    const ushort_t* __restrict__ VT,     // [16][64][1056]
    const ushort_t* __restrict__ BIASX,  // [8][1024][1152]
    ushort_t* __restrict__ O)            // [16384][512] bf16
{
    __shared__ __align__(16) ushort_t Ks[128 * 64];
    __shared__ __align__(16) ushort_t Vs[64 * 128];
    __shared__ __align__(16) ushort_t PT[4][16 * 136];
    int qt = blockIdx.x, frame = blockIdx.y;
    int q0 = qt * 16;
    int tid = threadIdx.x, lane = tid & 63, wid = tid >> 6;
    int quad = lane >> 4, l16 = lane & 15;
    ushort_t* PTw = &PT[wid][0];

    bf16x8 aQ[2][2];
    const ushort_t* brow[2];
    #pragma unroll
    for (int i = 0; i < 2; ++i) {
        int h = wid * 2 + i;
        const ushort_t* qp = Q + (size_t)(frame * 1024 + q0 + l16) * 512 + h * 64 + quad * 8;
        aQ[i][0] = *(const bf16x8*)qp;
        aQ[i][1] = *(const bf16x8*)(qp + 32);
        brow[i] = BIASX + ((size_t)h * 1024 + q0 + l16) * BSTRIDE;
    }
    f32x4 Oc[2][4];
    float mcol[2], lcol[2];
    #pragma unroll
    for (int i = 0; i < 2; ++i) {
        #pragma unroll
        for (int nt = 0; nt < 4; ++nt) { Oc[i][nt][0]=0.f; Oc[i][nt][1]=0.f; Oc[i][nt][2]=0.f; Oc[i][nt][3]=0.f; }
        mcol[i] = -1.0e30f; lcol[i] = 0.f;
    }

    for (int jt = 0; jt < 9; ++jt) {
        __syncthreads();
        #pragma unroll
        for (int r = 0; r < 4; ++r) {
            int L = wid * 256 + r * 64 + lane;
            int c = L >> 3, gp = L & 7, gg = gp ^ (c & 7);
            int jj = jt * 128 + c; if (jj > KVPAD - 1) jj = KVPAD - 1;
            gload_lds16(KP + ((size_t)frame * KVPAD + jj) * 64 + gg * 8, &Ks[(wid * 256 + r * 64) * 8]);
        }
        #pragma unroll
        for (int r = 0; r < 4; ++r) {
            int L = wid * 256 + r * 64 + lane;
            int d = L >> 4, cgp = L & 15;
            int cg = (cgp & 8) | ((cgp & 7) ^ (d & 7));
            int col = jt * 128 + cg * 8; if (col > KVPAD - 8) col = KVPAD - 8;
            gload_lds16(VT + ((size_t)frame * 64 + d) * KVPAD + col, &Vs[(wid * 256 + r * 64) * 8]);
        }
        __syncthreads();
        f32x4 S[2][8];
        #pragma unroll
        for (int i = 0; i < 2; ++i)
            #pragma unroll
            for (int j = 0; j < 8; ++j) { S[i][j][0]=0.f; S[i][j][1]=0.f; S[i][j][2]=0.f; S[i][j][3]=0.f; }
        #pragma unroll
        for (int j = 0; j < 8; ++j) {
            int c = j * 16 + l16;
            #pragma unroll
            for (int ks = 0; ks < 2; ++ks) {
                bf16x8 kb = *(bf16x8*)&Ks[(c * 8 + ((ks * 4 + quad) ^ (c & 7))) * 8];
                S[0][j] = __builtin_amdgcn_mfma_f32_16x16x32_bf16(kb, aQ[0][ks], S[0][j], 0, 0, 0);
                S[1][j] = __builtin_amdgcn_mfma_f32_16x16x32_bf16(kb, aQ[1][ks], S[1][j], 0, 0, 0);
            }
        }
        #pragma unroll
        for (int i = 0; i < 2; ++i) {
            #pragma unroll
            for (int j = 0; j < 8; ++j) {
                int kbase = jt * 128 + j * 16 + quad * 4;
                uint2 bv = *(const uint2*)(brow[i] + kbase);
                S[i][j][0] += b2f((ushort_t)(bv.x & 0xffffu));
                S[i][j][1] += b2f((ushort_t)(bv.x >> 16));
                S[i][j][2] += b2f((ushort_t)(bv.y & 0xffffu));
                S[i][j][3] += b2f((ushort_t)(bv.y >> 16));
            }
        }
        float alpha[2];
        #pragma unroll
        for (int i = 0; i < 2; ++i) {
            float mx = S[i][0][0];
            #pragma unroll
            for (int j = 0; j < 8; ++j)
                #pragma unroll
                for (int r = 0; r < 4; ++r) mx = fmaxf(mx, S[i][j][r]);
            mx = fmaxf(mx, __shfl_xor(mx, 16, 64));
            mx = fmaxf(mx, __shfl_xor(mx, 32, 64));
            float mnew = fmaxf(mcol[i], mx);
            alpha[i] = __expf(mcol[i] - mnew);
            mcol[i] = mnew;
            float rs = 0.f;
            #pragma unroll
            for (int j = 0; j < 8; ++j)
                #pragma unroll
                for (int r = 0; r < 4; ++r) {
                    float p = __expf(S[i][j][r] - mnew);
                    S[i][j][r] = p;
                    rs += p;
                }
            rs += __shfl_xor(rs, 16, 64);
            rs += __shfl_xor(rs, 32, 64);
            lcol[i] = lcol[i] * alpha[i] + rs;
        }
        #pragma unroll
        for (int i = 0; i < 2; ++i) {
            #pragma unroll
            for (int r = 0; r < 4; ++r) {
                float ar = __shfl(alpha[i], quad * 4 + r, 64);
                #pragma unroll
                for (int nt = 0; nt < 4; ++nt) Oc[i][nt][r] *= ar;
            }
        }
        #pragma unroll
        for (int i = 0; i < 2; ++i) {
            #pragma unroll
            for (int j = 0; j < 8; ++j) {
                u32 u0 = __float_as_uint(S[i][j][0]) + 0x8000u;
                u32 u1 = __float_as_uint(S[i][j][1]) + 0x8000u;
                u32 u2 = __float_as_uint(S[i][j][2]) + 0x8000u;
                u32 u3 = __float_as_uint(S[i][j][3]) + 0x8000u;
                uint2 pk;
                pk.x = (u0 >> 16) | (u1 & 0xffff0000u);
                pk.y = (u2 >> 16) | (u3 & 0xffff0000u);
                *(uint2*)&PTw[l16 * 136 + j * 16 + quad * 4] = pk;
            }
            #pragma unroll
            for (int ks = 0; ks < 4; ++ks) {
                bf16x8 pa = *(bf16x8*)&PTw[l16 * 136 + ks * 32 + quad * 8];
                #pragma unroll
                for (int nt = 0; nt < 4; ++nt) {
                    int d = nt * 16 + l16;
                    int cg = ks * 4 + quad;
                    int phys = (cg & 8) | ((cg & 7) ^ (d & 7));
                    bf16x8 vb = *(bf16x8*)&Vs[(d * 16 + phys) * 8];
                    Oc[i][nt] = __builtin_amdgcn_mfma_f32_16x16x32_bf16(pa, vb, Oc[i][nt], 0, 0, 0);
                }
            }
        }
    }
    #pragma unroll
    for (int i = 0; i < 2; ++i) {
        int h = wid * 2 + i;
        #pragma unroll
        for (int r = 0; r < 4; ++r) {
            float linv = 1.f / __shfl(lcol[i], quad * 4 + r, 64);
            int ql = quad * 4 + r;
            #pragma unroll
            for (int nt = 0; nt < 4; ++nt) {
                int d = nt * 16 + l16;
                O[(size_t)(frame * 1024 + q0 + ql) * 512 + h * 64 + d] = f2b(Oc[i][nt][r] * linv);
            }
        }
    }
}

// ---------------------------------------------------------------- temporal attention
__global__ __launch_bounds__(256) void attn_tp_kernel(
    const ushort_t* __restrict__ q, const ushort_t* __restrict__ kv,
    const float* __restrict__ nullkv, const float* __restrict__ nullbias,
    const float* __restrict__ table, ushort_t* __restrict__ out)
{
    __shared__ float qs[16][512];
    __shared__ float ks[17][64];
    __shared__ float vs[17][64];
    __shared__ float sc[8][16][17];
    int b = blockIdx.x;
    int t = threadIdx.x;
    for (int e = t; e < 16 * 512; e += 256) {
        int f = e >> 9, c = e & 511;
        qs[f][c] = b2f(q[(size_t)(b * 16 + f) * 512 + c]);
    }
    for (int e = t; e < 17 * 64; e += 256) {
        int j = e >> 6, d = e & 63;
        ks[j][d] = (j == 0) ? nullkv[d]      : b2f(kv[(size_t)(b * 16 + j - 1) * 128 + d]);
        vs[j][d] = (j == 0) ? nullkv[64 + d] : b2f(kv[(size_t)(b * 16 + j - 1) * 128 + 64 + d]);
    }
    __syncthreads();
    for (int e = t; e < 8 * 16 * 17; e += 256) {
        int h = e / 272, rem = e - h * 272;
        int i = rem / 17, j = rem - i * 17;
        float acc = 0.f;
        for (int d = 0; d < 64; ++d) acc += qs[i][h * 64 + d] * ks[j][d];
        float bias = (j == 0) ? nullbias[h] : table[(i - (j - 1) + 15) * 8 + h];
        sc[h][i][j] = acc + bias;
    }
    __syncthreads();
    if (t < 128) {
        int h = t >> 4, i = t & 15;
        float mx = -1e30f;
        for (int j = 0; j < 17; ++j) mx = fmaxf(mx, sc[h][i][j]);
        float s = 0.f;
        for (int j = 0; j < 17; ++j) { float p = __expf(sc[h][i][j] - mx); sc[h][i][j] = p; s += p; }
        float inv = 1.f / s;
        for (int j = 0; j < 17; ++j) sc[h][i][j] *= inv;
    }
    __syncthreads();
    for (int e = t; e < 16 * 512; e += 256) {
        int i = e >> 9, c = e & 511;
        int h = c >> 6, d = c & 63;
        float acc = 0.f;
        #pragma unroll
        for (int j = 0; j < 17; ++j) acc += sc[h][i][j] * vs[j][d];
        out[(size_t)(b * 16 + i) * 512 + c] = f2b(acc);
    }
}

// ------------------------- FF shift-LN row stats from bf16 YS: (mean*rstd, rstd)
__global__ __launch_bounds__(256) void rowstats_bf16_kernel(
    const ushort_t* __restrict__ YS, float* __restrict__ stats)
{
    __shared__ float r1[4], r2[4];
    int r = blockIdx.x, t = threadIdx.x;
    const ushort_t* row = YS + (size_t)r * YSLD;
    float s = 0.f, s2 = 0.f;
    for (int c = t; c < FFI; c += 256) {
        float v = b2f(row[c]);
        s += v; s2 += v * v;
    }
    #pragma unroll
    for (int o = 32; o > 0; o >>= 1) { s += __shfl_down(s, o, 64); s2 += __shfl_down(s2, o, 64); }
    if ((t & 63) == 0) { r1[t >> 6] = s; r2[t >> 6] = s2; }
    __syncthreads();
    float S  = r1[0] + r1[1] + r1[2] + r1[3];
    float S2 = r2[0] + r2[1] + r2[2] + r2[3];
    float mean = S * (1.f / 1365.f);
    float var  = S2 * (1.f / 1365.f) - mean * mean;
    float rstd = rsqrtf(fmaxf(var, 1e-5f));
    if (t == 0) { stats[2 * r] = mean * rstd; stats[2 * r + 1] = rstd; }
}

// --------------------- colsum[n] = sum_k W'[n][k]  (rows of converted W')
__global__ __launch_bounds__(64) void colsum_kernel(
    const ushort_t* __restrict__ Wt, float* __restrict__ colsum)
{
    int n = blockIdx.x, t = threadIdx.x;
    const ushort_t* row = Wt + (size_t)n * YSLD;
    float s = 0.f;
    for (int k = t; k < YSLD; k += 64) s += b2f(row[k]);
    #pragma unroll
    for (int o = 32; o > 0; o >>= 1) s += __shfl_down(s, o, 64);
    if (t == 0) colsum[n] = s;
}

// ================================================================ launcher
extern "C" void kernel_launch(void* const* d_in, const int* in_sizes, int n_in,
                              void* d_out, int out_size, void* d_ws, size_t ws_size,
                              hipStream_t stream)
{
    const float* x          = (const float*)d_in[0];
    const float* sa_ln_w    = (const float*)d_in[1];
    const float* sa_ln_b    = (const float*)d_in[2];
    const float* sa_wq      = (const float*)d_in[3];
    const float* sa_wkv     = (const float*)d_in[4];
    const float* sa_null_kv = (const float*)d_in[5];
    const float* sa_null_b  = (const float*)d_in[6];
    const float* sa_wout    = (const float*)d_in[7];
    const float* sa_oln_w   = (const float*)d_in[8];
    const float* sa_oln_b   = (const float*)d_in[9];
    const float* ta_ln_w    = (const float*)d_in[10];
    const float* ta_ln_b    = (const float*)d_in[11];
    const float* ta_wq      = (const float*)d_in[12];
    const float* ta_wkv     = (const float*)d_in[13];
    const float* ta_null_kv = (const float*)d_in[14];
    const float* ta_null_b  = (const float*)d_in[15];
    const float* ta_wout    = (const float*)d_in[16];
    const float* ta_oln_w   = (const float*)d_in[17];
    const float* ta_oln_b   = (const float*)d_in[18];
    const float* sp_w0      = (const float*)d_in[19];
    const float* sp_b0      = (const float*)d_in[20];
    const float* sp_w1      = (const float*)d_in[21];
    const float* sp_b1      = (const float*)d_in[22];
    const float* sp_w2      = (const float*)d_in[23];
    const float* sp_b2      = (const float*)d_in[24];
    const float* tp_w0      = (const float*)d_in[25];
    const float* tp_b0      = (const float*)d_in[26];
    const float* tp_w1      = (const float*)d_in[27];
    const float* tp_b1      = (const float*)d_in[28];
    const float* tp_w2      = (const float*)d_in[29];
    const float* tp_b2      = (const float*)d_in[30];
    const float* ff_win     = (const float*)d_in[31];
    const float* ff_g       = (const float*)d_in[32];
    const float* ff_wout    = (const float*)d_in[33];

    char* ws = (char*)d_ws;
    // regions (bytes)
    float*    RES   = (float*)(ws + 0);                        // 33,554,432 (residual, spatial layout)
    ushort_t* XN16  = (ushort_t*)(ws + 33554432);              // 16,777,216 (xn / x2 bf16)
    ushort_t* Q16   = (ushort_t*)(ws + 50331648);              // spatial Q bf16 (spatial phase)
    float*    RT    = (float*)(ws + 50331648);                 // temporal residual f32 (temporal phase)
    ushort_t* YS    = (ushort_t*)(ws + 50331648);              // FF shifted act bf16 [16384][1376] -> ends 95,420,416
    ushort_t* WSA   = (ushort_t*)(ws + 67108864);              // spatial weights (dead by FF)
    ushort_t* KP    = (ushort_t*)(ws + 83886080);              // 16x1056x64 bf16 (spatial)
    ushort_t* VTb   = (ushort_t*)(ws + 86048768);              // 16x64x1056 bf16 (spatial)
    ushort_t* KV16  = (ushort_t*)(ws + 83886080);              // temporal KV bf16
    ushort_t* WTA   = (ushort_t*)(ws + 90439680);              // temporal weights
    ushort_t* AO16  = (ushort_t*)(ws + 92274688);              // attn out bf16 (dead by FF)
    ushort_t* WFFG  = (ushort_t*)(ws + 96468992);              // FF gate weights (FF phase; dead AO16 zone) ends 97,866,752
    ushort_t* WFFB  = (ushort_t*)(ws + 97867776);              // W' = (ff_wout*g)^T [512][1376] ends 99,276,800
    ushort_t* BIAS16= (ushort_t*)(ws + 109051904);             // spatial bias bf16 (PRJ region)
    float*    PRJ   = (float*)(ws + 109051904);                // proj out f32
    ushort_t* Q16t  = (ushort_t*)(ws + 109051904);             // temporal Q bf16
    ushort_t* WFFA  = (ushort_t*)(ws + 139984896);             // FF a-weights bf16 (dead PRJ zone)
    float*    STATS = (float*)(ws + 142606336);                // 16384 x (mean*rstd, rstd)
    float*    SPT   = (float*)(ws + 142737408);                // spatial CPB table (spatial phase)
    float*    COLSUM= (float*)(ws + 142737408);                // colsum[512] (FF phase, dead SPT)
    float*    TPT   = (float*)(ws + 142864448);

    ushort_t* WQ_T  = WSA;                 // [512][512]
    ushort_t* WKV_T = WSA + 262144;        // [128][512]
    ushort_t* WO_T  = WSA + 327680;        // [512][512]
    ushort_t* tWQ_T  = WTA;
    ushort_t* tWKV_T = WTA + 262144;
    ushort_t* tWO_T  = WTA + 327680;

    dim3 blk(256);

    // bias tables
    cpb_kernel<<<dim3(3969), blk, 0, stream>>>(sp_w0, sp_b0, sp_w1, sp_b1, sp_w2, sp_b2, SPT, 0);
    cpb_kernel<<<dim3(31),   blk, 0, stream>>>(tp_w0, tp_b0, tp_w1, tp_b1, tp_w2, tp_b2, TPT, 1);
    bias_sp_kernel<<<dim3(1024, 8), blk, 0, stream>>>(SPT, sa_null_b, BIAS16);
    kvinit_kernel<<<dim3(16), blk, 0, stream>>>(sa_null_kv, KP, VTb);

    // ---------------- spatial ----------------
    wcvt_kernel<<<dim3(16, 16), blk, 0, stream>>>(sa_wq, 512, 0, WQ_T, 512, 512, 512, nullptr);
    wcvt_kernel<<<dim3(4, 16),  blk, 0, stream>>>(sa_wkv, 128, 0, WKV_T, 512, 512, 128, nullptr);
    wcvt_kernel<<<dim3(16, 16), blk, 0, stream>>>(sa_wout, 512, 0, WO_T, 512, 512, 512, nullptr);
    transpose_in_kernel<<<dim3(512, 16), blk, 0, stream>>>(x, RES);
    ln_bf16_kernel<<<dim3(TOK), blk, 0, stream>>>(RES, XN16, sa_ln_w, sa_ln_b);
    gemm_mfma<3><<<dim3(4, 128), blk, 0, stream>>>(XN16, 512, WQ_T, 512,
        nullptr, Q16, 512, TOK, 512, 512, 0.125f, nullptr, nullptr, nullptr, nullptr, nullptr, nullptr);
    gemm_mfma<4><<<dim3(1, 128), blk, 0, stream>>>(XN16, 512, WKV_T, 512,
        nullptr, nullptr, 0, TOK, 128, 512, 1.0f, nullptr, nullptr, nullptr, nullptr, KP, VTb);
    attn_sp_mfma<<<dim3(64, 16), blk, 0, stream>>>(Q16, KP, VTb, BIAS16, AO16);
    gemm_mfma<0><<<dim3(4, 128), blk, 0, stream>>>(AO16, 512, WO_T, 512,
        PRJ, nullptr, 512, TOK, 512, 512, 1.0f, nullptr, nullptr, nullptr, nullptr, nullptr, nullptr);
    ln_add_kernel<<<dim3(TOK), blk, 0, stream>>>(PRJ, RES, sa_oln_w, sa_oln_b);

    // ---------------- temporal ----------------
    permute0_kernel<<<dim3(TOK), dim3(128), 0, stream>>>(RES, RT);
    wcvt_kernel<<<dim3(16, 16), blk, 0, stream>>>(ta_wq, 512, 0, tWQ_T, 512, 512, 512, nullptr);
    wcvt_kernel<<<dim3(4, 16),  blk, 0, stream>>>(ta_wkv, 128, 0, tWKV_T, 512, 512, 128, nullptr);
    wcvt_kernel<<<dim3(16, 16), blk, 0, stream>>>(ta_wout, 512, 0, tWO_T, 512, 512, 512, nullptr);
    ln_bf16_kernel<<<dim3(TOK), blk, 0, stream>>>(RT, XN16, ta_ln_w, ta_ln_b);
    gemm_mfma<3><<<dim3(4, 128), blk, 0, stream>>>(XN16, 512, tWQ_T, 512,
        nullptr, Q16t, 512, TOK, 512, 512, 0.125f, nullptr, nullptr, nullptr, nullptr, nullptr, nullptr);
    gemm_mfma<3><<<dim3(1, 128), blk, 0, stream>>>(XN16, 512, tWKV_T, 512,
        nullptr, KV16, 128, TOK, 128, 512, 1.0f, nullptr, nullptr, nullptr, nullptr, nullptr, nullptr);
    attn_tp_kernel<<<dim3(1024), blk, 0, stream>>>(Q16t, KV16, ta_null_kv, ta_null_b, TPT, AO16);
    gemm_mfma<0><<<dim3(4, 128), blk, 0, stream>>>(AO16, 512, tWO_T, 512,
        PRJ, nullptr, 512, TOK, 512, 512, 1.0f, nullptr, nullptr, nullptr, nullptr, nullptr, nullptr);
    ln_add_kernel<<<dim3(TOK), blk, 0, stream>>>(PRJ, RT, ta_oln_w, ta_oln_b);
    permute1_dual_kernel<<<dim3(TOK), dim3(128), 0, stream>>>(RT, RES, XN16);

    // ---------------- feed-forward ----------------
    wcvt_kernel<<<dim3(43, 16), blk, 0, stream>>>(ff_win, 2730, 0,   WFFA, 512, 512, FFI, nullptr);
    wcvt_kernel<<<dim3(43, 16), blk, 0, stream>>>(ff_win, 2730, FFI, WFFG, 512, 512, FFI, nullptr);
    wcvt_kernel<<<dim3(16, 43), blk, 0, stream>>>(ff_wout, 512, 0, WFFB, YSLD, FFI, 512, ff_g);
    colsum_kernel<<<dim3(512), dim3(64), 0, stream>>>(WFFB, COLSUM);
    ff_gemm_fused<<<dim3(11, 128), blk, 0, stream>>>(XN16, WFFA, WFFG, YS);
    rowstats_bf16_kernel<<<dim3(TOK), blk, 0, stream>>>(YS, STATS);
    gemm_mfma<5><<<dim3(4, 128), blk, 0, stream>>>(YS, YSLD, WFFB, YSLD,
        nullptr, nullptr, 0, TOK, 512, YSLD, 1.0f, STATS, COLSUM, RES, (float*)d_out, nullptr, nullptr);
}

// Round 7
// 1012.773 us; speedup vs baseline: 5.0810x; 1.0252x over previous
//
#include <hip/hip_runtime.h>
#include <math.h>

#define TOK 16384
#define DIMC 512
#define FFI 1365
#define CH1 683
#define YSLD 1376         // YS row stride (bf16 elements, 16B aligned)
#define KVPAD 1056        // padded key count for spatial attn (mult of 8)
#define BSTRIDE 1152      // BIASX row stride (cols: 0=null, 1..1024=keys, rest=mask)
#define MASKB (-30000.f)  // softmax mask bias (bf16-safe, no near-inf)

typedef unsigned int u32;
typedef unsigned short ushort_t;
typedef __attribute__((ext_vector_type(8))) short bf16x8;
typedef __attribute__((ext_vector_type(4))) float f32x4;

__device__ inline ushort_t f2b(float x) {
    u32 u = __float_as_uint(x);
    u32 r = (u + 0x7fffu + ((u >> 16) & 1u)) >> 16;
    return (ushort_t)r;
}
__device__ inline float b2f(ushort_t u) { return __uint_as_float(((u32)u) << 16); }

__device__ inline void gload_lds16(const void* g, void* l) {
    __builtin_amdgcn_global_load_lds(
        (const __attribute__((address_space(1))) u32*)g,
        (__attribute__((address_space(3))) u32*)l, 16, 0, 0);
}

__device__ inline float gelu_exact(float x) {
    return 0.5f * x * (1.f + erff(x * 0.70710678118654752f));
}

// ---------------------------------------------------------------- CPB MLP
__global__ __launch_bounds__(256) void cpb_kernel(
    const float* __restrict__ w0, const float* __restrict__ b0,
    const float* __restrict__ w1, const float* __restrict__ b1,
    const float* __restrict__ w2, const float* __restrict__ b2,
    float* __restrict__ table, int mode)
{
    __shared__ float t0[256];
    __shared__ float t1[256];
    int r = blockIdx.x;
    int t = threadIdx.x;
    float c0, c1;
    if (mode == 0) { c0 = (float)(r / 63 - 31); c1 = (float)(r % 63 - 31); }
    else           { c0 = (float)(r - 15);      c1 = 0.f; }
    float a = c0 * w0[t] + b0[t];
    if (mode == 0) a += c1 * w0[256 + t];
    t0[t] = a / (1.f + __expf(-a));
    __syncthreads();
    float s = b1[t];
    for (int k = 0; k < 256; ++k) s += t0[k] * w1[k * 256 + t];
    t1[t] = s / (1.f + __expf(-s));
    __syncthreads();
    if (t < 8) {
        float o = b2[t];
        for (int k = 0; k < 256; ++k) o += t1[k] * w2[k * 8 + t];
        table[r * 8 + t] = o;
    }
}

// ------------------------------- materialize spatial bias bf16, padded layout
__global__ __launch_bounds__(256) void bias_sp_kernel(
    const float* __restrict__ tab, const float* __restrict__ nullbias,
    ushort_t* __restrict__ out)
{
    int pi = blockIdx.x, h = blockIdx.y;
    int phi = pi >> 5, pwi = pi & 31;
    ushort_t* row = out + ((size_t)h * 1024 + pi) * BSTRIDE;
    for (int c = threadIdx.x; c < BSTRIDE; c += 256) {
        float v;
        if (c == 0) v = nullbias[h];
        else if (c <= 1024) {
            int pj = c - 1;
            int phj = pj >> 5, pwj = pj & 31;
            int idx = (phi - phj + 31) * 63 + (pwi - pwj + 31);
            v = tab[idx * 8 + h];
        } else v = MASKB;
        row[c] = f2b(v);
    }
}

// -------------------------------------------- KP/VT pad+null init. grid 16
__global__ __launch_bounds__(256) void kvinit_kernel(
    const float* __restrict__ nullkv, ushort_t* __restrict__ KP, ushort_t* __restrict__ VT)
{
    int f = blockIdx.x, t = threadIdx.x;
    for (int e = t; e < 32 * 64; e += 256) {
        int rr = e >> 6, d = e & 63;
        int row = (rr == 0) ? 0 : (1024 + rr);
        KP[((size_t)f * KVPAD + row) * 64 + d] = (rr == 0) ? f2b(nullkv[d]) : (ushort_t)0;
    }
    for (int e = t; e < 64 * 32; e += 256) {
        int d = e >> 5, cc = e & 31;
        int col = (cc == 0) ? 0 : (1024 + cc);
        VT[((size_t)f * 64 + d) * KVPAD + col] = (cc == 0) ? f2b(nullkv[64 + d]) : (ushort_t)0;
    }
}

// ---------------- weight convert: W[K][ldw] (col window c0) -> Bt[N][Kp] bf16
__global__ __launch_bounds__(256) void wcvt_kernel(
    const float* __restrict__ W, int ldw, int c0,
    ushort_t* __restrict__ Bt, int Kp, int K, int Ncols,
    const float* __restrict__ gv)
{
    __shared__ float tile[32][33];
    int nb = blockIdx.x * 32, kb = blockIdx.y * 32;
    int tx = threadIdx.x & 31, ty = threadIdx.x >> 5;
    #pragma unroll
    for (int it = 0; it < 4; ++it) {
        int k = kb + ty + it * 8, n = nb + tx;
        float v = (k < K && n < Ncols) ? W[(size_t)k * ldw + c0 + n] : 0.f;
        if (gv && k < K) v *= gv[k];
        tile[ty + it * 8][tx] = v;
    }
    __syncthreads();
    #pragma unroll
    for (int it = 0; it < 4; ++it) {
        int n = nb + ty + it * 8, k = kb + tx;
        if (n < Ncols && k < Kp) Bt[(size_t)n * Kp + k] = f2b(tile[tx][ty + it * 8]);
    }
}

// ---------------------------------------------------- (C,T) -> (T,C) transpose
__global__ __launch_bounds__(256) void transpose_in_kernel(
    const float* __restrict__ x, float* __restrict__ dst)
{
    __shared__ float tile[32][33];
    int t0b = blockIdx.x * 32, c0b = blockIdx.y * 32;
    int tx = threadIdx.x & 31, ty = threadIdx.x >> 5;
    #pragma unroll
    for (int it = 0; it < 4; ++it) {
        int c = ty + it * 8;
        tile[c][tx] = x[(size_t)(c0b + c) * TOK + t0b + tx];
    }
    __syncthreads();
    #pragma unroll
    for (int it = 0; it < 4; ++it) {
        int tr = ty + it * 8;
        dst[(size_t)(t0b + tr) * DIMC + c0b + tx] = tile[tx][tr];
    }
}

// ---------------------------------------------------------------- LayerNorm → bf16
__global__ __launch_bounds__(256) void ln_bf16_kernel(
    const float* __restrict__ in, ushort_t* __restrict__ out,
    const float* __restrict__ w, const float* __restrict__ b)
{
    __shared__ float r1[4], r2[4];
    size_t base = (size_t)blockIdx.x * DIMC;
    int t = threadIdx.x;
    float x0 = in[base + t], x1 = in[base + 256 + t];
    float s = x0 + x1, s2 = x0 * x0 + x1 * x1;
    #pragma unroll
    for (int o = 32; o > 0; o >>= 1) { s += __shfl_down(s, o, 64); s2 += __shfl_down(s2, o, 64); }
    if ((t & 63) == 0) { r1[t >> 6] = s; r2[t >> 6] = s2; }
    __syncthreads();
    float mean = (r1[0] + r1[1] + r1[2] + r1[3]) * (1.f / 512.f);
    float ex2  = (r2[0] + r2[1] + r2[2] + r2[3]) * (1.f / 512.f);
    float rstd = rsqrtf(ex2 - mean * mean + 1e-5f);
    out[base + t]       = f2b((x0 - mean) * rstd * w[t] + b[t]);
    out[base + 256 + t] = f2b((x1 - mean) * rstd * w[256 + t] + b[256 + t]);
}

// LN(proj f32) + residual in place
__global__ __launch_bounds__(256) void ln_add_kernel(
    const float* __restrict__ proj, float* __restrict__ io,
    const float* __restrict__ w, const float* __restrict__ b)
{
    __shared__ float r1[4], r2[4];
    size_t base = (size_t)blockIdx.x * DIMC;
    int t = threadIdx.x;
    float x0 = proj[base + t], x1 = proj[base + 256 + t];
    float s = x0 + x1, s2 = x0 * x0 + x1 * x1;
    #pragma unroll
    for (int o = 32; o > 0; o >>= 1) { s += __shfl_down(s, o, 64); s2 += __shfl_down(s2, o, 64); }
    if ((t & 63) == 0) { r1[t >> 6] = s; r2[t >> 6] = s2; }
    __syncthreads();
    float mean = (r1[0] + r1[1] + r1[2] + r1[3]) * (1.f / 512.f);
    float ex2  = (r2[0] + r2[1] + r2[2] + r2[3]) * (1.f / 512.f);
    float rstd = rsqrtf(ex2 - mean * mean + 1e-5f);
    io[base + t]       += (x0 - mean) * rstd * w[t] + b[t];
    io[base + 256 + t] += (x1 - mean) * rstd * w[256 + t] + b[256 + t];
}

// spatial->temporal row permute (f32)
__global__ __launch_bounds__(128) void permute0_kernel(
    const float* __restrict__ src, float* __restrict__ dst)
{
    int rd = blockIdx.x;
    int rs = (rd & 15) * 1024 + (rd >> 4);
    ((float4*)(dst + (size_t)rd * DIMC))[threadIdx.x] =
        ((const float4*)(src + (size_t)rs * DIMC))[threadIdx.x];
}

// temporal->spatial permute, dual output f32 + bf16
__global__ __launch_bounds__(128) void permute1_dual_kernel(
    const float* __restrict__ src, float* __restrict__ dst, ushort_t* __restrict__ dstb)
{
    int rd = blockIdx.x;
    int rs = (rd & 1023) * 16 + (rd >> 10);
    float4 v = ((const float4*)(src + (size_t)rs * DIMC))[threadIdx.x];
    ((float4*)(dst + (size_t)rd * DIMC))[threadIdx.x] = v;
    u32 lo = (u32)f2b(v.x) | ((u32)f2b(v.y) << 16);
    u32 hi = (u32)f2b(v.z) | ((u32)f2b(v.w) << 16);
    ((uint2*)(dstb + (size_t)rd * DIMC))[threadIdx.x] = make_uint2(lo, hi);
}

// ---------------------------------------------------------------- MFMA GEMM
// 1-D grid of nx*16*8 blocks. XCD-aware swizzle: xcd = lin&7 owns m-tiles
// [xcd*16, xcd*16+16) for ALL nx n-tiles -> per-XCD L2-resident A band.
// EPI 0: C f32 = acc*scale. EPI 3: Cb bf16. EPI 4: spatial KV scatter.
// EPI 5: final FF epilogue outT[n*TOK+m] = acc*s1 - s0*colsum[n] + resid.
template<int EPI>
__global__ __launch_bounds__(256) void gemm_mfma(
    const ushort_t* __restrict__ A, int lda,
    const ushort_t* __restrict__ Bt, int Kp,
    float* __restrict__ C, ushort_t* __restrict__ Cb, int ldc,
    int M, int N, int K, float scale, int nx,
    const float* __restrict__ stats, const float* __restrict__ g,
    const float* __restrict__ resid, float* __restrict__ outT,
    ushort_t* __restrict__ KPo, ushort_t* __restrict__ VTo)
{
    __shared__ __align__(16) ushort_t As[4 * 128 * 8];
    __shared__ __align__(16) ushort_t Bs[4 * 128 * 8];
    int lin = blockIdx.x;
    int xcd = lin & 7, idx = lin >> 3;
    int m0 = (xcd * 16 + (idx & 15)) * 128;
    int n0 = (idx >> 4) * 128;
    int tid = threadIdx.x, lane = tid & 63, wid = tid >> 6;
    int wy = wid >> 1, wx = wid & 1, quad = lane >> 4, l16 = lane & 15;
    bool bfull = (n0 + 128 <= N);
    f32x4 acc[4][4];
    #pragma unroll
    for (int i = 0; i < 4; ++i)
        #pragma unroll
        for (int j = 0; j < 4; ++j) { acc[i][j][0]=0.f; acc[i][j][1]=0.f; acc[i][j][2]=0.f; acc[i][j][3]=0.f; }

    for (int k0 = 0; k0 < K; k0 += 32) {
        if (k0) __syncthreads();
        #pragma unroll
        for (int r = 0; r < 2; ++r) {
            int c = wid * 128 + r * 64 + lane;
            const ushort_t* src = A + (size_t)(m0 + (c & 127)) * lda + k0 + (c >> 7) * 8;
            gload_lds16(src, &As[(wid * 128 + r * 64) * 8]);
        }
        if (bfull) {
            #pragma unroll
            for (int r = 0; r < 2; ++r) {
                int c = wid * 128 + r * 64 + lane;
                const ushort_t* src = Bt + (size_t)(n0 + (c & 127)) * Kp + k0 + (c >> 7) * 8;
                gload_lds16(src, &Bs[(wid * 128 + r * 64) * 8]);
            }
        } else {
            #pragma unroll
            for (int r = 0; r < 2; ++r) {
                int c = tid + r * 256;
                int kg = c >> 7, nloc = c & 127;
                bf16x8 v;
                if (n0 + nloc < N) v = *(const bf16x8*)(Bt + (size_t)(n0 + nloc) * Kp + k0 + kg * 8);
                else { for (int e = 0; e < 8; ++e) v[e] = 0; }
                *(bf16x8*)&Bs[c * 8] = v;
            }
        }
        __syncthreads();
        bf16x8 af[4], bfr[4];
        #pragma unroll
        for (int i = 0; i < 4; ++i) af[i] = *(bf16x8*)&As[(quad * 128 + wy * 64 + i * 16 + l16) * 8];
        #pragma unroll
        for (int j = 0; j < 4; ++j) bfr[j] = *(bf16x8*)&Bs[(quad * 128 + wx * 64 + j * 16 + l16) * 8];
        #pragma unroll
        for (int i = 0; i < 4; ++i)
            #pragma unroll
            for (int j = 0; j < 4; ++j)
                acc[i][j] = __builtin_amdgcn_mfma_f32_16x16x32_bf16(af[i], bfr[j], acc[i][j], 0, 0, 0);
    }
    #pragma unroll
    for (int i = 0; i < 4; ++i) {
        #pragma unroll
        for (int j = 0; j < 4; ++j) {
            #pragma unroll
            for (int r = 0; r < 4; ++r) {
                int m = m0 + wy * 64 + i * 16 + quad * 4 + r;
                int n = n0 + wx * 64 + j * 16 + l16;
                if (n >= N) continue;
                float v = acc[i][j][r] * scale;
                if (EPI == 0) {
                    C[(size_t)m * ldc + n] = v;
                } else if (EPI == 3) {
                    Cb[(size_t)m * ldc + n] = f2b(v);
                } else if (EPI == 4) {
                    int frame = m >> 10, tt = m & 1023;
                    if (n < 64) KPo[((size_t)frame * KVPAD + 1 + tt) * 64 + n] = f2b(v);
                    else        VTo[((size_t)frame * 64 + (n - 64)) * KVPAD + 1 + tt] = f2b(v);
                } else if (EPI == 5) {
                    float s0 = stats[2 * m], s1 = stats[2 * m + 1];
                    outT[(size_t)n * TOK + m] = v * s1 - s0 * g[n] + resid[(size_t)m * DIMC + n];
                }
            }
        }
    }
}

// ------------------------------------------- fused FF front GEMM (a & gate)
// 1-D grid 1408 = 8 XCD x 16 m-tiles x 11 n-tiles (same swizzle as gemm_mfma).
__global__ __launch_bounds__(256) void ff_gemm_fused(
    const ushort_t* __restrict__ A,
    const ushort_t* __restrict__ Ba, const ushort_t* __restrict__ Bg,
    ushort_t* __restrict__ YS)
{
    __shared__ __align__(16) ushort_t As[4 * 128 * 8];
    __shared__ __align__(16) ushort_t Bsa[4 * 128 * 8];
    __shared__ __align__(16) ushort_t Bsg[4 * 128 * 8];
    int lin = blockIdx.x;
    int xcd = lin & 7, idx = lin >> 3;
    int m0 = (xcd * 16 + (idx & 15)) * 128;
    int n0 = (idx >> 4) * 128;
    int tid = threadIdx.x, lane = tid & 63, wid = tid >> 6;
    int wy = wid >> 1, wx = wid & 1, quad = lane >> 4, l16 = lane & 15;
    f32x4 aA[4][4], aG[4][4];
    #pragma unroll
    for (int i = 0; i < 4; ++i)
        #pragma unroll
        for (int j = 0; j < 4; ++j) {
            aA[i][j][0]=0.f; aA[i][j][1]=0.f; aA[i][j][2]=0.f; aA[i][j][3]=0.f;
            aG[i][j][0]=0.f; aG[i][j][1]=0.f; aG[i][j][2]=0.f; aG[i][j][3]=0.f;
        }

    for (int k0 = 0; k0 < 512; k0 += 32) {
        if (k0) __syncthreads();
        #pragma unroll
        for (int r = 0; r < 2; ++r) {
            int c = wid * 128 + r * 64 + lane;
            gload_lds16(A + (size_t)(m0 + (c & 127)) * 512 + k0 + (c >> 7) * 8,
                        &As[(wid * 128 + r * 64) * 8]);
        }
        #pragma unroll
        for (int r = 0; r < 2; ++r) {
            int c = tid + r * 256;
            int nloc = c & 127;
            bf16x8 va, vg;
            if (n0 + nloc < FFI) {
                size_t off = (size_t)(n0 + nloc) * 512 + k0 + (c >> 7) * 8;
                va = *(const bf16x8*)(Ba + off);
                vg = *(const bf16x8*)(Bg + off);
            } else {
                #pragma unroll
                for (int e = 0; e < 8; ++e) { va[e] = 0; vg[e] = 0; }
            }
            *(bf16x8*)&Bsa[c * 8] = va;
            *(bf16x8*)&Bsg[c * 8] = vg;
        }
        __syncthreads();
        bf16x8 af[4], ba[4], bg[4];
        #pragma unroll
        for (int i = 0; i < 4; ++i) af[i] = *(bf16x8*)&As[(quad * 128 + wy * 64 + i * 16 + l16) * 8];
        #pragma unroll
        for (int j = 0; j < 4; ++j) {
            int idx2 = (quad * 128 + wx * 64 + j * 16 + l16) * 8;
            ba[j] = *(bf16x8*)&Bsa[idx2];
            bg[j] = *(bf16x8*)&Bsg[idx2];
        }
        #pragma unroll
        for (int i = 0; i < 4; ++i)
            #pragma unroll
            for (int j = 0; j < 4; ++j) {
                aA[i][j] = __builtin_amdgcn_mfma_f32_16x16x32_bf16(af[i], ba[j], aA[i][j], 0, 0, 0);
                aG[i][j] = __builtin_amdgcn_mfma_f32_16x16x32_bf16(af[i], bg[j], aG[i][j], 0, 0, 0);
            }
    }
    #pragma unroll
    for (int i = 0; i < 4; ++i) {
        #pragma unroll
        for (int j = 0; j < 4; ++j) {
            #pragma unroll
            for (int r = 0; r < 4; ++r) {
                int m = m0 + wy * 64 + i * 16 + quad * 4 + r;
                int n = n0 + wx * 64 + j * 16 + l16;
                if (n >= FFI) {
                    if (n < YSLD) YS[(size_t)m * YSLD + n] = 0;   // zero pad cols
                    continue;
                }
                float v = aA[i][j][r] * gelu_exact(aG[i][j][r]);
                int dr = (n < CH1) ? m : m + 1024;
                if (dr < TOK) YS[(size_t)dr * YSLD + n] = f2b(v);
                if (n >= CH1 && m < 1024) YS[(size_t)m * YSLD + n] = 0;
            }
        }
    }
}

// --------------------------------------------------- spatial attention (MFMA flash)
// 1-D grid 1024 = 8 XCD x (2 frames x 64 q-tiles): per-XCD KV is L2-resident.
__global__ __launch_bounds__(256) void attn_sp_mfma(
    const ushort_t* __restrict__ Q,      // [16384][512] bf16 pre-scaled
    const ushort_t* __restrict__ KP,     // [16][1056][64]
    const ushort_t* __restrict__ VT,     // [16][64][1056]
    const ushort_t* __restrict__ BIASX,  // [8][1024][1152]
    ushort_t* __restrict__ O)            // [16384][512] bf16
{
    __shared__ __align__(16) ushort_t Ks[128 * 64];
    __shared__ __align__(16) ushort_t Vs[64 * 128];
    __shared__ __align__(16) ushort_t PT[4][16 * 136];
    int lin = blockIdx.x;
    int xcd = lin & 7, idx = lin >> 3;
    int frame = xcd * 2 + (idx >> 6);
    int qt = idx & 63;
    int q0 = qt * 16;
    int tid = threadIdx.x, lane = tid & 63, wid = tid >> 6;
    int quad = lane >> 4, l16 = lane & 15;
    ushort_t* PTw = &PT[wid][0];

    bf16x8 aQ[2][2];
    const ushort_t* brow[2];
    #pragma unroll
    for (int i = 0; i < 2; ++i) {
        int h = wid * 2 + i;
        const ushort_t* qp = Q + (size_t)(frame * 1024 + q0 + l16) * 512 + h * 64 + quad * 8;
        aQ[i][0] = *(const bf16x8*)qp;
        aQ[i][1] = *(const bf16x8*)(qp + 32);
        brow[i] = BIASX + ((size_t)h * 1024 + q0 + l16) * BSTRIDE;
    }
    f32x4 Oc[2][4];
    float mcol[2], lcol[2];
    #pragma unroll
    for (int i = 0; i < 2; ++i) {
        #pragma unroll
        for (int nt = 0; nt < 4; ++nt) { Oc[i][nt][0]=0.f; Oc[i][nt][1]=0.f; Oc[i][nt][2]=0.f; Oc[i][nt][3]=0.f; }
        mcol[i] = -1.0e30f; lcol[i] = 0.f;
    }

    for (int jt = 0; jt < 9; ++jt) {
        __syncthreads();
        #pragma unroll
        for (int r = 0; r < 4; ++r) {
            int L = wid * 256 + r * 64 + lane;
            int c = L >> 3, gp = L & 7, gg = gp ^ (c & 7);
            int jj = jt * 128 + c; if (jj > KVPAD - 1) jj = KVPAD - 1;
            gload_lds16(KP + ((size_t)frame * KVPAD + jj) * 64 + gg * 8, &Ks[(wid * 256 + r * 64) * 8]);
        }
        #pragma unroll
        for (int r = 0; r < 4; ++r) {
            int L = wid * 256 + r * 64 + lane;
            int d = L >> 4, cgp = L & 15;
            int cg = (cgp & 8) | ((cgp & 7) ^ (d & 7));
            int col = jt * 128 + cg * 8; if (col > KVPAD - 8) col = KVPAD - 8;
            gload_lds16(VT + ((size_t)frame * 64 + d) * KVPAD + col, &Vs[(wid * 256 + r * 64) * 8]);
        }
        __syncthreads();
        f32x4 S[2][8];
        #pragma unroll
        for (int i = 0; i < 2; ++i)
            #pragma unroll
            for (int j = 0; j < 8; ++j) { S[i][j][0]=0.f; S[i][j][1]=0.f; S[i][j][2]=0.f; S[i][j][3]=0.f; }
        #pragma unroll
        for (int j = 0; j < 8; ++j) {
            int c = j * 16 + l16;
            #pragma unroll
            for (int ks = 0; ks < 2; ++ks) {
                bf16x8 kb = *(bf16x8*)&Ks[(c * 8 + ((ks * 4 + quad) ^ (c & 7))) * 8];
                S[0][j] = __builtin_amdgcn_mfma_f32_16x16x32_bf16(kb, aQ[0][ks], S[0][j], 0, 0, 0);
                S[1][j] = __builtin_amdgcn_mfma_f32_16x16x32_bf16(kb, aQ[1][ks], S[1][j], 0, 0, 0);
            }
        }
        #pragma unroll
        for (int i = 0; i < 2; ++i) {
            #pragma unroll
            for (int j = 0; j < 8; ++j) {
                int kbase = jt * 128 + j * 16 + quad * 4;
                uint2 bv = *(const uint2*)(brow[i] + kbase);
                S[i][j][0] += b2f((ushort_t)(bv.x & 0xffffu));
                S[i][j][1] += b2f((ushort_t)(bv.x >> 16));
                S[i][j][2] += b2f((ushort_t)(bv.y & 0xffffu));
                S[i][j][3] += b2f((ushort_t)(bv.y >> 16));
            }
        }
        float alpha[2];
        #pragma unroll
        for (int i = 0; i < 2; ++i) {
            float mx = S[i][0][0];
            #pragma unroll
            for (int j = 0; j < 8; ++j)
                #pragma unroll
                for (int r = 0; r < 4; ++r) mx = fmaxf(mx, S[i][j][r]);
            mx = fmaxf(mx, __shfl_xor(mx, 16, 64));
            mx = fmaxf(mx, __shfl_xor(mx, 32, 64));
            float mnew = fmaxf(mcol[i], mx);
            alpha[i] = __expf(mcol[i] - mnew);
            mcol[i] = mnew;
            float rs = 0.f;
            #pragma unroll
            for (int j = 0; j < 8; ++j)
                #pragma unroll
                for (int r = 0; r < 4; ++r) {
                    float p = __expf(S[i][j][r] - mnew);
                    S[i][j][r] = p;
                    rs += p;
                }
            rs += __shfl_xor(rs, 16, 64);
            rs += __shfl_xor(rs, 32, 64);
            lcol[i] = lcol[i] * alpha[i] + rs;
        }
        #pragma unroll
        for (int i = 0; i < 2; ++i) {
            #pragma unroll
            for (int r = 0; r < 4; ++r) {
                float ar = __shfl(alpha[i], quad * 4 + r, 64);
                #pragma unroll
                for (int nt = 0; nt < 4; ++nt) Oc[i][nt][r] *= ar;
            }
        }
        #pragma unroll
        for (int i = 0; i < 2; ++i) {
            #pragma unroll
            for (int j = 0; j < 8; ++j) {
                u32 u0 = __float_as_uint(S[i][j][0]) + 0x8000u;
                u32 u1 = __float_as_uint(S[i][j][1]) + 0x8000u;
                u32 u2 = __float_as_uint(S[i][j][2]) + 0x8000u;
                u32 u3 = __float_as_uint(S[i][j][3]) + 0x8000u;
                uint2 pk;
                pk.x = (u0 >> 16) | (u1 & 0xffff0000u);
                pk.y = (u2 >> 16) | (u3 & 0xffff0000u);
                *(uint2*)&PTw[l16 * 136 + j * 16 + quad * 4] = pk;
            }
            #pragma unroll
            for (int ks = 0; ks < 4; ++ks) {
                bf16x8 pa = *(bf16x8*)&PTw[l16 * 136 + ks * 32 + quad * 8];
                #pragma unroll
                for (int nt = 0; nt < 4; ++nt) {
                    int d = nt * 16 + l16;
                    int cg = ks * 4 + quad;
                    int phys = (cg & 8) | ((cg & 7) ^ (d & 7));
                    bf16x8 vb = *(bf16x8*)&Vs[(d * 16 + phys) * 8];
                    Oc[i][nt] = __builtin_amdgcn_mfma_f32_16x16x32_bf16(pa, vb, Oc[i][nt], 0, 0, 0);
                }
            }
        }
    }
    #pragma unroll
    for (int i = 0; i < 2; ++i) {
        int h = wid * 2 + i;
        #pragma unroll
        for (int r = 0; r < 4; ++r) {
            float linv = 1.f / __shfl(lcol[i], quad * 4 + r, 64);
            int ql = quad * 4 + r;
            #pragma unroll
            for (int nt = 0; nt < 4; ++nt) {
                int d = nt * 16 + l16;
                O[(size_t)(frame * 1024 + q0 + ql) * 512 + h * 64 + d] = f2b(Oc[i][nt][r] * linv);
            }
        }
    }
}

// ---------------------------------------------------------------- temporal attention
__global__ __launch_bounds__(256) void attn_tp_kernel(
    const ushort_t* __restrict__ q, const ushort_t* __restrict__ kv,
    const float* __restrict__ nullkv, const float* __restrict__ nullbias,
    const float* __restrict__ table, ushort_t* __restrict__ out)
{
    __shared__ float qs[16][512];
    __shared__ float ks[17][64];
    __shared__ float vs[17][64];
    __shared__ float sc[8][16][17];
    int b = blockIdx.x;
    int t = threadIdx.x;
    for (int e = t; e < 16 * 512; e += 256) {
        int f = e >> 9, c = e & 511;
        qs[f][c] = b2f(q[(size_t)(b * 16 + f) * 512 + c]);
    }
    for (int e = t; e < 17 * 64; e += 256) {
        int j = e >> 6, d = e & 63;
        ks[j][d] = (j == 0) ? nullkv[d]      : b2f(kv[(size_t)(b * 16 + j - 1) * 128 + d]);
        vs[j][d] = (j == 0) ? nullkv[64 + d] : b2f(kv[(size_t)(b * 16 + j - 1) * 128 + 64 + d]);
    }
    __syncthreads();
    for (int e = t; e < 8 * 16 * 17; e += 256) {
        int h = e / 272, rem = e - h * 272;
        int i = rem / 17, j = rem - i * 17;
        float acc = 0.f;
        for (int d = 0; d < 64; ++d) acc += qs[i][h * 64 + d] * ks[j][d];
        float bias = (j == 0) ? nullbias[h] : table[(i - (j - 1) + 15) * 8 + h];
        sc[h][i][j] = acc + bias;
    }
    __syncthreads();
    if (t < 128) {
        int h = t >> 4, i = t & 15;
        float mx = -1e30f;
        for (int j = 0; j < 17; ++j) mx = fmaxf(mx, sc[h][i][j]);
        float s = 0.f;
        for (int j = 0; j < 17; ++j) { float p = __expf(sc[h][i][j] - mx); sc[h][i][j] = p; s += p; }
        float inv = 1.f / s;
        for (int j = 0; j < 17; ++j) sc[h][i][j] *= inv;
    }
    __syncthreads();
    for (int e = t; e < 16 * 512; e += 256) {
        int i = e >> 9, c = e & 511;
        int h = c >> 6, d = c & 63;
        float acc = 0.f;
        #pragma unroll
        for (int j = 0; j < 17; ++j) acc += sc[h][i][j] * vs[j][d];
        out[(size_t)(b * 16 + i) * 512 + c] = f2b(acc);
    }
}

// ------------------------- FF shift-LN row stats from bf16 YS: (mean*rstd, rstd)
__global__ __launch_bounds__(256) void rowstats_bf16_kernel(
    const ushort_t* __restrict__ YS, float* __restrict__ stats)
{
    __shared__ float r1[4], r2[4];
    int r = blockIdx.x, t = threadIdx.x;
    const ushort_t* row = YS + (size_t)r * YSLD;
    float s = 0.f, s2 = 0.f;
    for (int c = t; c < FFI; c += 256) {
        float v = b2f(row[c]);
        s += v; s2 += v * v;
    }
    #pragma unroll
    for (int o = 32; o > 0; o >>= 1) { s += __shfl_down(s, o, 64); s2 += __shfl_down(s2, o, 64); }
    if ((t & 63) == 0) { r1[t >> 6] = s; r2[t >> 6] = s2; }
    __syncthreads();
    float S  = r1[0] + r1[1] + r1[2] + r1[3];
    float S2 = r2[0] + r2[1] + r2[2] + r2[3];
    float mean = S * (1.f / 1365.f);
    float var  = S2 * (1.f / 1365.f) - mean * mean;
    float rstd = rsqrtf(fmaxf(var, 1e-5f));
    if (t == 0) { stats[2 * r] = mean * rstd; stats[2 * r + 1] = rstd; }
}

// --------------------- colsum[n] = sum_k W'[n][k]  (rows of converted W')
__global__ __launch_bounds__(64) void colsum_kernel(
    const ushort_t* __restrict__ Wt, float* __restrict__ colsum)
{
    int n = blockIdx.x, t = threadIdx.x;
    const ushort_t* row = Wt + (size_t)n * YSLD;
    float s = 0.f;
    for (int k = t; k < YSLD; k += 64) s += b2f(row[k]);
    #pragma unroll
    for (int o = 32; o > 0; o >>= 1) s += __shfl_down(s, o, 64);
    if (t == 0) colsum[n] = s;
}

// ================================================================ launcher
extern "C" void kernel_launch(void* const* d_in, const int* in_sizes, int n_in,
                              void* d_out, int out_size, void* d_ws, size_t ws_size,
                              hipStream_t stream)
{
    const float* x          = (const float*)d_in[0];
    const float* sa_ln_w    = (const float*)d_in[1];
    const float* sa_ln_b    = (const float*)d_in[2];
    const float* sa_wq      = (const float*)d_in[3];
    const float* sa_wkv     = (const float*)d_in[4];
    const float* sa_null_kv = (const float*)d_in[5];
    const float* sa_null_b  = (const float*)d_in[6];
    const float* sa_wout    = (const float*)d_in[7];
    const float* sa_oln_w   = (const float*)d_in[8];
    const float* sa_oln_b   = (const float*)d_in[9];
    const float* ta_ln_w    = (const float*)d_in[10];
    const float* ta_ln_b    = (const float*)d_in[11];
    const float* ta_wq      = (const float*)d_in[12];
    const float* ta_wkv     = (const float*)d_in[13];
    const float* ta_null_kv = (const float*)d_in[14];
    const float* ta_null_b  = (const float*)d_in[15];
    const float* ta_wout    = (const float*)d_in[16];
    const float* ta_oln_w   = (const float*)d_in[17];
    const float* ta_oln_b   = (const float*)d_in[18];
    const float* sp_w0      = (const float*)d_in[19];
    const float* sp_b0      = (const float*)d_in[20];
    const float* sp_w1      = (const float*)d_in[21];
    const float* sp_b1      = (const float*)d_in[22];
    const float* sp_w2      = (const float*)d_in[23];
    const float* sp_b2      = (const float*)d_in[24];
    const float* tp_w0      = (const float*)d_in[25];
    const float* tp_b0      = (const float*)d_in[26];
    const float* tp_w1      = (const float*)d_in[27];
    const float* tp_b1      = (const float*)d_in[28];
    const float* tp_w2      = (const float*)d_in[29];
    const float* tp_b2      = (const float*)d_in[30];
    const float* ff_win     = (const float*)d_in[31];
    const float* ff_g       = (const float*)d_in[32];
    const float* ff_wout    = (const float*)d_in[33];

    char* ws = (char*)d_ws;
    // regions (bytes)
    float*    RES   = (float*)(ws + 0);                        // 33,554,432 (residual, spatial layout)
    ushort_t* XN16  = (ushort_t*)(ws + 33554432);              // 16,777,216 (xn / x2 bf16)
    ushort_t* Q16   = (ushort_t*)(ws + 50331648);              // spatial Q bf16 (spatial phase)
    float*    RT    = (float*)(ws + 50331648);                 // temporal residual f32 (temporal phase)
    ushort_t* YS    = (ushort_t*)(ws + 50331648);              // FF shifted act bf16 [16384][1376]
    ushort_t* WSA   = (ushort_t*)(ws + 67108864);              // spatial weights (dead by FF)
    ushort_t* KP    = (ushort_t*)(ws + 83886080);              // 16x1056x64 bf16 (spatial)
    ushort_t* VTb   = (ushort_t*)(ws + 86048768);              // 16x64x1056 bf16 (spatial)
    ushort_t* KV16  = (ushort_t*)(ws + 83886080);              // temporal KV bf16
    ushort_t* WTA   = (ushort_t*)(ws + 90439680);              // temporal weights
    ushort_t* AO16  = (ushort_t*)(ws + 92274688);              // attn out bf16 (dead by FF)
    ushort_t* WFFG  = (ushort_t*)(ws + 96468992);              // FF gate weights (FF phase)
    ushort_t* WFFB  = (ushort_t*)(ws + 97867776);              // W' = (ff_wout*g)^T [512][1376]
    ushort_t* BIAS16= (ushort_t*)(ws + 109051904);             // spatial bias bf16 (PRJ region)
    float*    PRJ   = (float*)(ws + 109051904);                // proj out f32
    ushort_t* Q16t  = (ushort_t*)(ws + 109051904);             // temporal Q bf16
    ushort_t* WFFA  = (ushort_t*)(ws + 139984896);             // FF a-weights bf16 (dead PRJ zone)
    float*    STATS = (float*)(ws + 142606336);                // 16384 x (mean*rstd, rstd)
    float*    SPT   = (float*)(ws + 142737408);                // spatial CPB table (spatial phase)
    float*    COLSUM= (float*)(ws + 142737408);                // colsum[512] (FF phase, dead SPT)
    float*    TPT   = (float*)(ws + 142864448);

    ushort_t* WQ_T  = WSA;                 // [512][512]
    ushort_t* WKV_T = WSA + 262144;        // [128][512]
    ushort_t* WO_T  = WSA + 327680;        // [512][512]
    ushort_t* tWQ_T  = WTA;
    ushort_t* tWKV_T = WTA + 262144;
    ushort_t* tWO_T  = WTA + 327680;

    dim3 blk(256);

    // bias tables
    cpb_kernel<<<dim3(3969), blk, 0, stream>>>(sp_w0, sp_b0, sp_w1, sp_b1, sp_w2, sp_b2, SPT, 0);
    cpb_kernel<<<dim3(31),   blk, 0, stream>>>(tp_w0, tp_b0, tp_w1, tp_b1, tp_w2, tp_b2, TPT, 1);
    bias_sp_kernel<<<dim3(1024, 8), blk, 0, stream>>>(SPT, sa_null_b, BIAS16);
    kvinit_kernel<<<dim3(16), blk, 0, stream>>>(sa_null_kv, KP, VTb);

    // ---------------- spatial ----------------
    wcvt_kernel<<<dim3(16, 16), blk, 0, stream>>>(sa_wq, 512, 0, WQ_T, 512, 512, 512, nullptr);
    wcvt_kernel<<<dim3(4, 16),  blk, 0, stream>>>(sa_wkv, 128, 0, WKV_T, 512, 512, 128, nullptr);
    wcvt_kernel<<<dim3(16, 16), blk, 0, stream>>>(sa_wout, 512, 0, WO_T, 512, 512, 512, nullptr);
    transpose_in_kernel<<<dim3(512, 16), blk, 0, stream>>>(x, RES);
    ln_bf16_kernel<<<dim3(TOK), blk, 0, stream>>>(RES, XN16, sa_ln_w, sa_ln_b);
    gemm_mfma<3><<<dim3(512), blk, 0, stream>>>(XN16, 512, WQ_T, 512,
        nullptr, Q16, 512, TOK, 512, 512, 0.125f, 4, nullptr, nullptr, nullptr, nullptr, nullptr, nullptr);
    gemm_mfma<4><<<dim3(128), blk, 0, stream>>>(XN16, 512, WKV_T, 512,
        nullptr, nullptr, 0, TOK, 128, 512, 1.0f, 1, nullptr, nullptr, nullptr, nullptr, KP, VTb);
    attn_sp_mfma<<<dim3(1024), blk, 0, stream>>>(Q16, KP, VTb, BIAS16, AO16);
    gemm_mfma<0><<<dim3(512), blk, 0, stream>>>(AO16, 512, WO_T, 512,
        PRJ, nullptr, 512, TOK, 512, 512, 1.0f, 4, nullptr, nullptr, nullptr, nullptr, nullptr, nullptr);
    ln_add_kernel<<<dim3(TOK), blk, 0, stream>>>(PRJ, RES, sa_oln_w, sa_oln_b);

    // ---------------- temporal ----------------
    permute0_kernel<<<dim3(TOK), dim3(128), 0, stream>>>(RES, RT);
    wcvt_kernel<<<dim3(16, 16), blk, 0, stream>>>(ta_wq, 512, 0, tWQ_T, 512, 512, 512, nullptr);
    wcvt_kernel<<<dim3(4, 16),  blk, 0, stream>>>(ta_wkv, 128, 0, tWKV_T, 512, 512, 128, nullptr);
    wcvt_kernel<<<dim3(16, 16), blk, 0, stream>>>(ta_wout, 512, 0, tWO_T, 512, 512, 512, nullptr);
    ln_bf16_kernel<<<dim3(TOK), blk, 0, stream>>>(RT, XN16, ta_ln_w, ta_ln_b);
    gemm_mfma<3><<<dim3(512), blk, 0, stream>>>(XN16, 512, tWQ_T, 512,
        nullptr, Q16t, 512, TOK, 512, 512, 0.125f, 4, nullptr, nullptr, nullptr, nullptr, nullptr, nullptr);
    gemm_mfma<3><<<dim3(128), blk, 0, stream>>>(XN16, 512, tWKV_T, 512,
        nullptr, KV16, 128, TOK, 128, 512, 1.0f, 1, nullptr, nullptr, nullptr, nullptr, nullptr, nullptr);
    attn_tp_kernel<<<dim3(1024), blk, 0, stream>>>(Q16t, KV16, ta_null_kv, ta_null_b, TPT, AO16);
    gemm_mfma<0><<<dim3(512), blk, 0, stream>>>(AO16, 512, tWO_T, 512,
        PRJ, nullptr, 512, TOK, 512, 512, 1.0f, 4, nullptr, nullptr, nullptr, nullptr, nullptr, nullptr);
    ln_add_kernel<<<dim3(TOK), blk, 0, stream>>>(PRJ, RT, ta_oln_w, ta_oln_b);
    permute1_dual_kernel<<<dim3(TOK), dim3(128), 0, stream>>>(RT, RES, XN16);

    // ---------------- feed-forward ----------------
    wcvt_kernel<<<dim3(43, 16), blk, 0, stream>>>(ff_win, 2730, 0,   WFFA, 512, 512, FFI, nullptr);
    wcvt_kernel<<<dim3(43, 16), blk, 0, stream>>>(ff_win, 2730, FFI, WFFG, 512, 512, FFI, nullptr);
    wcvt_kernel<<<dim3(16, 43), blk, 0, stream>>>(ff_wout, 512, 0, WFFB, YSLD, FFI, 512, ff_g);
    colsum_kernel<<<dim3(512), dim3(64), 0, stream>>>(WFFB, COLSUM);
    ff_gemm_fused<<<dim3(1408), blk, 0, stream>>>(XN16, WFFA, WFFG, YS);
    rowstats_bf16_kernel<<<dim3(TOK), blk, 0, stream>>>(YS, STATS);
    gemm_mfma<5><<<dim3(512), blk, 0, stream>>>(YS, YSLD, WFFB, YSLD,
        nullptr, nullptr, 0, TOK, 512, YSLD, 1.0f, 4, STATS, COLSUM, RES, (float*)d_out, nullptr, nullptr);
}

// Round 8
// 915.570 us; speedup vs baseline: 5.6204x; 1.1062x over previous
//
#include <hip/hip_runtime.h>
#include <math.h>

#define TOK 16384
#define DIMC 512
#define FFI 1365
#define CH1 683
#define YSLD 1376         // YS row stride (bf16 elements, 16B aligned)
#define KVPAD 1056        // padded key count for spatial attn (mult of 8)
#define BSTRIDE 1152      // BIASX row stride (cols: 0=null, 1..1024=keys, rest=mask)
#define MASKB (-30000.f)  // softmax mask bias (bf16-safe, no near-inf)

typedef unsigned int u32;
typedef unsigned short ushort_t;
typedef __attribute__((ext_vector_type(8))) short bf16x8;
typedef __attribute__((ext_vector_type(4))) float f32x4;

__device__ inline ushort_t f2b(float x) {
    u32 u = __float_as_uint(x);
    u32 r = (u + 0x7fffu + ((u >> 16) & 1u)) >> 16;
    return (ushort_t)r;
}
__device__ inline float b2f(ushort_t u) { return __uint_as_float(((u32)u) << 16); }

__device__ inline void gload_lds16(const void* g, void* l) {
    __builtin_amdgcn_global_load_lds(
        (const __attribute__((address_space(1))) u32*)g,
        (__attribute__((address_space(3))) u32*)l, 16, 0, 0);
}

__device__ inline float gelu_exact(float x) {
    return 0.5f * x * (1.f + erff(x * 0.70710678118654752f));
}

// ---------------------------------------------------------------- CPB MLP
__global__ __launch_bounds__(256) void cpb_kernel(
    const float* __restrict__ w0, const float* __restrict__ b0,
    const float* __restrict__ w1, const float* __restrict__ b1,
    const float* __restrict__ w2, const float* __restrict__ b2,
    float* __restrict__ table, int mode)
{
    __shared__ float t0[256];
    __shared__ float t1[256];
    int r = blockIdx.x;
    int t = threadIdx.x;
    float c0, c1;
    if (mode == 0) { c0 = (float)(r / 63 - 31); c1 = (float)(r % 63 - 31); }
    else           { c0 = (float)(r - 15);      c1 = 0.f; }
    float a = c0 * w0[t] + b0[t];
    if (mode == 0) a += c1 * w0[256 + t];
    t0[t] = a / (1.f + __expf(-a));
    __syncthreads();
    float s = b1[t];
    for (int k = 0; k < 256; ++k) s += t0[k] * w1[k * 256 + t];
    t1[t] = s / (1.f + __expf(-s));
    __syncthreads();
    if (t < 8) {
        float o = b2[t];
        for (int k = 0; k < 256; ++k) o += t1[k] * w2[k * 8 + t];
        table[r * 8 + t] = o;
    }
}

// ------------------------------- materialize spatial bias bf16, padded layout
__global__ __launch_bounds__(256) void bias_sp_kernel(
    const float* __restrict__ tab, const float* __restrict__ nullbias,
    ushort_t* __restrict__ out)
{
    int pi = blockIdx.x, h = blockIdx.y;
    int phi = pi >> 5, pwi = pi & 31;
    ushort_t* row = out + ((size_t)h * 1024 + pi) * BSTRIDE;
    for (int c = threadIdx.x; c < BSTRIDE; c += 256) {
        float v;
        if (c == 0) v = nullbias[h];
        else if (c <= 1024) {
            int pj = c - 1;
            int phj = pj >> 5, pwj = pj & 31;
            int idx = (phi - phj + 31) * 63 + (pwi - pwj + 31);
            v = tab[idx * 8 + h];
        } else v = MASKB;
        row[c] = f2b(v);
    }
}

// -------------------------------------------- KP/VT pad+null init. grid 16
__global__ __launch_bounds__(256) void kvinit_kernel(
    const float* __restrict__ nullkv, ushort_t* __restrict__ KP, ushort_t* __restrict__ VT)
{
    int f = blockIdx.x, t = threadIdx.x;
    for (int e = t; e < 32 * 64; e += 256) {
        int rr = e >> 6, d = e & 63;
        int row = (rr == 0) ? 0 : (1024 + rr);
        KP[((size_t)f * KVPAD + row) * 64 + d] = (rr == 0) ? f2b(nullkv[d]) : (ushort_t)0;
    }
    for (int e = t; e < 64 * 32; e += 256) {
        int d = e >> 5, cc = e & 31;
        int col = (cc == 0) ? 0 : (1024 + cc);
        VT[((size_t)f * 64 + d) * KVPAD + col] = (cc == 0) ? f2b(nullkv[64 + d]) : (ushort_t)0;
    }
}

// ---------------- weight convert: W[K][ldw] (col window c0) -> Bt[N][Kp] bf16
// Writes rows n < Nwrite (zeros for n >= Ncols or k >= K) — pad rows are clean.
__global__ __launch_bounds__(256) void wcvt_kernel(
    const float* __restrict__ W, int ldw, int c0,
    ushort_t* __restrict__ Bt, int Kp, int K, int Ncols,
    const float* __restrict__ gv, int Nwrite)
{
    __shared__ float tile[32][33];
    int nb = blockIdx.x * 32, kb = blockIdx.y * 32;
    int tx = threadIdx.x & 31, ty = threadIdx.x >> 5;
    #pragma unroll
    for (int it = 0; it < 4; ++it) {
        int k = kb + ty + it * 8, n = nb + tx;
        float v = (k < K && n < Ncols) ? W[(size_t)k * ldw + c0 + n] : 0.f;
        if (gv && k < K) v *= gv[k];
        tile[ty + it * 8][tx] = v;
    }
    __syncthreads();
    #pragma unroll
    for (int it = 0; it < 4; ++it) {
        int n = nb + ty + it * 8, k = kb + tx;
        if (n < Nwrite && k < Kp) Bt[(size_t)n * Kp + k] = f2b(tile[tx][ty + it * 8]);
    }
}

// ---------------------------------------------------- (C,T) -> (T,C) transpose
__global__ __launch_bounds__(256) void transpose_in_kernel(
    const float* __restrict__ x, float* __restrict__ dst)
{
    __shared__ float tile[32][33];
    int t0b = blockIdx.x * 32, c0b = blockIdx.y * 32;
    int tx = threadIdx.x & 31, ty = threadIdx.x >> 5;
    #pragma unroll
    for (int it = 0; it < 4; ++it) {
        int c = ty + it * 8;
        tile[c][tx] = x[(size_t)(c0b + c) * TOK + t0b + tx];
    }
    __syncthreads();
    #pragma unroll
    for (int it = 0; it < 4; ++it) {
        int tr = ty + it * 8;
        dst[(size_t)(t0b + tr) * DIMC + c0b + tx] = tile[tx][tr];
    }
}

// ---------------------------------------------------------------- LayerNorm → bf16
__global__ __launch_bounds__(256) void ln_bf16_kernel(
    const float* __restrict__ in, ushort_t* __restrict__ out,
    const float* __restrict__ w, const float* __restrict__ b)
{
    __shared__ float r1[4], r2[4];
    size_t base = (size_t)blockIdx.x * DIMC;
    int t = threadIdx.x;
    float x0 = in[base + t], x1 = in[base + 256 + t];
    float s = x0 + x1, s2 = x0 * x0 + x1 * x1;
    #pragma unroll
    for (int o = 32; o > 0; o >>= 1) { s += __shfl_down(s, o, 64); s2 += __shfl_down(s2, o, 64); }
    if ((t & 63) == 0) { r1[t >> 6] = s; r2[t >> 6] = s2; }
    __syncthreads();
    float mean = (r1[0] + r1[1] + r1[2] + r1[3]) * (1.f / 512.f);
    float ex2  = (r2[0] + r2[1] + r2[2] + r2[3]) * (1.f / 512.f);
    float rstd = rsqrtf(ex2 - mean * mean + 1e-5f);
    out[base + t]       = f2b((x0 - mean) * rstd * w[t] + b[t]);
    out[base + 256 + t] = f2b((x1 - mean) * rstd * w[256 + t] + b[256 + t]);
}

// LN(proj f32) + residual in place
__global__ __launch_bounds__(256) void ln_add_kernel(
    const float* __restrict__ proj, float* __restrict__ io,
    const float* __restrict__ w, const float* __restrict__ b)
{
    __shared__ float r1[4], r2[4];
    size_t base = (size_t)blockIdx.x * DIMC;
    int t = threadIdx.x;
    float x0 = proj[base + t], x1 = proj[base + 256 + t];
    float s = x0 + x1, s2 = x0 * x0 + x1 * x1;
    #pragma unroll
    for (int o = 32; o > 0; o >>= 1) { s += __shfl_down(s, o, 64); s2 += __shfl_down(s2, o, 64); }
    if ((t & 63) == 0) { r1[t >> 6] = s; r2[t >> 6] = s2; }
    __syncthreads();
    float mean = (r1[0] + r1[1] + r1[2] + r1[3]) * (1.f / 512.f);
    float ex2  = (r2[0] + r2[1] + r2[2] + r2[3]) * (1.f / 512.f);
    float rstd = rsqrtf(ex2 - mean * mean + 1e-5f);
    io[base + t]       += (x0 - mean) * rstd * w[t] + b[t];
    io[base + 256 + t] += (x1 - mean) * rstd * w[256 + t] + b[256 + t];
}

// spatial->temporal row permute (f32)
__global__ __launch_bounds__(128) void permute0_kernel(
    const float* __restrict__ src, float* __restrict__ dst)
{
    int rd = blockIdx.x;
    int rs = (rd & 15) * 1024 + (rd >> 4);
    ((float4*)(dst + (size_t)rd * DIMC))[threadIdx.x] =
        ((const float4*)(src + (size_t)rs * DIMC))[threadIdx.x];
}

// temporal->spatial permute, dual output f32 + bf16
__global__ __launch_bounds__(128) void permute1_dual_kernel(
    const float* __restrict__ src, float* __restrict__ dst, ushort_t* __restrict__ dstb)
{
    int rd = blockIdx.x;
    int rs = (rd & 1023) * 16 + (rd >> 10);
    float4 v = ((const float4*)(src + (size_t)rs * DIMC))[threadIdx.x];
    ((float4*)(dst + (size_t)rd * DIMC))[threadIdx.x] = v;
    u32 lo = (u32)f2b(v.x) | ((u32)f2b(v.y) << 16);
    u32 hi = (u32)f2b(v.z) | ((u32)f2b(v.w) << 16);
    ((uint2*)(dstb + (size_t)rd * DIMC))[threadIdx.x] = make_uint2(lo, hi);
}

// ---------------------------------------------------------------- MFMA GEMM
// 1-D grid of nx*16*8 blocks. XCD-aware swizzle: xcd = lin&7 owns m-tiles
// [xcd*16, xcd*16+16) for ALL nx n-tiles -> per-XCD L2-resident A band.
template<int EPI>
__global__ __launch_bounds__(256) void gemm_mfma(
    const ushort_t* __restrict__ A, int lda,
    const ushort_t* __restrict__ Bt, int Kp,
    float* __restrict__ C, ushort_t* __restrict__ Cb, int ldc,
    int M, int N, int K, float scale, int nx,
    const float* __restrict__ stats, const float* __restrict__ g,
    const float* __restrict__ resid, float* __restrict__ outT,
    ushort_t* __restrict__ KPo, ushort_t* __restrict__ VTo)
{
    __shared__ __align__(16) ushort_t As[4 * 128 * 8];
    __shared__ __align__(16) ushort_t Bs[4 * 128 * 8];
    int lin = blockIdx.x;
    int xcd = lin & 7, idx = lin >> 3;
    int m0 = (xcd * 16 + (idx & 15)) * 128;
    int n0 = (idx >> 4) * 128;
    int tid = threadIdx.x, lane = tid & 63, wid = tid >> 6;
    int wy = wid >> 1, wx = wid & 1, quad = lane >> 4, l16 = lane & 15;
    bool bfull = (n0 + 128 <= N);
    f32x4 acc[4][4];
    #pragma unroll
    for (int i = 0; i < 4; ++i)
        #pragma unroll
        for (int j = 0; j < 4; ++j) { acc[i][j][0]=0.f; acc[i][j][1]=0.f; acc[i][j][2]=0.f; acc[i][j][3]=0.f; }

    for (int k0 = 0; k0 < K; k0 += 32) {
        if (k0) __syncthreads();
        #pragma unroll
        for (int r = 0; r < 2; ++r) {
            int c = wid * 128 + r * 64 + lane;
            const ushort_t* src = A + (size_t)(m0 + (c & 127)) * lda + k0 + (c >> 7) * 8;
            gload_lds16(src, &As[(wid * 128 + r * 64) * 8]);
        }
        if (bfull) {
            #pragma unroll
            for (int r = 0; r < 2; ++r) {
                int c = wid * 128 + r * 64 + lane;
                const ushort_t* src = Bt + (size_t)(n0 + (c & 127)) * Kp + k0 + (c >> 7) * 8;
                gload_lds16(src, &Bs[(wid * 128 + r * 64) * 8]);
            }
        } else {
            #pragma unroll
            for (int r = 0; r < 2; ++r) {
                int c = tid + r * 256;
                int kg = c >> 7, nloc = c & 127;
                bf16x8 v;
                if (n0 + nloc < N) v = *(const bf16x8*)(Bt + (size_t)(n0 + nloc) * Kp + k0 + kg * 8);
                else { for (int e = 0; e < 8; ++e) v[e] = 0; }
                *(bf16x8*)&Bs[c * 8] = v;
            }
        }
        __syncthreads();
        bf16x8 af[4], bfr[4];
        #pragma unroll
        for (int i = 0; i < 4; ++i) af[i] = *(bf16x8*)&As[(quad * 128 + wy * 64 + i * 16 + l16) * 8];
        #pragma unroll
        for (int j = 0; j < 4; ++j) bfr[j] = *(bf16x8*)&Bs[(quad * 128 + wx * 64 + j * 16 + l16) * 8];
        #pragma unroll
        for (int i = 0; i < 4; ++i)
            #pragma unroll
            for (int j = 0; j < 4; ++j)
                acc[i][j] = __builtin_amdgcn_mfma_f32_16x16x32_bf16(af[i], bfr[j], acc[i][j], 0, 0, 0);
    }
    #pragma unroll
    for (int i = 0; i < 4; ++i) {
        #pragma unroll
        for (int j = 0; j < 4; ++j) {
            #pragma unroll
            for (int r = 0; r < 4; ++r) {
                int m = m0 + wy * 64 + i * 16 + quad * 4 + r;
                int n = n0 + wx * 64 + j * 16 + l16;
                if (n >= N) continue;
                float v = acc[i][j][r] * scale;
                if (EPI == 0) {
                    C[(size_t)m * ldc + n] = v;
                } else if (EPI == 3) {
                    Cb[(size_t)m * ldc + n] = f2b(v);
                } else if (EPI == 4) {
                    int frame = m >> 10, tt = m & 1023;
                    if (n < 64) KPo[((size_t)frame * KVPAD + 1 + tt) * 64 + n] = f2b(v);
                    else        VTo[((size_t)frame * 64 + (n - 64)) * KVPAD + 1 + tt] = f2b(v);
                } else if (EPI == 5) {
                    float s0 = stats[2 * m], s1 = stats[2 * m + 1];
                    outT[(size_t)n * TOK + m] = v * s1 - s0 * g[n] + resid[(size_t)m * DIMC + n];
                }
            }
        }
    }
}

// ------------------------------------------- fused FF front GEMM (a & gate)
// ROUND-8 RESTRUCTURE: 128m x 64n dual-output tile -> acc = 64 AGPR/thread
// (was 128: 1 block/CU occupancy cliff). B from interleaved BI[2816][512]
// (row 2n = a-weights, 2n+1 = gate-weights) via pure global_load_lds.
// Grid 2816 = 8 XCD x 16 m-tiles x 22 n-tiles (XCD swizzle as gemm_mfma).
// LDS: As [kg4][m128][8], Bs [kg4][s2][n64][8].
__global__ __launch_bounds__(256) void ff_gemm_fused(
    const ushort_t* __restrict__ A,
    const ushort_t* __restrict__ BI,
    ushort_t* __restrict__ YS)
{
    __shared__ __align__(16) ushort_t As[4 * 128 * 8];
    __shared__ __align__(16) ushort_t Bs[4 * 2 * 64 * 8];
    int lin = blockIdx.x;
    int xcd = lin & 7, idx = lin >> 3;
    int m0 = (xcd * 16 + (idx & 15)) * 128;
    int n0 = (idx >> 4) * 64;
    int tid = threadIdx.x, lane = tid & 63, wid = tid >> 6;
    int wy = wid >> 1, wx = wid & 1, quad = lane >> 4, l16 = lane & 15;
    f32x4 aA[4][2], aG[4][2];
    #pragma unroll
    for (int i = 0; i < 4; ++i)
        #pragma unroll
        for (int j = 0; j < 2; ++j) {
            aA[i][j][0]=0.f; aA[i][j][1]=0.f; aA[i][j][2]=0.f; aA[i][j][3]=0.f;
            aG[i][j][0]=0.f; aG[i][j][1]=0.f; aG[i][j][2]=0.f; aG[i][j][3]=0.f;
        }

    for (int k0 = 0; k0 < 512; k0 += 32) {
        if (k0) __syncthreads();
        // A: chunk c = [kg4][m128]; 2 per thread
        #pragma unroll
        for (int r = 0; r < 2; ++r) {
            int c = wid * 128 + r * 64 + lane;
            gload_lds16(A + (size_t)(m0 + (c & 127)) * 512 + k0 + (c >> 7) * 8,
                        &As[(wid * 128 + r * 64) * 8]);
        }
        // B: chunk L = kg*128 + s*64 + n, kg=wid, s=r, n=lane; 2 per thread
        #pragma unroll
        for (int r = 0; r < 2; ++r) {
            gload_lds16(BI + (size_t)((n0 + lane) * 2 + r) * 512 + k0 + wid * 8,
                        &Bs[(wid * 128 + r * 64) * 8]);
        }
        __syncthreads();
        bf16x8 af[4], ba[2], bg[2];
        #pragma unroll
        for (int i = 0; i < 4; ++i) af[i] = *(bf16x8*)&As[(quad * 128 + wy * 64 + i * 16 + l16) * 8];
        #pragma unroll
        for (int j = 0; j < 2; ++j) {
            int nn = wx * 32 + j * 16 + l16;
            ba[j] = *(bf16x8*)&Bs[(quad * 128 + nn) * 8];
            bg[j] = *(bf16x8*)&Bs[(quad * 128 + 64 + nn) * 8];
        }
        #pragma unroll
        for (int i = 0; i < 4; ++i)
            #pragma unroll
            for (int j = 0; j < 2; ++j) {
                aA[i][j] = __builtin_amdgcn_mfma_f32_16x16x32_bf16(af[i], ba[j], aA[i][j], 0, 0, 0);
                aG[i][j] = __builtin_amdgcn_mfma_f32_16x16x32_bf16(af[i], bg[j], aG[i][j], 0, 0, 0);
            }
    }
    #pragma unroll
    for (int i = 0; i < 4; ++i) {
        #pragma unroll
        for (int j = 0; j < 2; ++j) {
            #pragma unroll
            for (int r = 0; r < 4; ++r) {
                int m = m0 + wy * 64 + i * 16 + quad * 4 + r;
                int n = n0 + wx * 32 + j * 16 + l16;
                if (n >= FFI) {
                    if (n < YSLD) YS[(size_t)m * YSLD + n] = 0;   // zero pad cols
                    continue;
                }
                float v = aA[i][j][r] * gelu_exact(aG[i][j][r]);
                int dr = (n < CH1) ? m : m + 1024;
                if (dr < TOK) YS[(size_t)dr * YSLD + n] = f2b(v);
                if (n >= CH1 && m < 1024) YS[(size_t)m * YSLD + n] = 0;
            }
        }
    }
}

// --------------------------------------------------- spatial attention (MFMA flash)
__global__ __launch_bounds__(256) void attn_sp_mfma(
    const ushort_t* __restrict__ Q,      // [16384][512] bf16 pre-scaled
    const ushort_t* __restrict__ KP,     // [16][1056][64]
    const ushort_t* __restrict__ VT,     // [16][64][1056]
    const ushort_t* __restrict__ BIASX,  // [8][1024][1152]
    ushort_t* __restrict__ O)            // [16384][512] bf16
{
    __shared__ __align__(16) ushort_t Ks[128 * 64];
    __shared__ __align__(16) ushort_t Vs[64 * 128];
    __shared__ __align__(16) ushort_t PT[4][16 * 136];
    int lin = blockIdx.x;
    int xcd = lin & 7, idx = lin >> 3;
    int frame = xcd * 2 + (idx >> 6);
    int qt = idx & 63;
    int q0 = qt * 16;
    int tid = threadIdx.x, lane = tid & 63, wid = tid >> 6;
    int quad = lane >> 4, l16 = lane & 15;
    ushort_t* PTw = &PT[wid][0];

    bf16x8 aQ[2][2];
    const ushort_t* brow[2];
    #pragma unroll
    for (int i = 0; i < 2; ++i) {
        int h = wid * 2 + i;
        const ushort_t* qp = Q + (size_t)(frame * 1024 + q0 + l16) * 512 + h * 64 + quad * 8;
        aQ[i][0] = *(const bf16x8*)qp;
        aQ[i][1] = *(const bf16x8*)(qp + 32);
        brow[i] = BIASX + ((size_t)h * 1024 + q0 + l16) * BSTRIDE;
    }
    f32x4 Oc[2][4];
    float mcol[2], lcol[2];
    #pragma unroll
    for (int i = 0; i < 2; ++i) {
        #pragma unroll
        for (int nt = 0; nt < 4; ++nt) { Oc[i][nt][0]=0.f; Oc[i][nt][1]=0.f; Oc[i][nt][2]=0.f; Oc[i][nt][3]=0.f; }
        mcol[i] = -1.0e30f; lcol[i] = 0.f;
    }

    for (int jt = 0; jt < 9; ++jt) {
        __syncthreads();
        #pragma unroll
        for (int r = 0; r < 4; ++r) {
            int L = wid * 256 + r * 64 + lane;
            int c = L >> 3, gp = L & 7, gg = gp ^ (c & 7);
            int jj = jt * 128 + c; if (jj > KVPAD - 1) jj = KVPAD - 1;
            gload_lds16(KP + ((size_t)frame * KVPAD + jj) * 64 + gg * 8, &Ks[(wid * 256 + r * 64) * 8]);
        }
        #pragma unroll
        for (int r = 0; r < 4; ++r) {
            int L = wid * 256 + r * 64 + lane;
            int d = L >> 4, cgp = L & 15;
            int cg = (cgp & 8) | ((cgp & 7) ^ (d & 7));
            int col = jt * 128 + cg * 8; if (col > KVPAD - 8) col = KVPAD - 8;
            gload_lds16(VT + ((size_t)frame * 64 + d) * KVPAD + col, &Vs[(wid * 256 + r * 64) * 8]);
        }
        __syncthreads();
        f32x4 S[2][8];
        #pragma unroll
        for (int i = 0; i < 2; ++i)
            #pragma unroll
            for (int j = 0; j < 8; ++j) { S[i][j][0]=0.f; S[i][j][1]=0.f; S[i][j][2]=0.f; S[i][j][3]=0.f; }
        #pragma unroll
        for (int j = 0; j < 8; ++j) {
            int c = j * 16 + l16;
            #pragma unroll
            for (int ks = 0; ks < 2; ++ks) {
                bf16x8 kb = *(bf16x8*)&Ks[(c * 8 + ((ks * 4 + quad) ^ (c & 7))) * 8];
                S[0][j] = __builtin_amdgcn_mfma_f32_16x16x32_bf16(kb, aQ[0][ks], S[0][j], 0, 0, 0);
                S[1][j] = __builtin_amdgcn_mfma_f32_16x16x32_bf16(kb, aQ[1][ks], S[1][j], 0, 0, 0);
            }
        }
        #pragma unroll
        for (int i = 0; i < 2; ++i) {
            #pragma unroll
            for (int j = 0; j < 8; ++j) {
                int kbase = jt * 128 + j * 16 + quad * 4;
                uint2 bv = *(const uint2*)(brow[i] + kbase);
                S[i][j][0] += b2f((ushort_t)(bv.x & 0xffffu));
                S[i][j][1] += b2f((ushort_t)(bv.x >> 16));
                S[i][j][2] += b2f((ushort_t)(bv.y & 0xffffu));
                S[i][j][3] += b2f((ushort_t)(bv.y >> 16));
            }
        }
        float alpha[2];
        #pragma unroll
        for (int i = 0; i < 2; ++i) {
            float mx = S[i][0][0];
            #pragma unroll
            for (int j = 0; j < 8; ++j)
                #pragma unroll
                for (int r = 0; r < 4; ++r) mx = fmaxf(mx, S[i][j][r]);
            mx = fmaxf(mx, __shfl_xor(mx, 16, 64));
            mx = fmaxf(mx, __shfl_xor(mx, 32, 64));
            float mnew = fmaxf(mcol[i], mx);
            alpha[i] = __expf(mcol[i] - mnew);
            mcol[i] = mnew;
            float rs = 0.f;
            #pragma unroll
            for (int j = 0; j < 8; ++j)
                #pragma unroll
                for (int r = 0; r < 4; ++r) {
                    float p = __expf(S[i][j][r] - mnew);
                    S[i][j][r] = p;
                    rs += p;
                }
            rs += __shfl_xor(rs, 16, 64);
            rs += __shfl_xor(rs, 32, 64);
            lcol[i] = lcol[i] * alpha[i] + rs;
        }
        #pragma unroll
        for (int i = 0; i < 2; ++i) {
            #pragma unroll
            for (int r = 0; r < 4; ++r) {
                float ar = __shfl(alpha[i], quad * 4 + r, 64);
                #pragma unroll
                for (int nt = 0; nt < 4; ++nt) Oc[i][nt][r] *= ar;
            }
        }
        #pragma unroll
        for (int i = 0; i < 2; ++i) {
            #pragma unroll
            for (int j = 0; j < 8; ++j) {
                u32 u0 = __float_as_uint(S[i][j][0]) + 0x8000u;
                u32 u1 = __float_as_uint(S[i][j][1]) + 0x8000u;
                u32 u2 = __float_as_uint(S[i][j][2]) + 0x8000u;
                u32 u3 = __float_as_uint(S[i][j][3]) + 0x8000u;
                uint2 pk;
                pk.x = (u0 >> 16) | (u1 & 0xffff0000u);
                pk.y = (u2 >> 16) | (u3 & 0xffff0000u);
                *(uint2*)&PTw[l16 * 136 + j * 16 + quad * 4] = pk;
            }
            #pragma unroll
            for (int ks = 0; ks < 4; ++ks) {
                bf16x8 pa = *(bf16x8*)&PTw[l16 * 136 + ks * 32 + quad * 8];
                #pragma unroll
                for (int nt = 0; nt < 4; ++nt) {
                    int d = nt * 16 + l16;
                    int cg = ks * 4 + quad;
                    int phys = (cg & 8) | ((cg & 7) ^ (d & 7));
                    bf16x8 vb = *(bf16x8*)&Vs[(d * 16 + phys) * 8];
                    Oc[i][nt] = __builtin_amdgcn_mfma_f32_16x16x32_bf16(pa, vb, Oc[i][nt], 0, 0, 0);
                }
            }
        }
    }
    #pragma unroll
    for (int i = 0; i < 2; ++i) {
        int h = wid * 2 + i;
        #pragma unroll
        for (int r = 0; r < 4; ++r) {
            float linv = 1.f / __shfl(lcol[i], quad * 4 + r, 64);
            int ql = quad * 4 + r;
            #pragma unroll
            for (int nt = 0; nt < 4; ++nt) {
                int d = nt * 16 + l16;
                O[(size_t)(frame * 1024 + q0 + ql) * 512 + h * 64 + d] = f2b(Oc[i][nt][r] * linv);
            }
        }
    }
}

// ---------------------------------------------------------------- temporal attention
__global__ __launch_bounds__(256) void attn_tp_kernel(
    const ushort_t* __restrict__ q, const ushort_t* __restrict__ kv,
    const float* __restrict__ nullkv, const float* __restrict__ nullbias,
    const float* __restrict__ table, ushort_t* __restrict__ out)
{
    __shared__ float qs[16][512];
    __shared__ float ks[17][64];
    __shared__ float vs[17][64];
    __shared__ float sc[8][16][17];
    int b = blockIdx.x;
    int t = threadIdx.x;
    for (int e = t; e < 16 * 512; e += 256) {
        int f = e >> 9, c = e & 511;
        qs[f][c] = b2f(q[(size_t)(b * 16 + f) * 512 + c]);
    }
    for (int e = t; e < 17 * 64; e += 256) {
        int j = e >> 6, d = e & 63;
        ks[j][d] = (j == 0) ? nullkv[d]      : b2f(kv[(size_t)(b * 16 + j - 1) * 128 + d]);
        vs[j][d] = (j == 0) ? nullkv[64 + d] : b2f(kv[(size_t)(b * 16 + j - 1) * 128 + 64 + d]);
    }
    __syncthreads();
    for (int e = t; e < 8 * 16 * 17; e += 256) {
        int h = e / 272, rem = e - h * 272;
        int i = rem / 17, j = rem - i * 17;
        float acc = 0.f;
        for (int d = 0; d < 64; ++d) acc += qs[i][h * 64 + d] * ks[j][d];
        float bias = (j == 0) ? nullbias[h] : table[(i - (j - 1) + 15) * 8 + h];
        sc[h][i][j] = acc + bias;
    }
    __syncthreads();
    if (t < 128) {
        int h = t >> 4, i = t & 15;
        float mx = -1e30f;
        for (int j = 0; j < 17; ++j) mx = fmaxf(mx, sc[h][i][j]);
        float s = 0.f;
        for (int j = 0; j < 17; ++j) { float p = __expf(sc[h][i][j] - mx); sc[h][i][j] = p; s += p; }
        float inv = 1.f / s;
        for (int j = 0; j < 17; ++j) sc[h][i][j] *= inv;
    }
    __syncthreads();
    for (int e = t; e < 16 * 512; e += 256) {
        int i = e >> 9, c = e & 511;
        int h = c >> 6, d = c & 63;
        float acc = 0.f;
        #pragma unroll
        for (int j = 0; j < 17; ++j) acc += sc[h][i][j] * vs[j][d];
        out[(size_t)(b * 16 + i) * 512 + c] = f2b(acc);
    }
}

// ------------------------- FF shift-LN row stats from bf16 YS: (mean*rstd, rstd)
__global__ __launch_bounds__(256) void rowstats_bf16_kernel(
    const ushort_t* __restrict__ YS, float* __restrict__ stats)
{
    __shared__ float r1[4], r2[4];
    int r = blockIdx.x, t = threadIdx.x;
    const ushort_t* row = YS + (size_t)r * YSLD;
    float s = 0.f, s2 = 0.f;
    for (int c = t; c < FFI; c += 256) {
        float v = b2f(row[c]);
        s += v; s2 += v * v;
    }
    #pragma unroll
    for (int o = 32; o > 0; o >>= 1) { s += __shfl_down(s, o, 64); s2 += __shfl_down(s2, o, 64); }
    if ((t & 63) == 0) { r1[t >> 6] = s; r2[t >> 6] = s2; }
    __syncthreads();
    float S  = r1[0] + r1[1] + r1[2] + r1[3];
    float S2 = r2[0] + r2[1] + r2[2] + r2[3];
    float mean = S * (1.f / 1365.f);
    float var  = S2 * (1.f / 1365.f) - mean * mean;
    float rstd = rsqrtf(fmaxf(var, 1e-5f));
    if (t == 0) { stats[2 * r] = mean * rstd; stats[2 * r + 1] = rstd; }
}

// --------------------- colsum[n] = sum_k W'[n][k]  (rows of converted W')
__global__ __launch_bounds__(64) void colsum_kernel(
    const ushort_t* __restrict__ Wt, float* __restrict__ colsum)
{
    int n = blockIdx.x, t = threadIdx.x;
    const ushort_t* row = Wt + (size_t)n * YSLD;
    float s = 0.f;
    for (int k = t; k < YSLD; k += 64) s += b2f(row[k]);
    #pragma unroll
    for (int o = 32; o > 0; o >>= 1) s += __shfl_down(s, o, 64);
    if (t == 0) colsum[n] = s;
}

// ================================================================ launcher
extern "C" void kernel_launch(void* const* d_in, const int* in_sizes, int n_in,
                              void* d_out, int out_size, void* d_ws, size_t ws_size,
                              hipStream_t stream)
{
    const float* x          = (const float*)d_in[0];
    const float* sa_ln_w    = (const float*)d_in[1];
    const float* sa_ln_b    = (const float*)d_in[2];
    const float* sa_wq      = (const float*)d_in[3];
    const float* sa_wkv     = (const float*)d_in[4];
    const float* sa_null_kv = (const float*)d_in[5];
    const float* sa_null_b  = (const float*)d_in[6];
    const float* sa_wout    = (const float*)d_in[7];
    const float* sa_oln_w   = (const float*)d_in[8];
    const float* sa_oln_b   = (const float*)d_in[9];
    const float* ta_ln_w    = (const float*)d_in[10];
    const float* ta_ln_b    = (const float*)d_in[11];
    const float* ta_wq      = (const float*)d_in[12];
    const float* ta_wkv     = (const float*)d_in[13];
    const float* ta_null_kv = (const float*)d_in[14];
    const float* ta_null_b  = (const float*)d_in[15];
    const float* ta_wout    = (const float*)d_in[16];
    const float* ta_oln_w   = (const float*)d_in[17];
    const float* ta_oln_b   = (const float*)d_in[18];
    const float* sp_w0      = (const float*)d_in[19];
    const float* sp_b0      = (const float*)d_in[20];
    const float* sp_w1      = (const float*)d_in[21];
    const float* sp_b1      = (const float*)d_in[22];
    const float* sp_w2      = (const float*)d_in[23];
    const float* sp_b2      = (const float*)d_in[24];
    const float* tp_w0      = (const float*)d_in[25];
    const float* tp_b0      = (const float*)d_in[26];
    const float* tp_w1      = (const float*)d_in[27];
    const float* tp_b1      = (const float*)d_in[28];
    const float* tp_w2      = (const float*)d_in[29];
    const float* tp_b2      = (const float*)d_in[30];
    const float* ff_win     = (const float*)d_in[31];
    const float* ff_g       = (const float*)d_in[32];
    const float* ff_wout    = (const float*)d_in[33];

    char* ws = (char*)d_ws;
    // regions (bytes)
    float*    RES   = (float*)(ws + 0);                        // residual, spatial layout
    ushort_t* XN16  = (ushort_t*)(ws + 33554432);              // xn / x2 bf16
    ushort_t* Q16   = (ushort_t*)(ws + 50331648);              // spatial Q bf16 (spatial phase)
    float*    RT    = (float*)(ws + 50331648);                 // temporal residual f32 (temporal phase)
    ushort_t* YS    = (ushort_t*)(ws + 50331648);              // FF shifted act bf16 [16384][1376]
    ushort_t* WSA   = (ushort_t*)(ws + 67108864);              // spatial weights (dead by FF)
    ushort_t* KP    = (ushort_t*)(ws + 83886080);              // 16x1056x64 bf16 (spatial)
    ushort_t* VTb   = (ushort_t*)(ws + 86048768);              // 16x64x1056 bf16 (spatial)
    ushort_t* KV16  = (ushort_t*)(ws + 83886080);              // temporal KV bf16
    ushort_t* WTA   = (ushort_t*)(ws + 90439680);              // temporal weights
    ushort_t* AO16  = (ushort_t*)(ws + 92274688);              // attn out bf16 (dead by FF)
    ushort_t* BI    = (ushort_t*)(ws + 96468992);              // FF interleaved W [2816][512] ends 99,352,576
    ushort_t* WFFB  = (ushort_t*)(ws + 99352576);              // W' = (ff_wout*g)^T [512][1376] ends 100,761,600
    ushort_t* BIAS16= (ushort_t*)(ws + 109051904);             // spatial bias bf16 (PRJ region)
    float*    PRJ   = (float*)(ws + 109051904);                // proj out f32
    ushort_t* Q16t  = (ushort_t*)(ws + 109051904);             // temporal Q bf16
    float*    STATS = (float*)(ws + 142606336);                // 16384 x (mean*rstd, rstd)
    float*    SPT   = (float*)(ws + 142737408);                // spatial CPB table (spatial phase)
    float*    COLSUM= (float*)(ws + 142737408);                // colsum[512] (FF phase, dead SPT)
    float*    TPT   = (float*)(ws + 142864448);

    ushort_t* WQ_T  = WSA;                 // [512][512]
    ushort_t* WKV_T = WSA + 262144;        // [128][512]
    ushort_t* WO_T  = WSA + 327680;        // [512][512]
    ushort_t* tWQ_T  = WTA;
    ushort_t* tWKV_T = WTA + 262144;
    ushort_t* tWO_T  = WTA + 327680;

    dim3 blk(256);

    // bias tables
    cpb_kernel<<<dim3(3969), blk, 0, stream>>>(sp_w0, sp_b0, sp_w1, sp_b1, sp_w2, sp_b2, SPT, 0);
    cpb_kernel<<<dim3(31),   blk, 0, stream>>>(tp_w0, tp_b0, tp_w1, tp_b1, tp_w2, tp_b2, TPT, 1);
    bias_sp_kernel<<<dim3(1024, 8), blk, 0, stream>>>(SPT, sa_null_b, BIAS16);
    kvinit_kernel<<<dim3(16), blk, 0, stream>>>(sa_null_kv, KP, VTb);

    // ---------------- spatial ----------------
    wcvt_kernel<<<dim3(16, 16), blk, 0, stream>>>(sa_wq, 512, 0, WQ_T, 512, 512, 512, nullptr, 512);
    wcvt_kernel<<<dim3(4, 16),  blk, 0, stream>>>(sa_wkv, 128, 0, WKV_T, 512, 512, 128, nullptr, 128);
    wcvt_kernel<<<dim3(16, 16), blk, 0, stream>>>(sa_wout, 512, 0, WO_T, 512, 512, 512, nullptr, 512);
    transpose_in_kernel<<<dim3(512, 16), blk, 0, stream>>>(x, RES);
    ln_bf16_kernel<<<dim3(TOK), blk, 0, stream>>>(RES, XN16, sa_ln_w, sa_ln_b);
    gemm_mfma<3><<<dim3(512), blk, 0, stream>>>(XN16, 512, WQ_T, 512,
        nullptr, Q16, 512, TOK, 512, 512, 0.125f, 4, nullptr, nullptr, nullptr, nullptr, nullptr, nullptr);
    gemm_mfma<4><<<dim3(128), blk, 0, stream>>>(XN16, 512, WKV_T, 512,
        nullptr, nullptr, 0, TOK, 128, 512, 1.0f, 1, nullptr, nullptr, nullptr, nullptr, KP, VTb);
    attn_sp_mfma<<<dim3(1024), blk, 0, stream>>>(Q16, KP, VTb, BIAS16, AO16);
    gemm_mfma<0><<<dim3(512), blk, 0, stream>>>(AO16, 512, WO_T, 512,
        PRJ, nullptr, 512, TOK, 512, 512, 1.0f, 4, nullptr, nullptr, nullptr, nullptr, nullptr, nullptr);
    ln_add_kernel<<<dim3(TOK), blk, 0, stream>>>(PRJ, RES, sa_oln_w, sa_oln_b);

    // ---------------- temporal ----------------
    permute0_kernel<<<dim3(TOK), dim3(128), 0, stream>>>(RES, RT);
    wcvt_kernel<<<dim3(16, 16), blk, 0, stream>>>(ta_wq, 512, 0, tWQ_T, 512, 512, 512, nullptr, 512);
    wcvt_kernel<<<dim3(4, 16),  blk, 0, stream>>>(ta_wkv, 128, 0, tWKV_T, 512, 512, 128, nullptr, 128);
    wcvt_kernel<<<dim3(16, 16), blk, 0, stream>>>(ta_wout, 512, 0, tWO_T, 512, 512, 512, nullptr, 512);
    ln_bf16_kernel<<<dim3(TOK), blk, 0, stream>>>(RT, XN16, ta_ln_w, ta_ln_b);
    gemm_mfma<3><<<dim3(512), blk, 0, stream>>>(XN16, 512, tWQ_T, 512,
        nullptr, Q16t, 512, TOK, 512, 512, 0.125f, 4, nullptr, nullptr, nullptr, nullptr, nullptr, nullptr);
    gemm_mfma<3><<<dim3(128), blk, 0, stream>>>(XN16, 512, tWKV_T, 512,
        nullptr, KV16, 128, TOK, 128, 512, 1.0f, 1, nullptr, nullptr, nullptr, nullptr, nullptr, nullptr);
    attn_tp_kernel<<<dim3(1024), blk, 0, stream>>>(Q16t, KV16, ta_null_kv, ta_null_b, TPT, AO16);
    gemm_mfma<0><<<dim3(512), blk, 0, stream>>>(AO16, 512, tWO_T, 512,
        PRJ, nullptr, 512, TOK, 512, 512, 1.0f, 4, nullptr, nullptr, nullptr, nullptr, nullptr, nullptr);
    ln_add_kernel<<<dim3(TOK), blk, 0, stream>>>(PRJ, RT, ta_oln_w, ta_oln_b);
    permute1_dual_kernel<<<dim3(TOK), dim3(128), 0, stream>>>(RT, RES, XN16);

    // ---------------- feed-forward ----------------
    // interleaved weights: BI row 2n = a-half, 2n+1 = gate-half; pad rows zeroed
    wcvt_kernel<<<dim3(44, 16), blk, 0, stream>>>(ff_win, 2730, 0,   BI,       1024, 512, FFI, nullptr, 1408);
    wcvt_kernel<<<dim3(44, 16), blk, 0, stream>>>(ff_win, 2730, FFI, BI + 512, 1024, 512, FFI, nullptr, 1408);
    wcvt_kernel<<<dim3(16, 43), blk, 0, stream>>>(ff_wout, 512, 0, WFFB, YSLD, FFI, 512, ff_g, 512);
    colsum_kernel<<<dim3(512), dim3(64), 0, stream>>>(WFFB, COLSUM);
    ff_gemm_fused<<<dim3(2816), blk, 0, stream>>>(XN16, BI, YS);
    rowstats_bf16_kernel<<<dim3(TOK), blk, 0, stream>>>(YS, STATS);
    gemm_mfma<5><<<dim3(512), blk, 0, stream>>>(YS, YSLD, WFFB, YSLD,
        nullptr, nullptr, 0, TOK, 512, YSLD, 1.0f, 4, STATS, COLSUM, RES, (float*)d_out, nullptr, nullptr);
}

// Round 9
// 909.570 us; speedup vs baseline: 5.6575x; 1.0066x over previous
//
#include <hip/hip_runtime.h>
#include <math.h>

#define TOK 16384
#define DIMC 512
#define FFI 1365
#define CH1 683
#define YSLD 1376         // YS row stride (bf16 elements, 16B aligned)
#define KVPAD 1056        // padded key count for spatial attn (mult of 8)
#define BSTRIDE 1152      // BIASX row stride (cols: 0=null, 1..1024=keys, rest=mask)
#define MASKB (-30000.f)  // softmax mask bias (bf16-safe, no near-inf)

typedef unsigned int u32;
typedef unsigned short ushort_t;
typedef __attribute__((ext_vector_type(8))) short bf16x8;
typedef __attribute__((ext_vector_type(4))) float f32x4;

__device__ inline ushort_t f2b(float x) {
    u32 u = __float_as_uint(x);
    u32 r = (u + 0x7fffu + ((u >> 16) & 1u)) >> 16;
    return (ushort_t)r;
}
__device__ inline float b2f(ushort_t u) { return __uint_as_float(((u32)u) << 16); }

__device__ inline void gload_lds16(const void* g, void* l) {
    __builtin_amdgcn_global_load_lds(
        (const __attribute__((address_space(1))) u32*)g,
        (__attribute__((address_space(3))) u32*)l, 16, 0, 0);
}

__device__ inline float gelu_exact(float x) {
    return 0.5f * x * (1.f + erff(x * 0.70710678118654752f));
}

// ---------------------------------------------------------------- CPB MLP
__global__ __launch_bounds__(256) void cpb_kernel(
    const float* __restrict__ w0, const float* __restrict__ b0,
    const float* __restrict__ w1, const float* __restrict__ b1,
    const float* __restrict__ w2, const float* __restrict__ b2,
    float* __restrict__ table, int mode)
{
    __shared__ float t0[256];
    __shared__ float t1[256];
    int r = blockIdx.x;
    int t = threadIdx.x;
    float c0, c1;
    if (mode == 0) { c0 = (float)(r / 63 - 31); c1 = (float)(r % 63 - 31); }
    else           { c0 = (float)(r - 15);      c1 = 0.f; }
    float a = c0 * w0[t] + b0[t];
    if (mode == 0) a += c1 * w0[256 + t];
    t0[t] = a / (1.f + __expf(-a));
    __syncthreads();
    float s = b1[t];
    for (int k = 0; k < 256; ++k) s += t0[k] * w1[k * 256 + t];
    t1[t] = s / (1.f + __expf(-s));
    __syncthreads();
    if (t < 8) {
        float o = b2[t];
        for (int k = 0; k < 256; ++k) o += t1[k] * w2[k * 8 + t];
        table[r * 8 + t] = o;
    }
}

// ------------------------------- materialize spatial bias bf16, padded layout
__global__ __launch_bounds__(256) void bias_sp_kernel(
    const float* __restrict__ tab, const float* __restrict__ nullbias,
    ushort_t* __restrict__ out)
{
    int pi = blockIdx.x, h = blockIdx.y;
    int phi = pi >> 5, pwi = pi & 31;
    ushort_t* row = out + ((size_t)h * 1024 + pi) * BSTRIDE;
    for (int c = threadIdx.x; c < BSTRIDE; c += 256) {
        float v;
        if (c == 0) v = nullbias[h];
        else if (c <= 1024) {
            int pj = c - 1;
            int phj = pj >> 5, pwj = pj & 31;
            int idx = (phi - phj + 31) * 63 + (pwi - pwj + 31);
            v = tab[idx * 8 + h];
        } else v = MASKB;
        row[c] = f2b(v);
    }
}

// -------------------------------------------- KP/VT pad+null init. grid 16
__global__ __launch_bounds__(256) void kvinit_kernel(
    const float* __restrict__ nullkv, ushort_t* __restrict__ KP, ushort_t* __restrict__ VT)
{
    int f = blockIdx.x, t = threadIdx.x;
    for (int e = t; e < 32 * 64; e += 256) {
        int rr = e >> 6, d = e & 63;
        int row = (rr == 0) ? 0 : (1024 + rr);
        KP[((size_t)f * KVPAD + row) * 64 + d] = (rr == 0) ? f2b(nullkv[d]) : (ushort_t)0;
    }
    for (int e = t; e < 64 * 32; e += 256) {
        int d = e >> 5, cc = e & 31;
        int col = (cc == 0) ? 0 : (1024 + cc);
        VT[((size_t)f * 64 + d) * KVPAD + col] = (cc == 0) ? f2b(nullkv[64 + d]) : (ushort_t)0;
    }
}

// ---------------- weight convert: W[K][ldw] (col window c0) -> Bt[N][Kp] bf16
// Writes rows n < Nwrite (zeros for n >= Ncols or k >= K) — pad rows are clean.
__global__ __launch_bounds__(256) void wcvt_kernel(
    const float* __restrict__ W, int ldw, int c0,
    ushort_t* __restrict__ Bt, int Kp, int K, int Ncols,
    const float* __restrict__ gv, int Nwrite)
{
    __shared__ float tile[32][33];
    int nb = blockIdx.x * 32, kb = blockIdx.y * 32;
    int tx = threadIdx.x & 31, ty = threadIdx.x >> 5;
    #pragma unroll
    for (int it = 0; it < 4; ++it) {
        int k = kb + ty + it * 8, n = nb + tx;
        float v = (k < K && n < Ncols) ? W[(size_t)k * ldw + c0 + n] : 0.f;
        if (gv && k < K) v *= gv[k];
        tile[ty + it * 8][tx] = v;
    }
    __syncthreads();
    #pragma unroll
    for (int it = 0; it < 4; ++it) {
        int n = nb + ty + it * 8, k = kb + tx;
        if (n < Nwrite && k < Kp) Bt[(size_t)n * Kp + k] = f2b(tile[tx][ty + it * 8]);
    }
}

// ---------------------------------------------------- (C,T) -> (T,C) transpose
__global__ __launch_bounds__(256) void transpose_in_kernel(
    const float* __restrict__ x, float* __restrict__ dst)
{
    __shared__ float tile[32][33];
    int t0b = blockIdx.x * 32, c0b = blockIdx.y * 32;
    int tx = threadIdx.x & 31, ty = threadIdx.x >> 5;
    #pragma unroll
    for (int it = 0; it < 4; ++it) {
        int c = ty + it * 8;
        tile[c][tx] = x[(size_t)(c0b + c) * TOK + t0b + tx];
    }
    __syncthreads();
    #pragma unroll
    for (int it = 0; it < 4; ++it) {
        int tr = ty + it * 8;
        dst[(size_t)(t0b + tr) * DIMC + c0b + tx] = tile[tx][tr];
    }
}

// ---------------------------------------------------------------- LayerNorm → bf16
__global__ __launch_bounds__(256) void ln_bf16_kernel(
    const float* __restrict__ in, ushort_t* __restrict__ out,
    const float* __restrict__ w, const float* __restrict__ b)
{
    __shared__ float r1[4], r2[4];
    size_t base = (size_t)blockIdx.x * DIMC;
    int t = threadIdx.x;
    float x0 = in[base + t], x1 = in[base + 256 + t];
    float s = x0 + x1, s2 = x0 * x0 + x1 * x1;
    #pragma unroll
    for (int o = 32; o > 0; o >>= 1) { s += __shfl_down(s, o, 64); s2 += __shfl_down(s2, o, 64); }
    if ((t & 63) == 0) { r1[t >> 6] = s; r2[t >> 6] = s2; }
    __syncthreads();
    float mean = (r1[0] + r1[1] + r1[2] + r1[3]) * (1.f / 512.f);
    float ex2  = (r2[0] + r2[1] + r2[2] + r2[3]) * (1.f / 512.f);
    float rstd = rsqrtf(ex2 - mean * mean + 1e-5f);
    out[base + t]       = f2b((x0 - mean) * rstd * w[t] + b[t]);
    out[base + 256 + t] = f2b((x1 - mean) * rstd * w[256 + t] + b[256 + t]);
}

// LN(proj f32) + residual in place
__global__ __launch_bounds__(256) void ln_add_kernel(
    const float* __restrict__ proj, float* __restrict__ io,
    const float* __restrict__ w, const float* __restrict__ b)
{
    __shared__ float r1[4], r2[4];
    size_t base = (size_t)blockIdx.x * DIMC;
    int t = threadIdx.x;
    float x0 = proj[base + t], x1 = proj[base + 256 + t];
    float s = x0 + x1, s2 = x0 * x0 + x1 * x1;
    #pragma unroll
    for (int o = 32; o > 0; o >>= 1) { s += __shfl_down(s, o, 64); s2 += __shfl_down(s2, o, 64); }
    if ((t & 63) == 0) { r1[t >> 6] = s; r2[t >> 6] = s2; }
    __syncthreads();
    float mean = (r1[0] + r1[1] + r1[2] + r1[3]) * (1.f / 512.f);
    float ex2  = (r2[0] + r2[1] + r2[2] + r2[3]) * (1.f / 512.f);
    float rstd = rsqrtf(ex2 - mean * mean + 1e-5f);
    io[base + t]       += (x0 - mean) * rstd * w[t] + b[t];
    io[base + 256 + t] += (x1 - mean) * rstd * w[256 + t] + b[256 + t];
}

// spatial->temporal row permute (f32)
__global__ __launch_bounds__(128) void permute0_kernel(
    const float* __restrict__ src, float* __restrict__ dst)
{
    int rd = blockIdx.x;
    int rs = (rd & 15) * 1024 + (rd >> 4);
    ((float4*)(dst + (size_t)rd * DIMC))[threadIdx.x] =
        ((const float4*)(src + (size_t)rs * DIMC))[threadIdx.x];
}

// temporal->spatial permute, dual output f32 + bf16
__global__ __launch_bounds__(128) void permute1_dual_kernel(
    const float* __restrict__ src, float* __restrict__ dst, ushort_t* __restrict__ dstb)
{
    int rd = blockIdx.x;
    int rs = (rd & 1023) * 16 + (rd >> 10);
    float4 v = ((const float4*)(src + (size_t)rs * DIMC))[threadIdx.x];
    ((float4*)(dst + (size_t)rd * DIMC))[threadIdx.x] = v;
    u32 lo = (u32)f2b(v.x) | ((u32)f2b(v.y) << 16);
    u32 hi = (u32)f2b(v.z) | ((u32)f2b(v.w) << 16);
    ((uint2*)(dstb + (size_t)rd * DIMC))[threadIdx.x] = make_uint2(lo, hi);
}

// ---------------------------------------------------------------- MFMA GEMM
// 1-D grid of nx*16*8 blocks. XCD-aware swizzle: xcd = lin&7 owns m-tiles
// [xcd*16, xcd*16+16) for ALL nx n-tiles -> per-XCD L2-resident A band.
template<int EPI>
__global__ __launch_bounds__(256) void gemm_mfma(
    const ushort_t* __restrict__ A, int lda,
    const ushort_t* __restrict__ Bt, int Kp,
    float* __restrict__ C, ushort_t* __restrict__ Cb, int ldc,
    int M, int N, int K, float scale, int nx,
    const float* __restrict__ stats, const float* __restrict__ g,
    const float* __restrict__ resid, float* __restrict__ outT,
    ushort_t* __restrict__ KPo, ushort_t* __restrict__ VTo)
{
    __shared__ __align__(16) ushort_t As[4 * 128 * 8];
    __shared__ __align__(16) ushort_t Bs[4 * 128 * 8];
    int lin = blockIdx.x;
    int xcd = lin & 7, idx = lin >> 3;
    int m0 = (xcd * 16 + (idx & 15)) * 128;
    int n0 = (idx >> 4) * 128;
    int tid = threadIdx.x, lane = tid & 63, wid = tid >> 6;
    int wy = wid >> 1, wx = wid & 1, quad = lane >> 4, l16 = lane & 15;
    bool bfull = (n0 + 128 <= N);
    f32x4 acc[4][4];
    #pragma unroll
    for (int i = 0; i < 4; ++i)
        #pragma unroll
        for (int j = 0; j < 4; ++j) { acc[i][j][0]=0.f; acc[i][j][1]=0.f; acc[i][j][2]=0.f; acc[i][j][3]=0.f; }

    for (int k0 = 0; k0 < K; k0 += 32) {
        if (k0) __syncthreads();
        #pragma unroll
        for (int r = 0; r < 2; ++r) {
            int c = wid * 128 + r * 64 + lane;
            const ushort_t* src = A + (size_t)(m0 + (c & 127)) * lda + k0 + (c >> 7) * 8;
            gload_lds16(src, &As[(wid * 128 + r * 64) * 8]);
        }
        if (bfull) {
            #pragma unroll
            for (int r = 0; r < 2; ++r) {
                int c = wid * 128 + r * 64 + lane;
                const ushort_t* src = Bt + (size_t)(n0 + (c & 127)) * Kp + k0 + (c >> 7) * 8;
                gload_lds16(src, &Bs[(wid * 128 + r * 64) * 8]);
            }
        } else {
            #pragma unroll
            for (int r = 0; r < 2; ++r) {
                int c = tid + r * 256;
                int kg = c >> 7, nloc = c & 127;
                bf16x8 v;
                if (n0 + nloc < N) v = *(const bf16x8*)(Bt + (size_t)(n0 + nloc) * Kp + k0 + kg * 8);
                else { for (int e = 0; e < 8; ++e) v[e] = 0; }
                *(bf16x8*)&Bs[c * 8] = v;
            }
        }
        __syncthreads();
        bf16x8 af[4], bfr[4];
        #pragma unroll
        for (int i = 0; i < 4; ++i) af[i] = *(bf16x8*)&As[(quad * 128 + wy * 64 + i * 16 + l16) * 8];
        #pragma unroll
        for (int j = 0; j < 4; ++j) bfr[j] = *(bf16x8*)&Bs[(quad * 128 + wx * 64 + j * 16 + l16) * 8];
        #pragma unroll
        for (int i = 0; i < 4; ++i)
            #pragma unroll
            for (int j = 0; j < 4; ++j)
                acc[i][j] = __builtin_amdgcn_mfma_f32_16x16x32_bf16(af[i], bfr[j], acc[i][j], 0, 0, 0);
    }
    #pragma unroll
    for (int i = 0; i < 4; ++i) {
        #pragma unroll
        for (int j = 0; j < 4; ++j) {
            #pragma unroll
            for (int r = 0; r < 4; ++r) {
                int m = m0 + wy * 64 + i * 16 + quad * 4 + r;
                int n = n0 + wx * 64 + j * 16 + l16;
                if (n >= N) continue;
                float v = acc[i][j][r] * scale;
                if (EPI == 0) {
                    C[(size_t)m * ldc + n] = v;
                } else if (EPI == 3) {
                    Cb[(size_t)m * ldc + n] = f2b(v);
                } else if (EPI == 4) {
                    int frame = m >> 10, tt = m & 1023;
                    if (n < 64) KPo[((size_t)frame * KVPAD + 1 + tt) * 64 + n] = f2b(v);
                    else        VTo[((size_t)frame * 64 + (n - 64)) * KVPAD + 1 + tt] = f2b(v);
                } else if (EPI == 5) {
                    float s0 = stats[2 * m], s1 = stats[2 * m + 1];
                    outT[(size_t)n * TOK + m] = v * s1 - s0 * g[n] + resid[(size_t)m * DIMC + n];
                }
            }
        }
    }
}

// ------------------------------------------- fused FF front GEMM (a & gate)
// 128m x 64n dual-output tile -> acc = 64 AGPR/thread. B from interleaved
// BI[2816][512] via pure global_load_lds. Grid 2816 = 8 XCD x 16 m x 22 n.
__global__ __launch_bounds__(256) void ff_gemm_fused(
    const ushort_t* __restrict__ A,
    const ushort_t* __restrict__ BI,
    ushort_t* __restrict__ YS)
{
    __shared__ __align__(16) ushort_t As[4 * 128 * 8];
    __shared__ __align__(16) ushort_t Bs[4 * 2 * 64 * 8];
    int lin = blockIdx.x;
    int xcd = lin & 7, idx = lin >> 3;
    int m0 = (xcd * 16 + (idx & 15)) * 128;
    int n0 = (idx >> 4) * 64;
    int tid = threadIdx.x, lane = tid & 63, wid = tid >> 6;
    int wy = wid >> 1, wx = wid & 1, quad = lane >> 4, l16 = lane & 15;
    f32x4 aA[4][2], aG[4][2];
    #pragma unroll
    for (int i = 0; i < 4; ++i)
        #pragma unroll
        for (int j = 0; j < 2; ++j) {
            aA[i][j][0]=0.f; aA[i][j][1]=0.f; aA[i][j][2]=0.f; aA[i][j][3]=0.f;
            aG[i][j][0]=0.f; aG[i][j][1]=0.f; aG[i][j][2]=0.f; aG[i][j][3]=0.f;
        }

    for (int k0 = 0; k0 < 512; k0 += 32) {
        if (k0) __syncthreads();
        #pragma unroll
        for (int r = 0; r < 2; ++r) {
            int c = wid * 128 + r * 64 + lane;
            gload_lds16(A + (size_t)(m0 + (c & 127)) * 512 + k0 + (c >> 7) * 8,
                        &As[(wid * 128 + r * 64) * 8]);
        }
        #pragma unroll
        for (int r = 0; r < 2; ++r) {
            gload_lds16(BI + (size_t)((n0 + lane) * 2 + r) * 512 + k0 + wid * 8,
                        &Bs[(wid * 128 + r * 64) * 8]);
        }
        __syncthreads();
        bf16x8 af[4], ba[2], bg[2];
        #pragma unroll
        for (int i = 0; i < 4; ++i) af[i] = *(bf16x8*)&As[(quad * 128 + wy * 64 + i * 16 + l16) * 8];
        #pragma unroll
        for (int j = 0; j < 2; ++j) {
            int nn = wx * 32 + j * 16 + l16;
            ba[j] = *(bf16x8*)&Bs[(quad * 128 + nn) * 8];
            bg[j] = *(bf16x8*)&Bs[(quad * 128 + 64 + nn) * 8];
        }
        #pragma unroll
        for (int i = 0; i < 4; ++i)
            #pragma unroll
            for (int j = 0; j < 2; ++j) {
                aA[i][j] = __builtin_amdgcn_mfma_f32_16x16x32_bf16(af[i], ba[j], aA[i][j], 0, 0, 0);
                aG[i][j] = __builtin_amdgcn_mfma_f32_16x16x32_bf16(af[i], bg[j], aG[i][j], 0, 0, 0);
            }
    }
    #pragma unroll
    for (int i = 0; i < 4; ++i) {
        #pragma unroll
        for (int j = 0; j < 2; ++j) {
            #pragma unroll
            for (int r = 0; r < 4; ++r) {
                int m = m0 + wy * 64 + i * 16 + quad * 4 + r;
                int n = n0 + wx * 32 + j * 16 + l16;
                if (n >= FFI) {
                    if (n < YSLD) YS[(size_t)m * YSLD + n] = 0;   // zero pad cols
                    continue;
                }
                float v = aA[i][j][r] * gelu_exact(aG[i][j][r]);
                int dr = (n < CH1) ? m : m + 1024;
                if (dr < TOK) YS[(size_t)dr * YSLD + n] = f2b(v);
                if (n >= CH1 && m < 1024) YS[(size_t)m * YSLD + n] = 0;
            }
        }
    }
}

// --------------------------------------------------- spatial attention (MFMA flash)
// ROUND-9 GRID REMAP: per XCD = q-tile band (8 qt) x ALL 16 frames, frame
// varying slowest. Bias is frame-independent & q-indexed -> per-XCD bias
// working set 18.9 MB -> 2.36 MB (L2-resident). lin&7=xcd; idx=lin>>3:
// qt = xcd*8 + (idx&7), frame = idx>>3.
__global__ __launch_bounds__(256) void attn_sp_mfma(
    const ushort_t* __restrict__ Q,      // [16384][512] bf16 pre-scaled
    const ushort_t* __restrict__ KP,     // [16][1056][64]
    const ushort_t* __restrict__ VT,     // [16][64][1056]
    const ushort_t* __restrict__ BIASX,  // [8][1024][1152]
    ushort_t* __restrict__ O)            // [16384][512] bf16
{
    __shared__ __align__(16) ushort_t Ks[128 * 64];
    __shared__ __align__(16) ushort_t Vs[64 * 128];
    __shared__ __align__(16) ushort_t PT[4][16 * 136];
    int lin = blockIdx.x;
    int xcd = lin & 7, idx = lin >> 3;
    int qt = xcd * 8 + (idx & 7);
    int frame = idx >> 3;
    int q0 = qt * 16;
    int tid = threadIdx.x, lane = tid & 63, wid = tid >> 6;
    int quad = lane >> 4, l16 = lane & 15;
    ushort_t* PTw = &PT[wid][0];

    bf16x8 aQ[2][2];
    const ushort_t* brow[2];
    #pragma unroll
    for (int i = 0; i < 2; ++i) {
        int h = wid * 2 + i;
        const ushort_t* qp = Q + (size_t)(frame * 1024 + q0 + l16) * 512 + h * 64 + quad * 8;
        aQ[i][0] = *(const bf16x8*)qp;
        aQ[i][1] = *(const bf16x8*)(qp + 32);
        brow[i] = BIASX + ((size_t)h * 1024 + q0 + l16) * BSTRIDE;
    }
    f32x4 Oc[2][4];
    float mcol[2], lcol[2];
    #pragma unroll
    for (int i = 0; i < 2; ++i) {
        #pragma unroll
        for (int nt = 0; nt < 4; ++nt) { Oc[i][nt][0]=0.f; Oc[i][nt][1]=0.f; Oc[i][nt][2]=0.f; Oc[i][nt][3]=0.f; }
        mcol[i] = -1.0e30f; lcol[i] = 0.f;
    }

    for (int jt = 0; jt < 9; ++jt) {
        __syncthreads();
        #pragma unroll
        for (int r = 0; r < 4; ++r) {
            int L = wid * 256 + r * 64 + lane;
            int c = L >> 3, gp = L & 7, gg = gp ^ (c & 7);
            int jj = jt * 128 + c; if (jj > KVPAD - 1) jj = KVPAD - 1;
            gload_lds16(KP + ((size_t)frame * KVPAD + jj) * 64 + gg * 8, &Ks[(wid * 256 + r * 64) * 8]);
        }
        #pragma unroll
        for (int r = 0; r < 4; ++r) {
            int L = wid * 256 + r * 64 + lane;
            int d = L >> 4, cgp = L & 15;
            int cg = (cgp & 8) | ((cgp & 7) ^ (d & 7));
            int col = jt * 128 + cg * 8; if (col > KVPAD - 8) col = KVPAD - 8;
            gload_lds16(VT + ((size_t)frame * 64 + d) * KVPAD + col, &Vs[(wid * 256 + r * 64) * 8]);
        }
        __syncthreads();
        f32x4 S[2][8];
        #pragma unroll
        for (int i = 0; i < 2; ++i)
            #pragma unroll
            for (int j = 0; j < 8; ++j) { S[i][j][0]=0.f; S[i][j][1]=0.f; S[i][j][2]=0.f; S[i][j][3]=0.f; }
        #pragma unroll
        for (int j = 0; j < 8; ++j) {
            int c = j * 16 + l16;
            #pragma unroll
            for (int ks = 0; ks < 2; ++ks) {
                bf16x8 kb = *(bf16x8*)&Ks[(c * 8 + ((ks * 4 + quad) ^ (c & 7))) * 8];
                S[0][j] = __builtin_amdgcn_mfma_f32_16x16x32_bf16(kb, aQ[0][ks], S[0][j], 0, 0, 0);
                S[1][j] = __builtin_amdgcn_mfma_f32_16x16x32_bf16(kb, aQ[1][ks], S[1][j], 0, 0, 0);
            }
        }
        #pragma unroll
        for (int i = 0; i < 2; ++i) {
            #pragma unroll
            for (int j = 0; j < 8; ++j) {
                int kbase = jt * 128 + j * 16 + quad * 4;
                uint2 bv = *(const uint2*)(brow[i] + kbase);
                S[i][j][0] += b2f((ushort_t)(bv.x & 0xffffu));
                S[i][j][1] += b2f((ushort_t)(bv.x >> 16));
                S[i][j][2] += b2f((ushort_t)(bv.y & 0xffffu));
                S[i][j][3] += b2f((ushort_t)(bv.y >> 16));
            }
        }
        float alpha[2];
        #pragma unroll
        for (int i = 0; i < 2; ++i) {
            float mx = S[i][0][0];
            #pragma unroll
            for (int j = 0; j < 8; ++j)
                #pragma unroll
                for (int r = 0; r < 4; ++r) mx = fmaxf(mx, S[i][j][r]);
            mx = fmaxf(mx, __shfl_xor(mx, 16, 64));
            mx = fmaxf(mx, __shfl_xor(mx, 32, 64));
            float mnew = fmaxf(mcol[i], mx);
            alpha[i] = __expf(mcol[i] - mnew);
            mcol[i] = mnew;
            float rs = 0.f;
            #pragma unroll
            for (int j = 0; j < 8; ++j)
                #pragma unroll
                for (int r = 0; r < 4; ++r) {
                    float p = __expf(S[i][j][r] - mnew);
                    S[i][j][r] = p;
                    rs += p;
                }
            rs += __shfl_xor(rs, 16, 64);
            rs += __shfl_xor(rs, 32, 64);
            lcol[i] = lcol[i] * alpha[i] + rs;
        }
        #pragma unroll
        for (int i = 0; i < 2; ++i) {
            #pragma unroll
            for (int r = 0; r < 4; ++r) {
                float ar = __shfl(alpha[i], quad * 4 + r, 64);
                #pragma unroll
                for (int nt = 0; nt < 4; ++nt) Oc[i][nt][r] *= ar;
            }
        }
        #pragma unroll
        for (int i = 0; i < 2; ++i) {
            #pragma unroll
            for (int j = 0; j < 8; ++j) {
                u32 u0 = __float_as_uint(S[i][j][0]) + 0x8000u;
                u32 u1 = __float_as_uint(S[i][j][1]) + 0x8000u;
                u32 u2 = __float_as_uint(S[i][j][2]) + 0x8000u;
                u32 u3 = __float_as_uint(S[i][j][3]) + 0x8000u;
                uint2 pk;
                pk.x = (u0 >> 16) | (u1 & 0xffff0000u);
                pk.y = (u2 >> 16) | (u3 & 0xffff0000u);
                *(uint2*)&PTw[l16 * 136 + j * 16 + quad * 4] = pk;
            }
            #pragma unroll
            for (int ks = 0; ks < 4; ++ks) {
                bf16x8 pa = *(bf16x8*)&PTw[l16 * 136 + ks * 32 + quad * 8];
                #pragma unroll
                for (int nt = 0; nt < 4; ++nt) {
                    int d = nt * 16 + l16;
                    int cg = ks * 4 + quad;
                    int phys = (cg & 8) | ((cg & 7) ^ (d & 7));
                    bf16x8 vb = *(bf16x8*)&Vs[(d * 16 + phys) * 8];
                    Oc[i][nt] = __builtin_amdgcn_mfma_f32_16x16x32_bf16(pa, vb, Oc[i][nt], 0, 0, 0);
                }
            }
        }
    }
    #pragma unroll
    for (int i = 0; i < 2; ++i) {
        int h = wid * 2 + i;
        #pragma unroll
        for (int r = 0; r < 4; ++r) {
            float linv = 1.f / __shfl(lcol[i], quad * 4 + r, 64);
            int ql = quad * 4 + r;
            #pragma unroll
            for (int nt = 0; nt < 4; ++nt) {
                int d = nt * 16 + l16;
                O[(size_t)(frame * 1024 + q0 + ql) * 512 + h * 64 + d] = f2b(Oc[i][nt][r] * linv);
            }
        }
    }
}

// ---------------------------------------------------------------- temporal attention
__global__ __launch_bounds__(256) void attn_tp_kernel(
    const ushort_t* __restrict__ q, const ushort_t* __restrict__ kv,
    const float* __restrict__ nullkv, const float* __restrict__ nullbias,
    const float* __restrict__ table, ushort_t* __restrict__ out)
{
    __shared__ float qs[16][512];
    __shared__ float ks[17][64];
    __shared__ float vs[17][64];
    __shared__ float sc[8][16][17];
    int b = blockIdx.x;
    int t = threadIdx.x;
    for (int e = t; e < 16 * 512; e += 256) {
        int f = e >> 9, c = e & 511;
        qs[f][c] = b2f(q[(size_t)(b * 16 + f) * 512 + c]);
    }
    for (int e = t; e < 17 * 64; e += 256) {
        int j = e >> 6, d = e & 63;
        ks[j][d] = (j == 0) ? nullkv[d]      : b2f(kv[(size_t)(b * 16 + j - 1) * 128 + d]);
        vs[j][d] = (j == 0) ? nullkv[64 + d] : b2f(kv[(size_t)(b * 16 + j - 1) * 128 + 64 + d]);
    }
    __syncthreads();
    for (int e = t; e < 8 * 16 * 17; e += 256) {
        int h = e / 272, rem = e - h * 272;
        int i = rem / 17, j = rem - i * 17;
        float acc = 0.f;
        for (int d = 0; d < 64; ++d) acc += qs[i][h * 64 + d] * ks[j][d];
        float bias = (j == 0) ? nullbias[h] : table[(i - (j - 1) + 15) * 8 + h];
        sc[h][i][j] = acc + bias;
    }
    __syncthreads();
    if (t < 128) {
        int h = t >> 4, i = t & 15;
        float mx = -1e30f;
        for (int j = 0; j < 17; ++j) mx = fmaxf(mx, sc[h][i][j]);
        float s = 0.f;
        for (int j = 0; j < 17; ++j) { float p = __expf(sc[h][i][j] - mx); sc[h][i][j] = p; s += p; }
        float inv = 1.f / s;
        for (int j = 0; j < 17; ++j) sc[h][i][j] *= inv;
    }
    __syncthreads();
    for (int e = t; e < 16 * 512; e += 256) {
        int i = e >> 9, c = e & 511;
        int h = c >> 6, d = c & 63;
        float acc = 0.f;
        #pragma unroll
        for (int j = 0; j < 17; ++j) acc += sc[h][i][j] * vs[j][d];
        out[(size_t)(b * 16 + i) * 512 + c] = f2b(acc);
    }
}

// ------------------------- FF shift-LN row stats from bf16 YS: (mean*rstd, rstd)
__global__ __launch_bounds__(256) void rowstats_bf16_kernel(
    const ushort_t* __restrict__ YS, float* __restrict__ stats)
{
    __shared__ float r1[4], r2[4];
    int r = blockIdx.x, t = threadIdx.x;
    const ushort_t* row = YS + (size_t)r * YSLD;
    float s = 0.f, s2 = 0.f;
    for (int c = t; c < FFI; c += 256) {
        float v = b2f(row[c]);
        s += v; s2 += v * v;
    }
    #pragma unroll
    for (int o = 32; o > 0; o >>= 1) { s += __shfl_down(s, o, 64); s2 += __shfl_down(s2, o, 64); }
    if ((t & 63) == 0) { r1[t >> 6] = s; r2[t >> 6] = s2; }
    __syncthreads();
    float S  = r1[0] + r1[1] + r1[2] + r1[3];
    float S2 = r2[0] + r2[1] + r2[2] + r2[3];
    float mean = S * (1.f / 1365.f);
    float var  = S2 * (1.f / 1365.f) - mean * mean;
    float rstd = rsqrtf(fmaxf(var, 1e-5f));
    if (t == 0) { stats[2 * r] = mean * rstd; stats[2 * r + 1] = rstd; }
}

// --------------------- colsum[n] = sum_k W'[n][k]  (rows of converted W')
__global__ __launch_bounds__(64) void colsum_kernel(
    const ushort_t* __restrict__ Wt, float* __restrict__ colsum)
{
    int n = blockIdx.x, t = threadIdx.x;
    const ushort_t* row = Wt + (size_t)n * YSLD;
    float s = 0.f;
    for (int k = t; k < YSLD; k += 64) s += b2f(row[k]);
    #pragma unroll
    for (int o = 32; o > 0; o >>= 1) s += __shfl_down(s, o, 64);
    if (t == 0) colsum[n] = s;
}

// ================================================================ launcher
extern "C" void kernel_launch(void* const* d_in, const int* in_sizes, int n_in,
                              void* d_out, int out_size, void* d_ws, size_t ws_size,
                              hipStream_t stream)
{
    const float* x          = (const float*)d_in[0];
    const float* sa_ln_w    = (const float*)d_in[1];
    const float* sa_ln_b    = (const float*)d_in[2];
    const float* sa_wq      = (const float*)d_in[3];
    const float* sa_wkv     = (const float*)d_in[4];
    const float* sa_null_kv = (const float*)d_in[5];
    const float* sa_null_b  = (const float*)d_in[6];
    const float* sa_wout    = (const float*)d_in[7];
    const float* sa_oln_w   = (const float*)d_in[8];
    const float* sa_oln_b   = (const float*)d_in[9];
    const float* ta_ln_w    = (const float*)d_in[10];
    const float* ta_ln_b    = (const float*)d_in[11];
    const float* ta_wq      = (const float*)d_in[12];
    const float* ta_wkv     = (const float*)d_in[13];
    const float* ta_null_kv = (const float*)d_in[14];
    const float* ta_null_b  = (const float*)d_in[15];
    const float* ta_wout    = (const float*)d_in[16];
    const float* ta_oln_w   = (const float*)d_in[17];
    const float* ta_oln_b   = (const float*)d_in[18];
    const float* sp_w0      = (const float*)d_in[19];
    const float* sp_b0      = (const float*)d_in[20];
    const float* sp_w1      = (const float*)d_in[21];
    const float* sp_b1      = (const float*)d_in[22];
    const float* sp_w2      = (const float*)d_in[23];
    const float* sp_b2      = (const float*)d_in[24];
    const float* tp_w0      = (const float*)d_in[25];
    const float* tp_b0      = (const float*)d_in[26];
    const float* tp_w1      = (const float*)d_in[27];
    const float* tp_b1      = (const float*)d_in[28];
    const float* tp_w2      = (const float*)d_in[29];
    const float* tp_b2      = (const float*)d_in[30];
    const float* ff_win     = (const float*)d_in[31];
    const float* ff_g       = (const float*)d_in[32];
    const float* ff_wout    = (const float*)d_in[33];

    char* ws = (char*)d_ws;
    // regions (bytes)
    float*    RES   = (float*)(ws + 0);                        // residual, spatial layout
    ushort_t* XN16  = (ushort_t*)(ws + 33554432);              // xn / x2 bf16
    ushort_t* Q16   = (ushort_t*)(ws + 50331648);              // spatial Q bf16 (spatial phase)
    float*    RT    = (float*)(ws + 50331648);                 // temporal residual f32 (temporal phase)
    ushort_t* YS    = (ushort_t*)(ws + 50331648);              // FF shifted act bf16 [16384][1376]
    ushort_t* WSA   = (ushort_t*)(ws + 67108864);              // spatial weights (dead by FF)
    ushort_t* KP    = (ushort_t*)(ws + 83886080);              // 16x1056x64 bf16 (spatial)
    ushort_t* VTb   = (ushort_t*)(ws + 86048768);              // 16x64x1056 bf16 (spatial)
    ushort_t* KV16  = (ushort_t*)(ws + 83886080);              // temporal KV bf16
    ushort_t* WTA   = (ushort_t*)(ws + 90439680);              // temporal weights
    ushort_t* AO16  = (ushort_t*)(ws + 92274688);              // attn out bf16 (dead by FF)
    ushort_t* BI    = (ushort_t*)(ws + 96468992);              // FF interleaved W [2816][512]
    ushort_t* WFFB  = (ushort_t*)(ws + 99352576);              // W' = (ff_wout*g)^T [512][1376]
    ushort_t* BIAS16= (ushort_t*)(ws + 109051904);             // spatial bias bf16 (PRJ region)
    float*    PRJ   = (float*)(ws + 109051904);                // proj out f32
    ushort_t* Q16t  = (ushort_t*)(ws + 109051904);             // temporal Q bf16
    float*    STATS = (float*)(ws + 142606336);                // 16384 x (mean*rstd, rstd)
    float*    SPT   = (float*)(ws + 142737408);                // spatial CPB table (spatial phase)
    float*    COLSUM= (float*)(ws + 142737408);                // colsum[512] (FF phase, dead SPT)
    float*    TPT   = (float*)(ws + 142864448);

    ushort_t* WQ_T  = WSA;                 // [512][512]
    ushort_t* WKV_T = WSA + 262144;        // [128][512]
    ushort_t* WO_T  = WSA + 327680;        // [512][512]
    ushort_t* tWQ_T  = WTA;
    ushort_t* tWKV_T = WTA + 262144;
    ushort_t* tWO_T  = WTA + 327680;

    dim3 blk(256);

    // bias tables
    cpb_kernel<<<dim3(3969), blk, 0, stream>>>(sp_w0, sp_b0, sp_w1, sp_b1, sp_w2, sp_b2, SPT, 0);
    cpb_kernel<<<dim3(31),   blk, 0, stream>>>(tp_w0, tp_b0, tp_w1, tp_b1, tp_w2, tp_b2, TPT, 1);
    bias_sp_kernel<<<dim3(1024, 8), blk, 0, stream>>>(SPT, sa_null_b, BIAS16);
    kvinit_kernel<<<dim3(16), blk, 0, stream>>>(sa_null_kv, KP, VTb);

    // ---------------- spatial ----------------
    wcvt_kernel<<<dim3(16, 16), blk, 0, stream>>>(sa_wq, 512, 0, WQ_T, 512, 512, 512, nullptr, 512);
    wcvt_kernel<<<dim3(4, 16),  blk, 0, stream>>>(sa_wkv, 128, 0, WKV_T, 512, 512, 128, nullptr, 128);
    wcvt_kernel<<<dim3(16, 16), blk, 0, stream>>>(sa_wout, 512, 0, WO_T, 512, 512, 512, nullptr, 512);
    transpose_in_kernel<<<dim3(512, 16), blk, 0, stream>>>(x, RES);
    ln_bf16_kernel<<<dim3(TOK), blk, 0, stream>>>(RES, XN16, sa_ln_w, sa_ln_b);
    gemm_mfma<3><<<dim3(512), blk, 0, stream>>>(XN16, 512, WQ_T, 512,
        nullptr, Q16, 512, TOK, 512, 512, 0.125f, 4, nullptr, nullptr, nullptr, nullptr, nullptr, nullptr);
    gemm_mfma<4><<<dim3(128), blk, 0, stream>>>(XN16, 512, WKV_T, 512,
        nullptr, nullptr, 0, TOK, 128, 512, 1.0f, 1, nullptr, nullptr, nullptr, nullptr, KP, VTb);
    attn_sp_mfma<<<dim3(1024), blk, 0, stream>>>(Q16, KP, VTb, BIAS16, AO16);
    gemm_mfma<0><<<dim3(512), blk, 0, stream>>>(AO16, 512, WO_T, 512,
        PRJ, nullptr, 512, TOK, 512, 512, 1.0f, 4, nullptr, nullptr, nullptr, nullptr, nullptr, nullptr);
    ln_add_kernel<<<dim3(TOK), blk, 0, stream>>>(PRJ, RES, sa_oln_w, sa_oln_b);

    // ---------------- temporal ----------------
    permute0_kernel<<<dim3(TOK), dim3(128), 0, stream>>>(RES, RT);
    wcvt_kernel<<<dim3(16, 16), blk, 0, stream>>>(ta_wq, 512, 0, tWQ_T, 512, 512, 512, nullptr, 512);
    wcvt_kernel<<<dim3(4, 16),  blk, 0, stream>>>(ta_wkv, 128, 0, tWKV_T, 512, 512, 128, nullptr, 128);
    wcvt_kernel<<<dim3(16, 16), blk, 0, stream>>>(ta_wout, 512, 0, tWO_T, 512, 512, 512, nullptr, 512);
    ln_bf16_kernel<<<dim3(TOK), blk, 0, stream>>>(RT, XN16, ta_ln_w, ta_ln_b);
    gemm_mfma<3><<<dim3(512), blk, 0, stream>>>(XN16, 512, tWQ_T, 512,
        nullptr, Q16t, 512, TOK, 512, 512, 0.125f, 4, nullptr, nullptr, nullptr, nullptr, nullptr, nullptr);
    gemm_mfma<3><<<dim3(128), blk, 0, stream>>>(XN16, 512, tWKV_T, 512,
        nullptr, KV16, 128, TOK, 128, 512, 1.0f, 1, nullptr, nullptr, nullptr, nullptr, nullptr, nullptr);
    attn_tp_kernel<<<dim3(1024), blk, 0, stream>>>(Q16t, KV16, ta_null_kv, ta_null_b, TPT, AO16);
    gemm_mfma<0><<<dim3(512), blk, 0, stream>>>(AO16, 512, tWO_T, 512,
        PRJ, nullptr, 512, TOK, 512, 512, 1.0f, 4, nullptr, nullptr, nullptr, nullptr, nullptr, nullptr);
    ln_add_kernel<<<dim3(TOK), blk, 0, stream>>>(PRJ, RT, ta_oln_w, ta_oln_b);
    permute1_dual_kernel<<<dim3(TOK), dim3(128), 0, stream>>>(RT, RES, XN16);

    // ---------------- feed-forward ----------------
    wcvt_kernel<<<dim3(44, 16), blk, 0, stream>>>(ff_win, 2730, 0,   BI,       1024, 512, FFI, nullptr, 1408);
    wcvt_kernel<<<dim3(44, 16), blk, 0, stream>>>(ff_win, 2730, FFI, BI + 512, 1024, 512, FFI, nullptr, 1408);
    wcvt_kernel<<<dim3(16, 43), blk, 0, stream>>>(ff_wout, 512, 0, WFFB, YSLD, FFI, 512, ff_g, 512);
    colsum_kernel<<<dim3(512), dim3(64), 0, stream>>>(WFFB, COLSUM);
    ff_gemm_fused<<<dim3(2816), blk, 0, stream>>>(XN16, BI, YS);
    rowstats_bf16_kernel<<<dim3(TOK), blk, 0, stream>>>(YS, STATS);
    gemm_mfma<5><<<dim3(512), blk, 0, stream>>>(YS, YSLD, WFFB, YSLD,
        nullptr, nullptr, 0, TOK, 512, YSLD, 1.0f, 4, STATS, COLSUM, RES, (float*)d_out, nullptr, nullptr);
}